// Round 10
// baseline (751.413 us; speedup 1.0000x reference)
//
#include <hip/hip_runtime.h>
#include <hip/hip_bf16.h>
#include <math.h>

#define CC 120       // channels
#define NHEADS 6
#define HDIM 20      // head dim
#define NTOK 128     // tokens per window
#define HID2 240
#define SCALE_F 0.2236067977499790f  // 20^-0.5

typedef __hip_bfloat16 bf16;
typedef __attribute__((ext_vector_type(8))) short bf16x8;   // 8 bf16 (4 VGPRs)
typedef __attribute__((ext_vector_type(4))) float f32x4;    // MFMA accumulator

__device__ inline f32x4 mfma16(bf16x8 a, bf16x8 b, f32x4 c) {
  return __builtin_amdgcn_mfma_f32_16x16x32_bf16(a, b, c, 0, 0, 0);
}

__device__ inline short f2bf_s(float f) {
  bf16 h = __float2bfloat16(f);
  return *reinterpret_cast<short*>(&h);
}

// LDS-only barrier: order LDS ops across waves WITHOUT draining vmcnt
// (global stores from the epilogue keep flying across blocks).
__device__ __forceinline__ void lds_barrier() {
  asm volatile("s_waitcnt lgkmcnt(0)" ::: "memory");
  __builtin_amdgcn_s_barrier();
  asm volatile("" ::: "memory");
}

// ---------------------------------------------------------------------------
// token -> rolled spatial source position (also the scatter destination for
// window-reverse + un-roll, which is the same map).
__device__ inline size_t token_src_offset(int token) {
  const int wi = token >> 7, n = token & 127;
  const int b_ = wi >> 8, rem = wi & 255;
  const int dB = rem >> 6, hB = (rem >> 3) & 7, wB = rem & 7;
  const int dI = n >> 6, hI = (n >> 3) & 7, wI = n & 7;
  const int d = dB * 2 + dI, h = hB * 8 + hI, w = wB * 8 + wI;
  const int ds = (d + 1) & 7, hs = (h + 4) & 63, ws2 = (w + 4) & 63;
  return (((size_t)(b_ * 8 + ds) * 64 + hs) * 64 + ws2) * CC;
}

__device__ inline void ln120(float* xv, const float* __restrict__ g,
                             const float* __restrict__ bb) {
  float s0 = 0.f, s1 = 0.f, s2 = 0.f, s3 = 0.f;
#pragma unroll
  for (int k = 0; k < CC; k += 4) {
    s0 += xv[k]; s1 += xv[k + 1]; s2 += xv[k + 2]; s3 += xv[k + 3];
  }
  const float mean = ((s0 + s1) + (s2 + s3)) * (1.f / 120.f);
  float v0 = 0.f, v1 = 0.f, v2 = 0.f, v3 = 0.f;
#pragma unroll
  for (int k = 0; k < CC; k += 4) {
    float d0 = xv[k] - mean, d1 = xv[k + 1] - mean;
    float d2 = xv[k + 2] - mean, d3 = xv[k + 3] - mean;
    v0 += d0 * d0; v1 += d1 * d1; v2 += d2 * d2; v3 += d3 * d3;
  }
  const float rstd = rsqrtf(((v0 + v1) + (v2 + v3)) * (1.f / 120.f) + 1e-5f);
#pragma unroll
  for (int k = 0; k < CC; k++) xv[k] = (xv[k] - mean) * rstd * g[k] + bb[k];
}

__device__ inline float dot120(const float* xv, const float* __restrict__ wr) {
  float a0 = 0.f, a1 = 0.f, a2 = 0.f, a3 = 0.f;
#pragma unroll
  for (int k = 0; k < CC; k += 4) {
    a0 = fmaf(xv[k], wr[k], a0);
    a1 = fmaf(xv[k + 1], wr[k + 1], a1);
    a2 = fmaf(xv[k + 2], wr[k + 2], a2);
    a3 = fmaf(xv[k + 3], wr[k + 3], a3);
  }
  return (a0 + a1) + (a2 + a3);
}

// ===========================================================================
// FAST PATH
// ===========================================================================
// Weight prep.
//  Bffn [512][128]: rows 0..239 = W11, 256..495 = W12 (K pad, bias separate)
//  Bfc2 [128][256], Bproj [128][256]
//  Wself2/Wmut2 [576][128]: rows 0..191 q (heads padded to 32, SCALE folded),
//    192..383 k, 384..575 v. col 120 = bias (A1 col120 == 1), pads 0.
//    v-row pad chan 20 = e120 (=> V col 20 == 1.0: PV computes softmax rowsum).
__global__ __launch_bounds__(256) void k_prep(
    const float* __restrict__ w11, const float* __restrict__ w12,
    const float* __restrict__ fc2w, const float* __restrict__ projw,
    const float* __restrict__ wself, const float* __restrict__ bself,
    const float* __restrict__ wmut, const float* __restrict__ bmut,
    bf16* __restrict__ Bffn, bf16* __restrict__ Bfc2, bf16* __restrict__ Bproj,
    bf16* __restrict__ Wself2, bf16* __restrict__ Wmut2) {
  const int i = blockIdx.x * 256 + threadIdx.x;
  if (i < 65536) {
    const int r = i >> 7, k = i & 127;
    float v = 0.f;
    if (k < 120) {
      if (r < 240) v = w11[r * 120 + k];
      else if (r >= 256 && r < 496) v = w12[(r - 256) * 120 + k];
    }
    Bffn[i] = __float2bfloat16(v);
  } else if (i < 98304) {
    const int j = i - 65536, r = j >> 8, k = j & 255;
    Bfc2[j] = __float2bfloat16((r < 120 && k < 240) ? fc2w[r * 240 + k] : 0.f);
  } else if (i < 131072) {
    const int j = i - 98304, r = j >> 8, k = j & 255;
    Bproj[j] = __float2bfloat16((r < 120 && k < 240) ? projw[r * 240 + k] : 0.f);
  } else if (i < 278528) {
    const int j = (i - 131072) % 73728;
    const bool is_self = (i - 131072) < 73728;
    const float* w = is_self ? wself : wmut;
    const float* b = is_self ? bself : bmut;
    const int r = j >> 7, k = j & 127;
    const int grp = r / 192;              // 0=q 1=k 2=v
    const int rr = r % 192;
    const int hh = rr >> 5, jj = rr & 31;
    float v = 0.f;
    if (jj < 20) {
      const int orow = grp * 120 + hh * 20 + jj;
      if (k < 120) v = w[orow * 120 + k];
      else if (k == 120) v = b[orow];
      if (grp == 0) v *= SCALE_F;
    } else if (grp == 2 && jj == 20 && k == 120) {
      v = 1.0f;                           // rowsum column
    }
    (is_self ? Wself2 : Wmut2)[j] = __float2bfloat16(v);
  }
}

// posqT[c][t63] = dot(pos[t63], W'_c over real channels); SCALE on q cols.
// TRANSPOSED so the QKV phase can f32x4-load 4 consecutive token rows
// (matching the MFMA C/D row layout quad*4+r).
__global__ __launch_bounds__(256) void k_posqT(
    const float* __restrict__ pos, const float* __restrict__ wmut,
    float* __restrict__ posqT) {
  const int i = blockIdx.x * 256 + threadIdx.x;
  if (i >= 576 * 64) return;
  const int c = i >> 6, t63 = i & 63;
  const int grp = c / 192, rr = c % 192;
  const int hh = rr >> 5, jj = rr & 31;
  float v = 0.f;
  if (jj < 20) {
    v = dot120(pos + (size_t)t63 * CC, wmut + (size_t)(grp * 120 + hh * 20 + jj) * CC);
    if (grp == 0) v *= SCALE_F;
  }
  posqT[i] = v;   // i == c*64 + t63
}

// biasT[h][col][row] = rpb[rpi[row,col]*6+h]  (TRANSPOSED rel-pos bias, fp32)
__global__ __launch_bounds__(256) void k_biasT(
    const int* __restrict__ rpi, const float* __restrict__ rpb,
    float* __restrict__ biasT) {
  const int i = blockIdx.x * 256 + threadIdx.x;
  if (i >= NHEADS * 16384) return;
  const int h = i >> 14, rc = i & 16383;
  const int col = rc >> 7, row = rc & 127;
  biasT[i] = rpb[rpi[row * 128 + col] * NHEADS + h];
}

// maskT[wc][col][row] = mask[wc][row][col]  (fp32, 16.8 MB). Coalesced writes.
__global__ __launch_bounds__(256) void k_maskT(
    const float* __restrict__ mask, float* __restrict__ maskT) {
  const int i = blockIdx.x * 256 + threadIdx.x;
  const int wc = i >> 14, rc = i & 16383;
  const int col = rc >> 7, row = rc & 127;
  maskT[i] = mask[(size_t)wc * 16384 + row * 128 + col];
}

// LN1 + roll + partition -> A1 bf16 [131072][128], col 120 = 1.0 (bias col).
__global__ __launch_bounds__(256) void k_a1(
    const float* __restrict__ x, const float* __restrict__ g1,
    const float* __restrict__ b1, bf16* __restrict__ A1) {
  const int token = blockIdx.x * 256 + threadIdx.x;
  const float4* xr4 = (const float4*)(x + token_src_offset(token));
  float xv[CC];
#pragma unroll
  for (int k = 0; k < 30; k++) {
    const float4 v = xr4[k];
    xv[k * 4] = v.x; xv[k * 4 + 1] = v.y; xv[k * 4 + 2] = v.z; xv[k * 4 + 3] = v.w;
  }
  ln120(xv, g1, b1);
  bf16x8* dst8 = (bf16x8*)(A1 + (size_t)token * 128);
#pragma unroll
  for (int k = 0; k < 15; k++) {
    bf16x8 v;
#pragma unroll
    for (int j = 0; j < 8; j++) v[j] = f2bf_s(xv[k * 8 + j]);
    dst8[k] = v;
  }
  bf16x8 tail = {0, 0, 0, 0, 0, 0, 0, 0};
  tail[0] = f2bf_s(1.0f);
  dst8[15] = tail;
}

// ---------------------------------------------------------------------------
// FUSED QKV + attention core for ONE (window, head, self|mut) triple.
// Single QKV -> barrier -> attention sequence, no trailing barrier: block
// exits right after its scattered stores are issued (vmcnt never drained
// mid-kernel). Bias/mask/pos enter through the MFMA C operand via TRANSPOSED
// fp32 tables (f32x4 loads supply acc rows quad*4+r directly).
template <bool MUT>
__device__ __forceinline__ void fattn_core(
    const int wi, const int hh, const bf16x8 (&af)[2][4],
    const bf16* __restrict__ W2, const float* __restrict__ posqT,
    const float* __restrict__ biasT, const bool hasmask,
    const float* __restrict__ maskTb, bf16* __restrict__ xout,
    bf16* kS, bf16* vS, bf16* qP) {
  const int w = threadIdx.x >> 6, lane = threadIdx.x & 63;
  const int ln = lane & 15, quad = lane >> 4;

  // ---- QKV phase: group g = 0(q) 1(k) 2(v) ----
#pragma unroll
  for (int g = 0; g < 3; g++) {
    bf16x8 bfr[2][4];
#pragma unroll
    for (int nt = 0; nt < 2; nt++)
#pragma unroll
      for (int s = 0; s < 4; s++)
        bfr[nt][s] = *(const bf16x8*)(W2 + (size_t)(g * 192 + hh * 32 + nt * 16 + ln) * 128 + s * 32 + quad * 8);
    f32x4 acc[2][2] = {};
#pragma unroll
    for (int s = 0; s < 4; s++)
#pragma unroll
      for (int mi = 0; mi < 2; mi++)
#pragma unroll
        for (int nt = 0; nt < 2; nt++)
          acc[mi][nt] = mfma16(af[mi][s], bfr[nt][s], acc[mi][nt]);
    if (MUT) {
#pragma unroll
      for (int mi = 0; mi < 2; mi++)
#pragma unroll
        for (int nt = 0; nt < 2; nt++) {
          const f32x4 pq = *(const f32x4*)&posqT[
              (size_t)(g * 192 + hh * 32 + nt * 16 + ln) * 64 +
              ((w * 32 + mi * 16 + quad * 4) & 63)];
          acc[mi][nt] += pq;
        }
    }
#pragma unroll
    for (int mi = 0; mi < 2; mi++)
#pragma unroll
      for (int nt = 0; nt < 2; nt++)
#pragma unroll
        for (int r = 0; r < 4; r++) {
          const int lrow = w * 32 + mi * 16 + quad * 4 + r;
          const short bv = f2bf_s(acc[mi][nt][r]);
          if (g == 0)      *(short*)&qP[lrow * 40 + nt * 16 + ln] = bv;
          else if (g == 1) *(short*)&kS[lrow * 40 + nt * 16 + ln] = bv;
          else             *(short*)&vS[(nt * 16 + ln) * 136 + lrow] = bv;
        }
  }
  lds_barrier();
  // ---- attention phase ----
  bf16x8 qf[2];
#pragma unroll
  for (int i = 0; i < 2; i++)
    qf[i] = *(const bf16x8*)(&qP[(w * 32 + i * 16 + ln) * 40 + quad * 8]);
  f32x4 accO[2][2];
#pragma unroll
  for (int i = 0; i < 2; i++)
#pragma unroll
    for (int nt = 0; nt < 2; nt++) accO[i][nt] = (f32x4){0.f, 0.f, 0.f, 0.f};
  const int kb = MUT ? ((w < 2) ? 64 : 0) : 0;
  const int nchunk = MUT ? 2 : 4;
  for (int chunk = 0; chunk < nchunk; chunk++) {
    const int key0 = kb + chunk * 32;
    bf16x8 kf[2], vf[2];
    kf[0] = *(const bf16x8*)(&kS[(key0 + ln) * 40 + quad * 8]);
    kf[1] = *(const bf16x8*)(&kS[(key0 + 16 + ln) * 40 + quad * 8]);
    vf[0] = *(const bf16x8*)(&vS[ln * 136 + key0 + quad * 8]);
    vf[1] = *(const bf16x8*)(&vS[(16 + ln) * 136 + key0 + quad * 8]);
#pragma unroll
    for (int i = 0; i < 2; i++) {
      const int rb = w * 32 + i * 16 + quad * 4;
      f32x4 c0, c1;
      if (MUT) {
        if (hasmask) {
          c0 = *(const f32x4*)&maskTb[(chunk * 32 + ln) * 128 + (rb & 63)];
          c1 = *(const f32x4*)&maskTb[(chunk * 32 + 16 + ln) * 128 + (rb & 63)];
        } else {
          c0 = (f32x4){0.f, 0.f, 0.f, 0.f};
          c1 = (f32x4){0.f, 0.f, 0.f, 0.f};
        }
      } else {
        c0 = *(const f32x4*)&biasT[(size_t)hh * 16384 + (key0 + ln) * 128 + rb];
        c1 = *(const f32x4*)&biasT[(size_t)hh * 16384 + (key0 + 16 + ln) * 128 + rb];
        if (hasmask) {
          c0 += *(const f32x4*)&maskTb[(key0 + ln) * 128 + rb];
          c1 += *(const f32x4*)&maskTb[(key0 + 16 + ln) * 128 + rb];
        }
      }
      const f32x4 s0 = mfma16(qf[i], kf[0], c0);
      const f32x4 s1 = mfma16(qf[i], kf[1], c1);
#pragma unroll
      for (int r = 0; r < 4; r++) {
        const int row = rb + r;
        *(short*)&qP[row * 40 + ln] = f2bf_s(__expf(s0[r]));
        *(short*)&qP[row * 40 + 16 + ln] = f2bf_s(__expf(s1[r]));
      }
    }
#pragma unroll
    for (int i = 0; i < 2; i++) {
      bf16x8 pf = *(const bf16x8*)(&qP[(w * 32 + i * 16 + ln) * 40 + quad * 8]);
      accO[i][0] = mfma16(pf, vf[0], accO[i][0]);
      accO[i][1] = mfma16(pf, vf[1], accO[i][1]);
    }
  }
  // ---- epilogue: rowsum (V pad col 20) + normalize + write ----
#pragma unroll
  for (int i = 0; i < 2; i++) {
#pragma unroll
    for (int r = 0; r < 4; r++) {
      const float rs = __shfl(accO[i][1][r], (lane & 48) + 4, 64);
      const float inv = 1.f / rs;
      const int row = w * 32 + i * 16 + quad * 4 + r;
      const int orow_i = MUT ? ((w < 2) ? 64 + row : row - 64) : row;
      const int token = wi * NTOK + orow_i;
      bf16* orow = xout + (size_t)token * 256 + (MUT ? 0 : CC) + hh * HDIM;
      orow[ln] = __float2bfloat16(accO[i][0][r] * inv);
      if (ln < 4) orow[16 + ln] = __float2bfloat16(accO[i][1][r] * inv);
    }
  }
}

// One block = one (window, head, self|mut) triple. 12288 blocks, LDS 29184 B
// -> 5 resident blocks/CU (20 waves), ~48 short staggered block-slots per CU:
// barriers of co-resident blocks never align, maximizing latency overlap.
// XCD-chunked swizzle keeps the 12 same-window blocks on one XCD's L2.
__global__ __launch_bounds__(256, 5) void k_fattn3(
    const bf16* __restrict__ A1, const bf16* __restrict__ Wself2,
    const bf16* __restrict__ Wmut2, const float* __restrict__ posqT,
    const float* __restrict__ biasT, const float* __restrict__ maskT,
    bf16* __restrict__ xout) {
  __shared__ bf16 kS[128 * 40];
  __shared__ bf16 vS[32 * 136];
  __shared__ bf16 qP[128 * 40];   // q staging, then P
  const int gid = blockIdx.x;
  const int bid = (gid & 7) * 1536 + (gid >> 3);  // bijective: 12288 = 8*1536
  const int wi = bid / 12;
  const int sub = bid - wi * 12;
  const int w = threadIdx.x >> 6, lane = threadIdx.x & 63;
  const int ln = lane & 15, quad = lane >> 4;
  bf16x8 af[2][4];
#pragma unroll
  for (int mi = 0; mi < 2; mi++)
#pragma unroll
    for (int s = 0; s < 4; s++)
      af[mi][s] = *(const bf16x8*)(A1 + (size_t)(wi * NTOK + w * 32 + mi * 16 + ln) * 128 + s * 32 + quad * 8);
  const int wc = wi & 255;
  // window crosses the roll boundary iff any block index is the last one
  const bool hasmask = ((wc >> 6) == 3) || (((wc >> 3) & 7) == 7) || ((wc & 7) == 7);
  const float* maskTb = maskT + (size_t)wc * 16384;

  if (sub < 6)
    fattn_core<false>(wi, sub, af, Wself2, nullptr, biasT, hasmask, maskTb, xout, kS, vS, qP);
  else
    fattn_core<true>(wi, sub - 6, af, Wmut2, posqT, biasT, hasmask, maskTb, xout, kS, vS, qP);
}

// LN2 -> bf16 A-matrix [131072][128]. float4 loads + bf16x8 stores.
__global__ __launch_bounds__(256) void k_ln2(
    const float* __restrict__ out, const float* __restrict__ g2,
    const float* __restrict__ b2, bf16* __restrict__ A2) {
  const int row = blockIdx.x * 256 + threadIdx.x;
  const float4* xr4 = (const float4*)(out + (size_t)row * CC);
  float xv[CC];
#pragma unroll
  for (int k = 0; k < 30; k++) {
    const float4 v = xr4[k];
    xv[k * 4] = v.x; xv[k * 4 + 1] = v.y; xv[k * 4 + 2] = v.z; xv[k * 4 + 3] = v.w;
  }
  ln120(xv, g2, b2);
  bf16x8* dst8 = (bf16x8*)(A2 + (size_t)row * 128);
#pragma unroll
  for (int k = 0; k < 15; k++) {
    bf16x8 v;
#pragma unroll
    for (int j = 0; j < 8; j++) v[j] = f2bf_s(xv[k * 8 + j]);
    dst8[k] = v;
  }
  bf16x8 tail = {0, 0, 0, 0, 0, 0, 0, 0};
  dst8[15] = tail;
}

// FFN1 MFMA: h = gelu(A2@W11^T) * (A2@W12^T). grid (4, 256) — R6 config.
__global__ __launch_bounds__(256) void k_ffn1_mfma(
    const bf16* __restrict__ A2, const bf16* __restrict__ Bffn,
    const float* __restrict__ b11, const float* __restrict__ b12,
    bf16* __restrict__ h) {
  const int j = blockIdx.x * 4 + (threadIdx.x >> 6);  // pair index 0..15
  const int lane = threadIdx.x & 63;
  const int ln = lane & 15, quad = lane >> 4;
  bf16x8 b1f[4], b2f[4];
#pragma unroll
  for (int s = 0; s < 4; s++) {
    b1f[s] = *(const bf16x8*)(Bffn + (size_t)(j * 16 + ln) * 128 + s * 32 + quad * 8);
    b2f[s] = *(const bf16x8*)(Bffn + (size_t)(j * 16 + 256 + ln) * 128 + s * 32 + quad * 8);
  }
  const int col = j * 16 + ln;
  const float bias1 = (col < HID2) ? b11[col] : 0.f;
  const float bias2 = (col < HID2) ? b12[col] : 0.f;
  const int m_base = blockIdx.y * 512;
  for (int it = 0; it < 16; it++) {
    const int m0 = m_base + it * 32;
    f32x4 acc[2][2] = {};
    bf16x8 af[2][4];
#pragma unroll
    for (int mi = 0; mi < 2; mi++)
#pragma unroll
      for (int s = 0; s < 4; s++)
        af[mi][s] = *(const bf16x8*)(A2 + (size_t)(m0 + mi * 16 + ln) * 128 + s * 32 + quad * 8);
#pragma unroll
    for (int s = 0; s < 4; s++)
#pragma unroll
      for (int mi = 0; mi < 2; mi++) {
        acc[mi][0] = mfma16(af[mi][s], b1f[s], acc[mi][0]);
        acc[mi][1] = mfma16(af[mi][s], b2f[s], acc[mi][1]);
      }
    if (col < HID2) {
#pragma unroll
      for (int mi = 0; mi < 2; mi++)
#pragma unroll
        for (int r = 0; r < 4; r++) {
          const int row = m0 + mi * 16 + quad * 4 + r;
          const float a = acc[mi][0][r] + bias1;
          const float c = acc[mi][1][r] + bias2;
          const float ge = 0.5f * a * (1.f + erff(a * 0.70710678118654752f));
          h[(size_t)row * 256 + col] = __float2bfloat16(ge * c);
        }
    }
  }
}

// Output GEMMs, K=256 (padded), N=120. grid (1, 1024).
template <bool PROJ>
__global__ __launch_bounds__(256) void k_out_mfma(
    const bf16* __restrict__ A, const bf16* __restrict__ Bw,
    const float* __restrict__ bias, const float* __restrict__ xin,
    float* __restrict__ out) {
  const int w = threadIdx.x >> 6;
  const int lane = threadIdx.x & 63;
  const int ln = lane & 15, quad = lane >> 4;
  bf16x8 bfr[2][8];
#pragma unroll
  for (int nt = 0; nt < 2; nt++)
#pragma unroll
    for (int s = 0; s < 8; s++)
      bfr[nt][s] = *(const bf16x8*)(Bw + (size_t)((w * 2 + nt) * 16 + ln) * 256 + s * 32 + quad * 8);
  const int m_base = blockIdx.y * 128;
  for (int it = 0; it < 4; it++) {
    const int m0 = m_base + it * 32;
    f32x4 acc[2][2] = {};
    bf16x8 af[2][8];
#pragma unroll
    for (int mi = 0; mi < 2; mi++)
#pragma unroll
      for (int s = 0; s < 8; s++)
        af[mi][s] = *(const bf16x8*)(A + (size_t)(m0 + mi * 16 + ln) * 256 + s * 32 + quad * 8);
#pragma unroll
    for (int s = 0; s < 8; s++)
#pragma unroll
      for (int mi = 0; mi < 2; mi++)
#pragma unroll
        for (int nt = 0; nt < 2; nt++)
          acc[mi][nt] = mfma16(af[mi][s], bfr[nt][s], acc[mi][nt]);
#pragma unroll
    for (int mi = 0; mi < 2; mi++)
#pragma unroll
      for (int nt = 0; nt < 2; nt++) {
        const int colc = (w * 2 + nt) * 16 + ln;
        if (colc < CC) {
#pragma unroll
          for (int r = 0; r < 4; r++) {
            const int row = m0 + mi * 16 + quad * 4 + r;
            if (PROJ) {
              const size_t dst = token_src_offset(row);
              out[dst + colc] = xin[dst + colc] + bias[colc] + acc[mi][nt][r];
            } else {
              out[(size_t)row * CC + colc] += bias[colc] + acc[mi][nt][r];
            }
          }
        }
      }
  }
}

// ===========================================================================
// FALLBACK PATH (round-2 proven kernels; used only if ws is too small)
// ===========================================================================
__global__ __launch_bounds__(128) void k_attn_self_fb(
    const float* __restrict__ x, const float* __restrict__ g1,
    const float* __restrict__ b1, const float* __restrict__ wqkv,
    const float* __restrict__ bqkv, const float* __restrict__ mask,
    const float* __restrict__ rpb, const int* __restrict__ rpi,
    bf16* __restrict__ xout) {
  __shared__ float kl[NTOK][HDIM];
  __shared__ float vl[NTOK][HDIM];
  const int wi = blockIdx.x, hh = blockIdx.y, t = threadIdx.x;
  const int token = wi * NTOK + t;
  const float* xr = x + token_src_offset(token);
  float xv[CC];
#pragma unroll
  for (int k = 0; k < CC; k++) xv[k] = xr[k];
  ln120(xv, g1, b1);
  float q[HDIM];
  for (int j = 0; j < HDIM; j++) {
    const int c = hh * HDIM + j;
    q[j] = (dot120(xv, wqkv + (size_t)c * CC) + bqkv[c]) * SCALE_F;
    kl[t][j] = dot120(xv, wqkv + (size_t)(CC + c) * CC) + bqkv[CC + c];
    vl[t][j] = dot120(xv, wqkv + (size_t)(2 * CC + c) * CC) + bqkv[2 * CC + c];
  }
  __syncthreads();
  const float* mrow = mask + ((size_t)(wi & 255) * NTOK + t) * NTOK;
  const int* rrow = rpi + t * NTOK;
  float sum = 0.f;
  float o[HDIM];
#pragma unroll
  for (int i = 0; i < HDIM; i++) o[i] = 0.f;
  for (int m = 0; m < NTOK; m++) {
    float a0 = 0.f, a1 = 0.f, a2 = 0.f, a3 = 0.f;
#pragma unroll
    for (int i = 0; i < HDIM; i += 4) {
      a0 = fmaf(q[i], kl[m][i], a0);
      a1 = fmaf(q[i + 1], kl[m][i + 1], a1);
      a2 = fmaf(q[i + 2], kl[m][i + 2], a2);
      a3 = fmaf(q[i + 3], kl[m][i + 3], a3);
    }
    const float sc = (a0 + a1) + (a2 + a3) + rpb[rrow[m] * NHEADS + hh] + mrow[m];
    const float p = __expf(sc);
    sum += p;
#pragma unroll
    for (int i = 0; i < HDIM; i++) o[i] = fmaf(p, vl[m][i], o[i]);
  }
  const float inv = 1.f / sum;
  bf16* orow = xout + (size_t)token * HID2 + CC + hh * HDIM;
#pragma unroll
  for (int i = 0; i < HDIM; i++) orow[i] = __float2bfloat16(o[i] * inv);
}

__global__ __launch_bounds__(64) void k_attn_mut_fb(
    const float* __restrict__ x, const float* __restrict__ g1,
    const float* __restrict__ b1, const float* __restrict__ wqkv,
    const float* __restrict__ bqkv, const float* __restrict__ pos,
    const float* __restrict__ mask, bf16* __restrict__ xout) {
  __shared__ float kl[64][HDIM];
  __shared__ float vl[64][HDIM];
  const int wi = blockIdx.x, hh = blockIdx.y, which = blockIdx.z;
  const int t = threadIdx.x;
  const int qtok = which ? t : 64 + t;
  const int ktok = which ? 64 + t : t;
  const float* pr = pos + (size_t)t * CC;
  float xv[CC];
  {
    const float* xr = x + token_src_offset(wi * NTOK + ktok);
#pragma unroll
    for (int k = 0; k < CC; k++) xv[k] = xr[k];
    ln120(xv, g1, b1);
#pragma unroll
    for (int k = 0; k < CC; k++) xv[k] += pr[k];
    for (int j = 0; j < HDIM; j++) {
      const int c = hh * HDIM + j;
      kl[t][j] = dot120(xv, wqkv + (size_t)(CC + c) * CC) + bqkv[CC + c];
      vl[t][j] = dot120(xv, wqkv + (size_t)(2 * CC + c) * CC) + bqkv[2 * CC + c];
    }
  }
  float q[HDIM];
  {
    const float* xr = x + token_src_offset(wi * NTOK + qtok);
#pragma unroll
    for (int k = 0; k < CC; k++) xv[k] = xr[k];
    ln120(xv, g1, b1);
#pragma unroll
    for (int k = 0; k < CC; k++) xv[k] += pr[k];
    for (int j = 0; j < HDIM; j++) {
      const int c = hh * HDIM + j;
      q[j] = (dot120(xv, wqkv + (size_t)c * CC) + bqkv[c]) * SCALE_F;
    }
  }
  __syncthreads();
  const float* mrow = mask + ((size_t)(wi & 255) * NTOK + t) * NTOK;
  float sum = 0.f;
  float o[HDIM];
#pragma unroll
  for (int i = 0; i < HDIM; i++) o[i] = 0.f;
  for (int m = 0; m < 64; m++) {
    float a0 = 0.f, a1 = 0.f, a2 = 0.f, a3 = 0.f;
#pragma unroll
    for (int i = 0; i < HDIM; i += 4) {
      a0 = fmaf(q[i], kl[m][i], a0);
      a1 = fmaf(q[i + 1], kl[m][i + 1], a1);
      a2 = fmaf(q[i + 2], kl[m][i + 2], a2);
      a3 = fmaf(q[i + 3], kl[m][i + 3], a3);
    }
    const float p = __expf((a0 + a1) + (a2 + a3) + mrow[m]);
    sum += p;
#pragma unroll
    for (int i = 0; i < HDIM; i++) o[i] = fmaf(p, vl[m][i], o[i]);
  }
  const float inv = 1.f / sum;
  const int orow_i = which ? 64 + t : t;
  bf16* orow = xout + (size_t)(wi * NTOK + orow_i) * HID2 + hh * HDIM;
#pragma unroll
  for (int i = 0; i < HDIM; i++) orow[i] = __float2bfloat16(o[i] * inv);
}

template <int HALF>
__global__ __launch_bounds__(256) void k_proj_fb(
    const bf16* __restrict__ xout, const float* __restrict__ pw,
    const float* __restrict__ pb, const float* __restrict__ xin,
    float* __restrict__ out) {
  const int token = blockIdx.x * 256 + threadIdx.x;
  float xv[CC];
  const bf16* xr = xout + (size_t)token * HID2 + HALF * CC;
#pragma unroll
  for (int k = 0; k < CC; k++) xv[k] = __bfloat162float(xr[k]);
  const size_t dst = token_src_offset(token);
  for (int o = 0; o < CC; o++) {
    const float acc = dot120(xv, pw + (size_t)o * HID2 + HALF * CC);
    if (HALF == 0)
      out[dst + o] = xin[dst + o] + pb[o] + acc;
    else
      out[dst + o] += acc;
  }
}

__global__ __launch_bounds__(256) void k_ffn1_fb(
    const float* __restrict__ xres, const float* __restrict__ g,
    const float* __restrict__ bb, const float* __restrict__ w11,
    const float* __restrict__ b11, const float* __restrict__ w12,
    const float* __restrict__ b12, bf16* __restrict__ hbuf) {
  const int row = blockIdx.x * 256 + threadIdx.x;
  const float* xr = xres + (size_t)row * CC;
  float xv[CC];
#pragma unroll
  for (int k = 0; k < CC; k++) xv[k] = xr[k];
  ln120(xv, g, bb);
  bf16* hr = hbuf + (size_t)row * HID2;
  for (int o = 0; o < HID2; o++) {
    const float a = b11[o] + dot120(xv, w11 + (size_t)o * CC);
    const float c = b12[o] + dot120(xv, w12 + (size_t)o * CC);
    const float ge = 0.5f * a * (1.f + erff(a * 0.70710678118654752f));
    hr[o] = __float2bfloat16(ge * c);
  }
}

template <int HALF>
__global__ __launch_bounds__(256) void k_ffn2_fb(
    const bf16* __restrict__ hbuf, const float* __restrict__ w2,
    const float* __restrict__ b2f, float* __restrict__ out) {
  const int row = blockIdx.x * 256 + threadIdx.x;
  float xv[CC];
  const bf16* xr = hbuf + (size_t)row * HID2 + HALF * CC;
#pragma unroll
  for (int k = 0; k < CC; k++) xv[k] = __bfloat162float(xr[k]);
  float* orow = out + (size_t)row * CC;
  for (int o = 0; o < CC; o++) {
    float acc = dot120(xv, w2 + (size_t)o * HID2 + HALF * CC);
    if (HALF == 0) acc += b2f[o];
    orow[o] += acc;
  }
}

// ---------------------------------------------------------------------------
extern "C" void kernel_launch(void* const* d_in, const int* in_sizes, int n_in,
                              void* d_out, int out_size, void* d_ws, size_t ws_size,
                              hipStream_t stream) {
  const float* x          = (const float*)d_in[0];
  const float* attn_mask  = (const float*)d_in[1];
  const float* g1         = (const float*)d_in[2];
  const float* b1         = (const float*)d_in[3];
  const float* qkv_self_w = (const float*)d_in[4];
  const float* qkv_self_b = (const float*)d_in[5];
  const float* qkv_mut_w  = (const float*)d_in[6];
  const float* qkv_mut_b  = (const float*)d_in[7];
  const float* proj_w     = (const float*)d_in[8];
  const float* proj_b     = (const float*)d_in[9];
  const float* rpb_table  = (const float*)d_in[10];
  const float* pos_bias   = (const float*)d_in[11];
  const float* g2         = (const float*)d_in[12];
  const float* b2         = (const float*)d_in[13];
  const float* fc11_w     = (const float*)d_in[14];
  const float* fc11_b     = (const float*)d_in[15];
  const float* fc12_w     = (const float*)d_in[16];
  const float* fc12_b     = (const float*)d_in[17];
  const float* fc2_w      = (const float*)d_in[18];
  const float* fc2_b      = (const float*)d_in[19];
  const int*   rpi        = (const int*)d_in[20];
  float* out = (float*)d_out;

  // ws layout (bytes), gate unchanged:
  //   xout  @ 0           : 131072*256*2 = 67,108,864
  //   A1/A2 @ 67,108,864  : 131072*128*2 = 33,554,432
  //   Bffn  @ 100,663,296 : 131,072 ; Bfc2 +65,536 ; Bproj +65,536
  // d_out doubles as scratch until proj overwrites every element:
  //   Wself2 @ 40,000,000 ; Wmut2 @ 40,200,000 ; posqT @ 40,400,000
  //   biasT @ 41,000,000 (393,216) ; maskT @ 41,500,000 (16,777,216)
  //   -> ends 58,277,216 < 62,914,560 (out bytes)
  const bool fast = ws_size >= (size_t)100925440;

  if (fast) {
    bf16* xout  = (bf16*)d_ws;
    bf16* hbuf  = xout;
    bf16* A1    = (bf16*)((char*)d_ws + 67108864);
    bf16* A2    = A1;
    bf16* Bffn  = (bf16*)((char*)d_ws + 100663296);
    bf16* Bfc2  = Bffn + 65536;
    bf16* Bproj = Bfc2 + 32768;

    bf16*  Wself2 = (bf16*)((char*)d_out + 40000000);
    bf16*  Wmut2  = (bf16*)((char*)d_out + 40200000);
    float* posqT  = (float*)((char*)d_out + 40400000);
    float* biasT  = (float*)((char*)d_out + 41000000);
    float* maskT  = (float*)((char*)d_out + 41500000);

    k_prep<<<1088, 256, 0, stream>>>(fc11_w, fc12_w, fc2_w, proj_w,
                                     qkv_self_w, qkv_self_b, qkv_mut_w, qkv_mut_b,
                                     Bffn, Bfc2, Bproj, Wself2, Wmut2);
    k_posqT<<<144, 256, 0, stream>>>(pos_bias, qkv_mut_w, posqT);
    k_biasT<<<384, 256, 0, stream>>>(rpi, rpb_table, biasT);
    k_maskT<<<16384, 256, 0, stream>>>(attn_mask, maskT);
    k_a1<<<512, 256, 0, stream>>>(x, g1, b1, A1);
    k_fattn3<<<12288, 256, 0, stream>>>(A1, Wself2, Wmut2, posqT, biasT, maskT, xout);
    k_out_mfma<true><<<dim3(1, 1024), 256, 0, stream>>>(xout, Bproj, proj_b, x, out);
    k_ln2<<<512, 256, 0, stream>>>(out, g2, b2, A2);
    k_ffn1_mfma<<<dim3(4, 256), 256, 0, stream>>>(A2, Bffn, fc11_b, fc12_b, hbuf);
    k_out_mfma<false><<<dim3(1, 1024), 256, 0, stream>>>(hbuf, Bfc2, fc2_b, nullptr, out);
  } else {
    bf16* xout = (bf16*)d_ws;
    bf16* hbuf = (bf16*)d_ws;
    k_attn_self_fb<<<dim3(1024, NHEADS), 128, 0, stream>>>(
        x, g1, b1, qkv_self_w, qkv_self_b, attn_mask, rpb_table, rpi, xout);
    k_attn_mut_fb<<<dim3(1024, NHEADS, 2), 64, 0, stream>>>(
        x, g1, b1, qkv_mut_w, qkv_mut_b, pos_bias, attn_mask, xout);
    k_proj_fb<0><<<512, 256, 0, stream>>>(xout, proj_w, proj_b, x, out);
    k_proj_fb<1><<<512, 256, 0, stream>>>(xout, proj_w, proj_b, x, out);
    k_ffn1_fb<<<512, 256, 0, stream>>>(out, g2, b2, fc11_w, fc11_b, fc12_w, fc12_b, hbuf);
    k_ffn2_fb<0><<<512, 256, 0, stream>>>(hbuf, fc2_w, fc2_b, out);
    k_ffn2_fb<1><<<512, 256, 0, stream>>>(hbuf, fc2_w, fc2_b, out);
  }
}

// Round 11
// 716.535 us; speedup vs baseline: 1.0487x; 1.0487x over previous
//
#include <hip/hip_runtime.h>
#include <hip/hip_bf16.h>
#include <math.h>

#define CC 120       // channels
#define NHEADS 6
#define HDIM 20      // head dim
#define NTOK 128     // tokens per window
#define HID2 240
#define SCALE_F 0.2236067977499790f  // 20^-0.5

typedef __hip_bfloat16 bf16;
typedef __attribute__((ext_vector_type(8))) short bf16x8;   // 8 bf16 (4 VGPRs)
typedef __attribute__((ext_vector_type(4))) float f32x4;    // MFMA accumulator

__device__ inline f32x4 mfma16(bf16x8 a, bf16x8 b, f32x4 c) {
  return __builtin_amdgcn_mfma_f32_16x16x32_bf16(a, b, c, 0, 0, 0);
}

__device__ inline short f2bf_s(float f) {
  bf16 h = __float2bfloat16(f);
  return *reinterpret_cast<short*>(&h);
}

// LDS-only barrier: order LDS ops across waves WITHOUT draining vmcnt
// (global stores keep flying across phases).
__device__ __forceinline__ void lds_barrier() {
  asm volatile("s_waitcnt lgkmcnt(0)" ::: "memory");
  __builtin_amdgcn_s_barrier();
  asm volatile("" ::: "memory");
}

// ---------------------------------------------------------------------------
// token -> rolled spatial source position (also the scatter destination for
// window-reverse + un-roll, which is the same map).
__device__ inline size_t token_src_offset(int token) {
  const int wi = token >> 7, n = token & 127;
  const int b_ = wi >> 8, rem = wi & 255;
  const int dB = rem >> 6, hB = (rem >> 3) & 7, wB = rem & 7;
  const int dI = n >> 6, hI = (n >> 3) & 7, wI = n & 7;
  const int d = dB * 2 + dI, h = hB * 8 + hI, w = wB * 8 + wI;
  const int ds = (d + 1) & 7, hs = (h + 4) & 63, ws2 = (w + 4) & 63;
  return (((size_t)(b_ * 8 + ds) * 64 + hs) * 64 + ws2) * CC;
}

__device__ inline void ln120(float* xv, const float* __restrict__ g,
                             const float* __restrict__ bb) {
  float s0 = 0.f, s1 = 0.f, s2 = 0.f, s3 = 0.f;
#pragma unroll
  for (int k = 0; k < CC; k += 4) {
    s0 += xv[k]; s1 += xv[k + 1]; s2 += xv[k + 2]; s3 += xv[k + 3];
  }
  const float mean = ((s0 + s1) + (s2 + s3)) * (1.f / 120.f);
  float v0 = 0.f, v1 = 0.f, v2 = 0.f, v3 = 0.f;
#pragma unroll
  for (int k = 0; k < CC; k += 4) {
    float d0 = xv[k] - mean, d1 = xv[k + 1] - mean;
    float d2 = xv[k + 2] - mean, d3 = xv[k + 3] - mean;
    v0 += d0 * d0; v1 += d1 * d1; v2 += d2 * d2; v3 += d3 * d3;
  }
  const float rstd = rsqrtf(((v0 + v1) + (v2 + v3)) * (1.f / 120.f) + 1e-5f);
#pragma unroll
  for (int k = 0; k < CC; k++) xv[k] = (xv[k] - mean) * rstd * g[k] + bb[k];
}

__device__ inline float dot120(const float* xv, const float* __restrict__ wr) {
  float a0 = 0.f, a1 = 0.f, a2 = 0.f, a3 = 0.f;
#pragma unroll
  for (int k = 0; k < CC; k += 4) {
    a0 = fmaf(xv[k], wr[k], a0);
    a1 = fmaf(xv[k + 1], wr[k + 1], a1);
    a2 = fmaf(xv[k + 2], wr[k + 2], a2);
    a3 = fmaf(xv[k + 3], wr[k + 3], a3);
  }
  return (a0 + a1) + (a2 + a3);
}

// ===========================================================================
// FAST PATH
// ===========================================================================
// Weight prep.
//  Bffn [512][128]: rows 0..239 = W11, 256..495 = W12 (K pad, bias separate)
//  Bfc2 [128][256], Bproj [128][256]
//  Wself2/Wmut2 [576][128]: rows 0..191 q (heads padded to 32, SCALE folded),
//    192..383 k, 384..575 v. col 120 = bias (A1 col120 == 1), pads 0.
//    v-row pad chan 20 = e120 (=> V col 20 == 1.0: PV computes softmax rowsum).
__global__ __launch_bounds__(256) void k_prep(
    const float* __restrict__ w11, const float* __restrict__ w12,
    const float* __restrict__ fc2w, const float* __restrict__ projw,
    const float* __restrict__ wself, const float* __restrict__ bself,
    const float* __restrict__ wmut, const float* __restrict__ bmut,
    bf16* __restrict__ Bffn, bf16* __restrict__ Bfc2, bf16* __restrict__ Bproj,
    bf16* __restrict__ Wself2, bf16* __restrict__ Wmut2) {
  const int i = blockIdx.x * 256 + threadIdx.x;
  if (i < 65536) {
    const int r = i >> 7, k = i & 127;
    float v = 0.f;
    if (k < 120) {
      if (r < 240) v = w11[r * 120 + k];
      else if (r >= 256 && r < 496) v = w12[(r - 256) * 120 + k];
    }
    Bffn[i] = __float2bfloat16(v);
  } else if (i < 98304) {
    const int j = i - 65536, r = j >> 8, k = j & 255;
    Bfc2[j] = __float2bfloat16((r < 120 && k < 240) ? fc2w[r * 240 + k] : 0.f);
  } else if (i < 131072) {
    const int j = i - 98304, r = j >> 8, k = j & 255;
    Bproj[j] = __float2bfloat16((r < 120 && k < 240) ? projw[r * 240 + k] : 0.f);
  } else if (i < 278528) {
    const int j = (i - 131072) % 73728;
    const bool is_self = (i - 131072) < 73728;
    const float* w = is_self ? wself : wmut;
    const float* b = is_self ? bself : bmut;
    const int r = j >> 7, k = j & 127;
    const int grp = r / 192;              // 0=q 1=k 2=v
    const int rr = r % 192;
    const int hh = rr >> 5, jj = rr & 31;
    float v = 0.f;
    if (jj < 20) {
      const int orow = grp * 120 + hh * 20 + jj;
      if (k < 120) v = w[orow * 120 + k];
      else if (k == 120) v = b[orow];
      if (grp == 0) v *= SCALE_F;
    } else if (grp == 2 && jj == 20 && k == 120) {
      v = 1.0f;                           // rowsum column
    }
    (is_self ? Wself2 : Wmut2)[j] = __float2bfloat16(v);
  }
}

// posqT[c][t63] = dot(pos[t63], W'_c over real channels); SCALE on q cols.
// TRANSPOSED so the QKV phase can f32x4-load 4 consecutive token rows
// (matching the MFMA C/D row layout quad*4+r).
__global__ __launch_bounds__(256) void k_posqT(
    const float* __restrict__ pos, const float* __restrict__ wmut,
    float* __restrict__ posqT) {
  const int i = blockIdx.x * 256 + threadIdx.x;
  if (i >= 576 * 64) return;
  const int c = i >> 6, t63 = i & 63;
  const int grp = c / 192, rr = c % 192;
  const int hh = rr >> 5, jj = rr & 31;
  float v = 0.f;
  if (jj < 20) {
    v = dot120(pos + (size_t)t63 * CC, wmut + (size_t)(grp * 120 + hh * 20 + jj) * CC);
    if (grp == 0) v *= SCALE_F;
  }
  posqT[i] = v;   // i == c*64 + t63
}

// biasT[h][col][row] = rpb[rpi[row,col]*6+h]  (TRANSPOSED rel-pos bias, fp32)
__global__ __launch_bounds__(256) void k_biasT(
    const int* __restrict__ rpi, const float* __restrict__ rpb,
    float* __restrict__ biasT) {
  const int i = blockIdx.x * 256 + threadIdx.x;
  if (i >= NHEADS * 16384) return;
  const int h = i >> 14, rc = i & 16383;
  const int col = rc >> 7, row = rc & 127;
  biasT[i] = rpb[rpi[row * 128 + col] * NHEADS + h];
}

// maskT[wc][col][row] = mask[wc][row][col]  (fp32, 16.8 MB). Coalesced writes.
__global__ __launch_bounds__(256) void k_maskT(
    const float* __restrict__ mask, float* __restrict__ maskT) {
  const int i = blockIdx.x * 256 + threadIdx.x;
  const int wc = i >> 14, rc = i & 16383;
  const int col = rc >> 7, row = rc & 127;
  maskT[i] = mask[(size_t)wc * 16384 + row * 128 + col];
}

// LN1 + roll + partition -> A1 bf16 [131072][128], col 120 = 1.0 (bias col).
__global__ __launch_bounds__(256) void k_a1(
    const float* __restrict__ x, const float* __restrict__ g1,
    const float* __restrict__ b1, bf16* __restrict__ A1) {
  const int token = blockIdx.x * 256 + threadIdx.x;
  const float4* xr4 = (const float4*)(x + token_src_offset(token));
  float xv[CC];
#pragma unroll
  for (int k = 0; k < 30; k++) {
    const float4 v = xr4[k];
    xv[k * 4] = v.x; xv[k * 4 + 1] = v.y; xv[k * 4 + 2] = v.z; xv[k * 4 + 3] = v.w;
  }
  ln120(xv, g1, b1);
  bf16x8* dst8 = (bf16x8*)(A1 + (size_t)token * 128);
#pragma unroll
  for (int k = 0; k < 15; k++) {
    bf16x8 v;
#pragma unroll
    for (int j = 0; j < 8; j++) v[j] = f2bf_s(xv[k * 8 + j]);
    dst8[k] = v;
  }
  bf16x8 tail = {0, 0, 0, 0, 0, 0, 0, 0};
  tail[0] = f2bf_s(1.0f);
  dst8[15] = tail;
}

// ---------------------------------------------------------------------------
// FUSED QKV + attention (Round-3 measured-best structure, restored verbatim).
// Block = window-pass, 4 waves; loop 6 heads. Bias/mask/pos enter through
// the MFMA C operand via TRANSPOSED fp32 tables. Barriers are LDS-only.
template <bool MUT>
__device__ __forceinline__ void fattn_body(
    const int wi, const bf16* __restrict__ A1, const bf16* __restrict__ W2,
    const float* __restrict__ posqT, const float* __restrict__ biasT,
    const float* __restrict__ maskT, bf16* __restrict__ xout,
    bf16* kS, bf16* vS, bf16* qP) {
  const int w = threadIdx.x >> 6, lane = threadIdx.x & 63;
  const int ln = lane & 15, quad = lane >> 4;
  // A-fragments for this wave's 32 rows (reused across 6 heads x 3 groups)
  bf16x8 af[2][4];
#pragma unroll
  for (int mi = 0; mi < 2; mi++)
#pragma unroll
    for (int s = 0; s < 4; s++)
      af[mi][s] = *(const bf16x8*)(A1 + (size_t)(wi * NTOK + w * 32 + mi * 16 + ln) * 128 + s * 32 + quad * 8);
  const int wc = wi & 255;
  // window crosses the roll boundary iff any block index is the last one
  const bool hasmask = ((wc >> 6) == 3) || (((wc >> 3) & 7) == 7) || ((wc & 7) == 7);
  const float* maskTb = maskT + (size_t)wc * 16384;

  for (int hh = 0; hh < NHEADS; hh++) {
    // ---- QKV phase: group g = 0(q) 1(k) 2(v) ----
#pragma unroll
    for (int g = 0; g < 3; g++) {
      bf16x8 bfr[2][4];
#pragma unroll
      for (int nt = 0; nt < 2; nt++)
#pragma unroll
        for (int s = 0; s < 4; s++)
          bfr[nt][s] = *(const bf16x8*)(W2 + (size_t)(g * 192 + hh * 32 + nt * 16 + ln) * 128 + s * 32 + quad * 8);
      f32x4 acc[2][2] = {};
#pragma unroll
      for (int s = 0; s < 4; s++)
#pragma unroll
        for (int mi = 0; mi < 2; mi++)
#pragma unroll
          for (int nt = 0; nt < 2; nt++)
            acc[mi][nt] = mfma16(af[mi][s], bfr[nt][s], acc[mi][nt]);
      if (MUT) {
#pragma unroll
        for (int mi = 0; mi < 2; mi++)
#pragma unroll
          for (int nt = 0; nt < 2; nt++) {
            const f32x4 pq = *(const f32x4*)&posqT[
                (size_t)(g * 192 + hh * 32 + nt * 16 + ln) * 64 +
                ((w * 32 + mi * 16 + quad * 4) & 63)];
            acc[mi][nt] += pq;
          }
      }
#pragma unroll
      for (int mi = 0; mi < 2; mi++)
#pragma unroll
        for (int nt = 0; nt < 2; nt++)
#pragma unroll
          for (int r = 0; r < 4; r++) {
            const int lrow = w * 32 + mi * 16 + quad * 4 + r;
            const short bv = f2bf_s(acc[mi][nt][r]);
            if (g == 0)      *(short*)&qP[lrow * 40 + nt * 16 + ln] = bv;
            else if (g == 1) *(short*)&kS[lrow * 40 + nt * 16 + ln] = bv;
            else             *(short*)&vS[(nt * 16 + ln) * 136 + lrow] = bv;
          }
    }
    lds_barrier();
    // ---- attention phase ----
    bf16x8 qf[2];
#pragma unroll
    for (int i = 0; i < 2; i++)
      qf[i] = *(const bf16x8*)(&qP[(w * 32 + i * 16 + ln) * 40 + quad * 8]);
    f32x4 accO[2][2];
#pragma unroll
    for (int i = 0; i < 2; i++)
#pragma unroll
      for (int nt = 0; nt < 2; nt++) accO[i][nt] = (f32x4){0.f, 0.f, 0.f, 0.f};
    const int kb = MUT ? ((w < 2) ? 64 : 0) : 0;
    const int nchunk = MUT ? 2 : 4;
    for (int chunk = 0; chunk < nchunk; chunk++) {
      const int key0 = kb + chunk * 32;
      bf16x8 kf[2], vf[2];
      kf[0] = *(const bf16x8*)(&kS[(key0 + ln) * 40 + quad * 8]);
      kf[1] = *(const bf16x8*)(&kS[(key0 + 16 + ln) * 40 + quad * 8]);
      vf[0] = *(const bf16x8*)(&vS[ln * 136 + key0 + quad * 8]);
      vf[1] = *(const bf16x8*)(&vS[(16 + ln) * 136 + key0 + quad * 8]);
#pragma unroll
      for (int i = 0; i < 2; i++) {
        const int rb = w * 32 + i * 16 + quad * 4;
        f32x4 c0, c1;
        if (MUT) {
          if (hasmask) {
            c0 = *(const f32x4*)&maskTb[(chunk * 32 + ln) * 128 + (rb & 63)];
            c1 = *(const f32x4*)&maskTb[(chunk * 32 + 16 + ln) * 128 + (rb & 63)];
          } else {
            c0 = (f32x4){0.f, 0.f, 0.f, 0.f};
            c1 = (f32x4){0.f, 0.f, 0.f, 0.f};
          }
        } else {
          c0 = *(const f32x4*)&biasT[(size_t)hh * 16384 + (key0 + ln) * 128 + rb];
          c1 = *(const f32x4*)&biasT[(size_t)hh * 16384 + (key0 + 16 + ln) * 128 + rb];
          if (hasmask) {
            c0 += *(const f32x4*)&maskTb[(key0 + ln) * 128 + rb];
            c1 += *(const f32x4*)&maskTb[(key0 + 16 + ln) * 128 + rb];
          }
        }
        const f32x4 s0 = mfma16(qf[i], kf[0], c0);
        const f32x4 s1 = mfma16(qf[i], kf[1], c1);
#pragma unroll
        for (int r = 0; r < 4; r++) {
          const int row = rb + r;
          *(short*)&qP[row * 40 + ln] = f2bf_s(__expf(s0[r]));
          *(short*)&qP[row * 40 + 16 + ln] = f2bf_s(__expf(s1[r]));
        }
      }
#pragma unroll
      for (int i = 0; i < 2; i++) {
        bf16x8 pf = *(const bf16x8*)(&qP[(w * 32 + i * 16 + ln) * 40 + quad * 8]);
        accO[i][0] = mfma16(pf, vf[0], accO[i][0]);
        accO[i][1] = mfma16(pf, vf[1], accO[i][1]);
      }
    }
    // ---- epilogue: rowsum (V pad col 20) + normalize + write ----
#pragma unroll
    for (int i = 0; i < 2; i++) {
#pragma unroll
      for (int r = 0; r < 4; r++) {
        const float rs = __shfl(accO[i][1][r], (lane & 48) + 4, 64);
        const float inv = 1.f / rs;
        const int row = w * 32 + i * 16 + quad * 4 + r;
        const int orow_i = MUT ? ((w < 2) ? 64 + row : row - 64) : row;
        const int token = wi * NTOK + orow_i;
        bf16* orow = xout + (size_t)token * 256 + (MUT ? 0 : CC) + hh * HDIM;
        orow[ln] = __float2bfloat16(accO[i][0][r] * inv);
        if (ln < 4) orow[16 + ln] = __float2bfloat16(accO[i][1][r] * inv);
      }
    }
    lds_barrier();   // protect kS/vS/qP before next head's QKV overwrite
  }
}

// Merged self+mut launch: blocks 0..1023 self, 1024..2047 mut. (R3 measured best.)
__global__ __launch_bounds__(256, 4) void k_fattn2(
    const bf16* __restrict__ A1, const bf16* __restrict__ Wself2,
    const bf16* __restrict__ Wmut2, const float* __restrict__ posqT,
    const float* __restrict__ biasT, const float* __restrict__ maskT,
    bf16* __restrict__ xout) {
  __shared__ bf16 kS[128 * 40];
  __shared__ bf16 vS[32 * 136];
  __shared__ bf16 qP[128 * 40];   // q staging, then P
  if (blockIdx.x < 1024)
    fattn_body<false>(blockIdx.x, A1, Wself2, nullptr, biasT, maskT, xout, kS, vS, qP);
  else
    fattn_body<true>(blockIdx.x - 1024, A1, Wmut2, posqT, biasT, maskT, xout, kS, vS, qP);
}

// ---------------------------------------------------------------------------
// PROJ GEMM + residual + FUSED LN2. Replaces k_out_mfma<true> + k_ln2:
// the block already holds each output row's full 120 channels, so LN2's
// separate 63 MB re-read of `out` is eliminated. vals staged in LDS (16 KB),
// 8 threads/row shuffle-tree reduce, A2 bf16 rows written directly.
__global__ __launch_bounds__(256) void k_proj_ln2(
    const bf16* __restrict__ A, const bf16* __restrict__ Bw,
    const float* __restrict__ bias, const float* __restrict__ xin,
    const float* __restrict__ g2, const float* __restrict__ b2,
    float* __restrict__ out, bf16* __restrict__ A2) {
  __shared__ float vals[32][128];
  const int w = threadIdx.x >> 6;
  const int lane = threadIdx.x & 63;
  const int ln = lane & 15, quad = lane >> 4;
  bf16x8 bfr[2][8];
#pragma unroll
  for (int nt = 0; nt < 2; nt++)
#pragma unroll
    for (int s = 0; s < 8; s++)
      bfr[nt][s] = *(const bf16x8*)(Bw + (size_t)((w * 2 + nt) * 16 + ln) * 256 + s * 32 + quad * 8);
  const int m_base = blockIdx.y * 128;
  for (int it = 0; it < 4; it++) {
    const int m0 = m_base + it * 32;
    f32x4 acc[2][2] = {};
    bf16x8 af[2][8];
#pragma unroll
    for (int mi = 0; mi < 2; mi++)
#pragma unroll
      for (int s = 0; s < 8; s++)
        af[mi][s] = *(const bf16x8*)(A + (size_t)(m0 + mi * 16 + ln) * 256 + s * 32 + quad * 8);
#pragma unroll
    for (int s = 0; s < 8; s++)
#pragma unroll
      for (int mi = 0; mi < 2; mi++)
#pragma unroll
        for (int nt = 0; nt < 2; nt++)
          acc[mi][nt] = mfma16(af[mi][s], bfr[nt][s], acc[mi][nt]);
    // write out (residual) + stage fp32 row values in LDS
#pragma unroll
    for (int mi = 0; mi < 2; mi++)
#pragma unroll
      for (int nt = 0; nt < 2; nt++) {
        const int colc = (w * 2 + nt) * 16 + ln;
#pragma unroll
        for (int r = 0; r < 4; r++) {
          const int rloc = mi * 16 + quad * 4 + r;
          float v = 0.f;
          if (colc < CC) {
            const size_t dst = token_src_offset(m0 + rloc);
            v = xin[dst + colc] + bias[colc] + acc[mi][nt][r];
            out[dst + colc] = v;
          }
          vals[rloc][colc] = v;
        }
      }
    lds_barrier();
    // per-row LN: 8 threads per row (lanes rloc*8+sub, all in one wave octet)
    {
      const int rloc = threadIdx.x >> 3, sub = threadIdx.x & 7;
      float s = 0.f;
#pragma unroll
      for (int k = 0; k < 15; k++) s += vals[rloc][sub * 15 + k];
      s += __shfl_xor(s, 1); s += __shfl_xor(s, 2); s += __shfl_xor(s, 4);
      const float mean = s * (1.f / 120.f);
      float vv = 0.f;
#pragma unroll
      for (int k = 0; k < 15; k++) {
        const float d = vals[rloc][sub * 15 + k] - mean;
        vv += d * d;
      }
      vv += __shfl_xor(vv, 1); vv += __shfl_xor(vv, 2); vv += __shfl_xor(vv, 4);
      const float rstd = rsqrtf(vv * (1.f / 120.f) + 1e-5f);
      const size_t srow = token_src_offset(m0 + rloc) / CC;   // spatial row
      bf16x8 o0, o1;
#pragma unroll
      for (int k = 0; k < 8; k++) {
        const int c0 = sub * 16 + k, c1 = sub * 16 + 8 + k;
        const float f0 = (c0 < CC) ? (vals[rloc][c0] - mean) * rstd * g2[c0] + b2[c0] : 0.f;
        const float f1 = (c1 < CC) ? (vals[rloc][c1] - mean) * rstd * g2[c1] + b2[c1] : 0.f;
        o0[k] = f2bf_s(f0); o1[k] = f2bf_s(f1);
      }
      *(bf16x8*)(A2 + srow * 128 + sub * 16) = o0;
      *(bf16x8*)(A2 + srow * 128 + sub * 16 + 8) = o1;
    }
    lds_barrier();   // protect vals before next iteration overwrites
  }
}

// FFN1 MFMA: h = gelu(A2@W11^T) * (A2@W12^T). grid (4, 256) — R6 config.
__global__ __launch_bounds__(256) void k_ffn1_mfma(
    const bf16* __restrict__ A2, const bf16* __restrict__ Bffn,
    const float* __restrict__ b11, const float* __restrict__ b12,
    bf16* __restrict__ h) {
  const int j = blockIdx.x * 4 + (threadIdx.x >> 6);  // pair index 0..15
  const int lane = threadIdx.x & 63;
  const int ln = lane & 15, quad = lane >> 4;
  bf16x8 b1f[4], b2f[4];
#pragma unroll
  for (int s = 0; s < 4; s++) {
    b1f[s] = *(const bf16x8*)(Bffn + (size_t)(j * 16 + ln) * 128 + s * 32 + quad * 8);
    b2f[s] = *(const bf16x8*)(Bffn + (size_t)(j * 16 + 256 + ln) * 128 + s * 32 + quad * 8);
  }
  const int col = j * 16 + ln;
  const float bias1 = (col < HID2) ? b11[col] : 0.f;
  const float bias2 = (col < HID2) ? b12[col] : 0.f;
  const int m_base = blockIdx.y * 512;
  for (int it = 0; it < 16; it++) {
    const int m0 = m_base + it * 32;
    f32x4 acc[2][2] = {};
    bf16x8 af[2][4];
#pragma unroll
    for (int mi = 0; mi < 2; mi++)
#pragma unroll
      for (int s = 0; s < 4; s++)
        af[mi][s] = *(const bf16x8*)(A2 + (size_t)(m0 + mi * 16 + ln) * 128 + s * 32 + quad * 8);
#pragma unroll
    for (int s = 0; s < 4; s++)
#pragma unroll
      for (int mi = 0; mi < 2; mi++) {
        acc[mi][0] = mfma16(af[mi][s], b1f[s], acc[mi][0]);
        acc[mi][1] = mfma16(af[mi][s], b2f[s], acc[mi][1]);
      }
    if (col < HID2) {
#pragma unroll
      for (int mi = 0; mi < 2; mi++)
#pragma unroll
        for (int r = 0; r < 4; r++) {
          const int row = m0 + mi * 16 + quad * 4 + r;
          const float a = acc[mi][0][r] + bias1;
          const float c = acc[mi][1][r] + bias2;
          const float ge = 0.5f * a * (1.f + erff(a * 0.70710678118654752f));
          h[(size_t)row * 256 + col] = __float2bfloat16(ge * c);
        }
    }
  }
}

// Output GEMM, K=256 (padded), N=120. grid (1, 1024). (fc2 path only now.)
template <bool PROJ>
__global__ __launch_bounds__(256) void k_out_mfma(
    const bf16* __restrict__ A, const bf16* __restrict__ Bw,
    const float* __restrict__ bias, const float* __restrict__ xin,
    float* __restrict__ out) {
  const int w = threadIdx.x >> 6;
  const int lane = threadIdx.x & 63;
  const int ln = lane & 15, quad = lane >> 4;
  bf16x8 bfr[2][8];
#pragma unroll
  for (int nt = 0; nt < 2; nt++)
#pragma unroll
    for (int s = 0; s < 8; s++)
      bfr[nt][s] = *(const bf16x8*)(Bw + (size_t)((w * 2 + nt) * 16 + ln) * 256 + s * 32 + quad * 8);
  const int m_base = blockIdx.y * 128;
  for (int it = 0; it < 4; it++) {
    const int m0 = m_base + it * 32;
    f32x4 acc[2][2] = {};
    bf16x8 af[2][8];
#pragma unroll
    for (int mi = 0; mi < 2; mi++)
#pragma unroll
      for (int s = 0; s < 8; s++)
        af[mi][s] = *(const bf16x8*)(A + (size_t)(m0 + mi * 16 + ln) * 256 + s * 32 + quad * 8);
#pragma unroll
    for (int s = 0; s < 8; s++)
#pragma unroll
      for (int mi = 0; mi < 2; mi++)
#pragma unroll
        for (int nt = 0; nt < 2; nt++)
          acc[mi][nt] = mfma16(af[mi][s], bfr[nt][s], acc[mi][nt]);
#pragma unroll
    for (int mi = 0; mi < 2; mi++)
#pragma unroll
      for (int nt = 0; nt < 2; nt++) {
        const int colc = (w * 2 + nt) * 16 + ln;
        if (colc < CC) {
#pragma unroll
          for (int r = 0; r < 4; r++) {
            const int row = m0 + mi * 16 + quad * 4 + r;
            if (PROJ) {
              const size_t dst = token_src_offset(row);
              out[dst + colc] = xin[dst + colc] + bias[colc] + acc[mi][nt][r];
            } else {
              out[(size_t)row * CC + colc] += bias[colc] + acc[mi][nt][r];
            }
          }
        }
      }
  }
}

// ===========================================================================
// FALLBACK PATH (round-2 proven kernels; used only if ws is too small)
// ===========================================================================
__global__ __launch_bounds__(128) void k_attn_self_fb(
    const float* __restrict__ x, const float* __restrict__ g1,
    const float* __restrict__ b1, const float* __restrict__ wqkv,
    const float* __restrict__ bqkv, const float* __restrict__ mask,
    const float* __restrict__ rpb, const int* __restrict__ rpi,
    bf16* __restrict__ xout) {
  __shared__ float kl[NTOK][HDIM];
  __shared__ float vl[NTOK][HDIM];
  const int wi = blockIdx.x, hh = blockIdx.y, t = threadIdx.x;
  const int token = wi * NTOK + t;
  const float* xr = x + token_src_offset(token);
  float xv[CC];
#pragma unroll
  for (int k = 0; k < CC; k++) xv[k] = xr[k];
  ln120(xv, g1, b1);
  float q[HDIM];
  for (int j = 0; j < HDIM; j++) {
    const int c = hh * HDIM + j;
    q[j] = (dot120(xv, wqkv + (size_t)c * CC) + bqkv[c]) * SCALE_F;
    kl[t][j] = dot120(xv, wqkv + (size_t)(CC + c) * CC) + bqkv[CC + c];
    vl[t][j] = dot120(xv, wqkv + (size_t)(2 * CC + c) * CC) + bqkv[2 * CC + c];
  }
  __syncthreads();
  const float* mrow = mask + ((size_t)(wi & 255) * NTOK + t) * NTOK;
  const int* rrow = rpi + t * NTOK;
  float sum = 0.f;
  float o[HDIM];
#pragma unroll
  for (int i = 0; i < HDIM; i++) o[i] = 0.f;
  for (int m = 0; m < NTOK; m++) {
    float a0 = 0.f, a1 = 0.f, a2 = 0.f, a3 = 0.f;
#pragma unroll
    for (int i = 0; i < HDIM; i += 4) {
      a0 = fmaf(q[i], kl[m][i], a0);
      a1 = fmaf(q[i + 1], kl[m][i + 1], a1);
      a2 = fmaf(q[i + 2], kl[m][i + 2], a2);
      a3 = fmaf(q[i + 3], kl[m][i + 3], a3);
    }
    const float sc = (a0 + a1) + (a2 + a3) + rpb[rrow[m] * NHEADS + hh] + mrow[m];
    const float p = __expf(sc);
    sum += p;
#pragma unroll
    for (int i = 0; i < HDIM; i++) o[i] = fmaf(p, vl[m][i], o[i]);
  }
  const float inv = 1.f / sum;
  bf16* orow = xout + (size_t)token * HID2 + CC + hh * HDIM;
#pragma unroll
  for (int i = 0; i < HDIM; i++) orow[i] = __float2bfloat16(o[i] * inv);
}

__global__ __launch_bounds__(64) void k_attn_mut_fb(
    const float* __restrict__ x, const float* __restrict__ g1,
    const float* __restrict__ b1, const float* __restrict__ wqkv,
    const float* __restrict__ bqkv, const float* __restrict__ pos,
    const float* __restrict__ mask, bf16* __restrict__ xout) {
  __shared__ float kl[64][HDIM];
  __shared__ float vl[64][HDIM];
  const int wi = blockIdx.x, hh = blockIdx.y, which = blockIdx.z;
  const int t = threadIdx.x;
  const int qtok = which ? t : 64 + t;
  const int ktok = which ? 64 + t : t;
  const float* pr = pos + (size_t)t * CC;
  float xv[CC];
  {
    const float* xr = x + token_src_offset(wi * NTOK + ktok);
#pragma unroll
    for (int k = 0; k < CC; k++) xv[k] = xr[k];
    ln120(xv, g1, b1);
#pragma unroll
    for (int k = 0; k < CC; k++) xv[k] += pr[k];
    for (int j = 0; j < HDIM; j++) {
      const int c = hh * HDIM + j;
      kl[t][j] = dot120(xv, wqkv + (size_t)(CC + c) * CC) + bqkv[CC + c];
      vl[t][j] = dot120(xv, wqkv + (size_t)(2 * CC + c) * CC) + bqkv[2 * CC + c];
    }
  }
  float q[HDIM];
  {
    const float* xr = x + token_src_offset(wi * NTOK + qtok);
#pragma unroll
    for (int k = 0; k < CC; k++) xv[k] = xr[k];
    ln120(xv, g1, b1);
#pragma unroll
    for (int k = 0; k < CC; k++) xv[k] += pr[k];
    for (int j = 0; j < HDIM; j++) {
      const int c = hh * HDIM + j;
      q[j] = (dot120(xv, wqkv + (size_t)c * CC) + bqkv[c]) * SCALE_F;
    }
  }
  __syncthreads();
  const float* mrow = mask + ((size_t)(wi & 255) * NTOK + t) * NTOK;
  float sum = 0.f;
  float o[HDIM];
#pragma unroll
  for (int i = 0; i < HDIM; i++) o[i] = 0.f;
  for (int m = 0; m < 64; m++) {
    float a0 = 0.f, a1 = 0.f, a2 = 0.f, a3 = 0.f;
#pragma unroll
    for (int i = 0; i < HDIM; i += 4) {
      a0 = fmaf(q[i], kl[m][i], a0);
      a1 = fmaf(q[i + 1], kl[m][i + 1], a1);
      a2 = fmaf(q[i + 2], kl[m][i + 2], a2);
      a3 = fmaf(q[i + 3], kl[m][i + 3], a3);
    }
    const float p = __expf((a0 + a1) + (a2 + a3) + mrow[m]);
    sum += p;
#pragma unroll
    for (int i = 0; i < HDIM; i++) o[i] = fmaf(p, vl[m][i], o[i]);
  }
  const float inv = 1.f / sum;
  const int orow_i = which ? 64 + t : t;
  bf16* orow = xout + (size_t)(wi * NTOK + orow_i) * HID2 + hh * HDIM;
#pragma unroll
  for (int i = 0; i < HDIM; i++) orow[i] = __float2bfloat16(o[i] * inv);
}

template <int HALF>
__global__ __launch_bounds__(256) void k_proj_fb(
    const bf16* __restrict__ xout, const float* __restrict__ pw,
    const float* __restrict__ pb, const float* __restrict__ xin,
    float* __restrict__ out) {
  const int token = blockIdx.x * 256 + threadIdx.x;
  float xv[CC];
  const bf16* xr = xout + (size_t)token * HID2 + HALF * CC;
#pragma unroll
  for (int k = 0; k < CC; k++) xv[k] = __bfloat162float(xr[k]);
  const size_t dst = token_src_offset(token);
  for (int o = 0; o < CC; o++) {
    const float acc = dot120(xv, pw + (size_t)o * HID2 + HALF * CC);
    if (HALF == 0)
      out[dst + o] = xin[dst + o] + pb[o] + acc;
    else
      out[dst + o] += acc;
  }
}

__global__ __launch_bounds__(256) void k_ffn1_fb(
    const float* __restrict__ xres, const float* __restrict__ g,
    const float* __restrict__ bb, const float* __restrict__ w11,
    const float* __restrict__ b11, const float* __restrict__ w12,
    const float* __restrict__ b12, bf16* __restrict__ hbuf) {
  const int row = blockIdx.x * 256 + threadIdx.x;
  const float* xr = xres + (size_t)row * CC;
  float xv[CC];
#pragma unroll
  for (int k = 0; k < CC; k++) xv[k] = xr[k];
  ln120(xv, g, bb);
  bf16* hr = hbuf + (size_t)row * HID2;
  for (int o = 0; o < HID2; o++) {
    const float a = b11[o] + dot120(xv, w11 + (size_t)o * CC);
    const float c = b12[o] + dot120(xv, w12 + (size_t)o * CC);
    const float ge = 0.5f * a * (1.f + erff(a * 0.70710678118654752f));
    hr[o] = __float2bfloat16(ge * c);
  }
}

template <int HALF>
__global__ __launch_bounds__(256) void k_ffn2_fb(
    const bf16* __restrict__ hbuf, const float* __restrict__ w2,
    const float* __restrict__ b2f, float* __restrict__ out) {
  const int row = blockIdx.x * 256 + threadIdx.x;
  float xv[CC];
  const bf16* xr = hbuf + (size_t)row * HID2 + HALF * CC;
#pragma unroll
  for (int k = 0; k < CC; k++) xv[k] = __bfloat162float(xr[k]);
  float* orow = out + (size_t)row * CC;
  for (int o = 0; o < CC; o++) {
    float acc = dot120(xv, w2 + (size_t)o * HID2 + HALF * CC);
    if (HALF == 0) acc += b2f[o];
    orow[o] += acc;
  }
}

// ---------------------------------------------------------------------------
extern "C" void kernel_launch(void* const* d_in, const int* in_sizes, int n_in,
                              void* d_out, int out_size, void* d_ws, size_t ws_size,
                              hipStream_t stream) {
  const float* x          = (const float*)d_in[0];
  const float* attn_mask  = (const float*)d_in[1];
  const float* g1         = (const float*)d_in[2];
  const float* b1         = (const float*)d_in[3];
  const float* qkv_self_w = (const float*)d_in[4];
  const float* qkv_self_b = (const float*)d_in[5];
  const float* qkv_mut_w  = (const float*)d_in[6];
  const float* qkv_mut_b  = (const float*)d_in[7];
  const float* proj_w     = (const float*)d_in[8];
  const float* proj_b     = (const float*)d_in[9];
  const float* rpb_table  = (const float*)d_in[10];
  const float* pos_bias   = (const float*)d_in[11];
  const float* g2         = (const float*)d_in[12];
  const float* b2         = (const float*)d_in[13];
  const float* fc11_w     = (const float*)d_in[14];
  const float* fc11_b     = (const float*)d_in[15];
  const float* fc12_w     = (const float*)d_in[16];
  const float* fc12_b     = (const float*)d_in[17];
  const float* fc2_w      = (const float*)d_in[18];
  const float* fc2_b      = (const float*)d_in[19];
  const int*   rpi        = (const int*)d_in[20];
  float* out = (float*)d_out;

  // ws layout (bytes), gate unchanged:
  //   xout  @ 0           : 131072*256*2 = 67,108,864
  //   A1/A2 @ 67,108,864  : 131072*128*2 = 33,554,432
  //   Bffn  @ 100,663,296 : 131,072 ; Bfc2 +65,536 ; Bproj +65,536
  // d_out doubles as scratch until proj overwrites every element:
  //   Wself2 @ 40,000,000 ; Wmut2 @ 40,200,000 ; posqT @ 40,400,000
  //   biasT @ 41,000,000 (393,216) ; maskT @ 41,500,000 (16,777,216)
  //   -> ends 58,277,216 < 62,914,560 (out bytes)
  const bool fast = ws_size >= (size_t)100925440;

  if (fast) {
    bf16* xout  = (bf16*)d_ws;
    bf16* hbuf  = xout;
    bf16* A1    = (bf16*)((char*)d_ws + 67108864);
    bf16* A2    = A1;
    bf16* Bffn  = (bf16*)((char*)d_ws + 100663296);
    bf16* Bfc2  = Bffn + 65536;
    bf16* Bproj = Bfc2 + 32768;

    bf16*  Wself2 = (bf16*)((char*)d_out + 40000000);
    bf16*  Wmut2  = (bf16*)((char*)d_out + 40200000);
    float* posqT  = (float*)((char*)d_out + 40400000);
    float* biasT  = (float*)((char*)d_out + 41000000);
    float* maskT  = (float*)((char*)d_out + 41500000);

    k_prep<<<1088, 256, 0, stream>>>(fc11_w, fc12_w, fc2_w, proj_w,
                                     qkv_self_w, qkv_self_b, qkv_mut_w, qkv_mut_b,
                                     Bffn, Bfc2, Bproj, Wself2, Wmut2);
    k_posqT<<<144, 256, 0, stream>>>(pos_bias, qkv_mut_w, posqT);
    k_biasT<<<384, 256, 0, stream>>>(rpi, rpb_table, biasT);
    k_maskT<<<16384, 256, 0, stream>>>(attn_mask, maskT);
    k_a1<<<512, 256, 0, stream>>>(x, g1, b1, A1);
    k_fattn2<<<2048, 256, 0, stream>>>(A1, Wself2, Wmut2, posqT, biasT, maskT, xout);
    k_proj_ln2<<<dim3(1, 1024), 256, 0, stream>>>(xout, Bproj, proj_b, x, g2, b2, out, A2);
    k_ffn1_mfma<<<dim3(4, 256), 256, 0, stream>>>(A2, Bffn, fc11_b, fc12_b, hbuf);
    k_out_mfma<false><<<dim3(1, 1024), 256, 0, stream>>>(hbuf, Bfc2, fc2_b, nullptr, out);
  } else {
    bf16* xout = (bf16*)d_ws;
    bf16* hbuf = (bf16*)d_ws;
    k_attn_self_fb<<<dim3(1024, NHEADS), 128, 0, stream>>>(
        x, g1, b1, qkv_self_w, qkv_self_b, attn_mask, rpb_table, rpi, xout);
    k_attn_mut_fb<<<dim3(1024, NHEADS, 2), 64, 0, stream>>>(
        x, g1, b1, qkv_mut_w, qkv_mut_b, pos_bias, attn_mask, xout);
    k_proj_fb<0><<<512, 256, 0, stream>>>(xout, proj_w, proj_b, x, out);
    k_proj_fb<1><<<512, 256, 0, stream>>>(xout, proj_w, proj_b, x, out);
    k_ffn1_fb<<<512, 256, 0, stream>>>(out, g2, b2, fc11_w, fc11_b, fc12_w, fc12_b, hbuf);
    k_ffn2_fb<0><<<512, 256, 0, stream>>>(hbuf, fc2_w, fc2_b, out);
    k_ffn2_fb<1><<<512, 256, 0, stream>>>(hbuf, fc2_w, fc2_b, out);
  }
}

// Round 13
// 701.579 us; speedup vs baseline: 1.0710x; 1.0213x over previous
//
#include <hip/hip_runtime.h>
#include <hip/hip_bf16.h>
#include <math.h>

#define CC 120       // channels
#define NHEADS 6
#define HDIM 20      // head dim
#define NTOK 128     // tokens per window
#define HID2 240
#define SCALE_F 0.2236067977499790f  // 20^-0.5

typedef __hip_bfloat16 bf16;
typedef __attribute__((ext_vector_type(8))) short bf16x8;   // 8 bf16 (4 VGPRs)
typedef __attribute__((ext_vector_type(4))) float f32x4;    // MFMA accumulator

__device__ inline f32x4 mfma16(bf16x8 a, bf16x8 b, f32x4 c) {
  return __builtin_amdgcn_mfma_f32_16x16x32_bf16(a, b, c, 0, 0, 0);
}

__device__ inline short f2bf_s(float f) {
  bf16 h = __float2bfloat16(f);
  return *reinterpret_cast<short*>(&h);
}

// LDS-only barrier: order LDS ops across waves WITHOUT draining vmcnt
// (global stores keep flying across phases).
__device__ __forceinline__ void lds_barrier() {
  asm volatile("s_waitcnt lgkmcnt(0)" ::: "memory");
  __builtin_amdgcn_s_barrier();
  asm volatile("" ::: "memory");
}

// ---------------------------------------------------------------------------
// token -> rolled spatial source position (also the scatter destination for
// window-reverse + un-roll, which is the same map).
__device__ inline size_t token_src_offset(int token) {
  const int wi = token >> 7, n = token & 127;
  const int b_ = wi >> 8, rem = wi & 255;
  const int dB = rem >> 6, hB = (rem >> 3) & 7, wB = rem & 7;
  const int dI = n >> 6, hI = (n >> 3) & 7, wI = n & 7;
  const int d = dB * 2 + dI, h = hB * 8 + hI, w = wB * 8 + wI;
  const int ds = (d + 1) & 7, hs = (h + 4) & 63, ws2 = (w + 4) & 63;
  return (((size_t)(b_ * 8 + ds) * 64 + hs) * 64 + ws2) * CC;
}

__device__ inline void ln120(float* xv, const float* __restrict__ g,
                             const float* __restrict__ bb) {
  float s0 = 0.f, s1 = 0.f, s2 = 0.f, s3 = 0.f;
#pragma unroll
  for (int k = 0; k < CC; k += 4) {
    s0 += xv[k]; s1 += xv[k + 1]; s2 += xv[k + 2]; s3 += xv[k + 3];
  }
  const float mean = ((s0 + s1) + (s2 + s3)) * (1.f / 120.f);
  float v0 = 0.f, v1 = 0.f, v2 = 0.f, v3 = 0.f;
#pragma unroll
  for (int k = 0; k < CC; k += 4) {
    float d0 = xv[k] - mean, d1 = xv[k + 1] - mean;
    float d2 = xv[k + 2] - mean, d3 = xv[k + 3] - mean;
    v0 += d0 * d0; v1 += d1 * d1; v2 += d2 * d2; v3 += d3 * d3;
  }
  const float rstd = rsqrtf(((v0 + v1) + (v2 + v3)) * (1.f / 120.f) + 1e-5f);
#pragma unroll
  for (int k = 0; k < CC; k++) xv[k] = (xv[k] - mean) * rstd * g[k] + bb[k];
}

__device__ inline float dot120(const float* xv, const float* __restrict__ wr) {
  float a0 = 0.f, a1 = 0.f, a2 = 0.f, a3 = 0.f;
#pragma unroll
  for (int k = 0; k < CC; k += 4) {
    a0 = fmaf(xv[k], wr[k], a0);
    a1 = fmaf(xv[k + 1], wr[k + 1], a1);
    a2 = fmaf(xv[k + 2], wr[k + 2], a2);
    a3 = fmaf(xv[k + 3], wr[k + 3], a3);
  }
  return (a0 + a1) + (a2 + a3);
}

// ===========================================================================
// FAST PATH
// ===========================================================================
// Weight prep.
//  Bffn [512][128]: rows 0..239 = W11, 256..495 = W12 (K pad, bias separate)
//  Bfc2 [128][256], Bproj [128][256]
//  Wself2/Wmut2 [576][128]: rows 0..191 q (heads padded to 32, SCALE folded),
//    192..383 k, 384..575 v. col 120 = bias (A1 col120 == 1), pads 0.
//    v-row pad chan 20 = e120 (=> V col 20 == 1.0: PV computes softmax rowsum).
__global__ __launch_bounds__(256) void k_prep(
    const float* __restrict__ w11, const float* __restrict__ w12,
    const float* __restrict__ fc2w, const float* __restrict__ projw,
    const float* __restrict__ wself, const float* __restrict__ bself,
    const float* __restrict__ wmut, const float* __restrict__ bmut,
    bf16* __restrict__ Bffn, bf16* __restrict__ Bfc2, bf16* __restrict__ Bproj,
    bf16* __restrict__ Wself2, bf16* __restrict__ Wmut2) {
  const int i = blockIdx.x * 256 + threadIdx.x;
  if (i < 65536) {
    const int r = i >> 7, k = i & 127;
    float v = 0.f;
    if (k < 120) {
      if (r < 240) v = w11[r * 120 + k];
      else if (r >= 256 && r < 496) v = w12[(r - 256) * 120 + k];
    }
    Bffn[i] = __float2bfloat16(v);
  } else if (i < 98304) {
    const int j = i - 65536, r = j >> 8, k = j & 255;
    Bfc2[j] = __float2bfloat16((r < 120 && k < 240) ? fc2w[r * 240 + k] : 0.f);
  } else if (i < 131072) {
    const int j = i - 98304, r = j >> 8, k = j & 255;
    Bproj[j] = __float2bfloat16((r < 120 && k < 240) ? projw[r * 240 + k] : 0.f);
  } else if (i < 278528) {
    const int j = (i - 131072) % 73728;
    const bool is_self = (i - 131072) < 73728;
    const float* w = is_self ? wself : wmut;
    const float* b = is_self ? bself : bmut;
    const int r = j >> 7, k = j & 127;
    const int grp = r / 192;              // 0=q 1=k 2=v
    const int rr = r % 192;
    const int hh = rr >> 5, jj = rr & 31;
    float v = 0.f;
    if (jj < 20) {
      const int orow = grp * 120 + hh * 20 + jj;
      if (k < 120) v = w[orow * 120 + k];
      else if (k == 120) v = b[orow];
      if (grp == 0) v *= SCALE_F;
    } else if (grp == 2 && jj == 20 && k == 120) {
      v = 1.0f;                           // rowsum column
    }
    (is_self ? Wself2 : Wmut2)[j] = __float2bfloat16(v);
  }
}

// posqT[c][t63] = dot(pos[t63], W'_c over real channels); SCALE on q cols.
// TRANSPOSED so the QKV phase can f32x4-load 4 consecutive token rows
// (matching the MFMA C/D row layout quad*4+r).
__global__ __launch_bounds__(256) void k_posqT(
    const float* __restrict__ pos, const float* __restrict__ wmut,
    float* __restrict__ posqT) {
  const int i = blockIdx.x * 256 + threadIdx.x;
  if (i >= 576 * 64) return;
  const int c = i >> 6, t63 = i & 63;
  const int grp = c / 192, rr = c % 192;
  const int hh = rr >> 5, jj = rr & 31;
  float v = 0.f;
  if (jj < 20) {
    v = dot120(pos + (size_t)t63 * CC, wmut + (size_t)(grp * 120 + hh * 20 + jj) * CC);
    if (grp == 0) v *= SCALE_F;
  }
  posqT[i] = v;   // i == c*64 + t63
}

// biasT[h][col][row] = rpb[rpi[row,col]*6+h]  (TRANSPOSED rel-pos bias, fp32)
__global__ __launch_bounds__(256) void k_biasT(
    const int* __restrict__ rpi, const float* __restrict__ rpb,
    float* __restrict__ biasT) {
  const int i = blockIdx.x * 256 + threadIdx.x;
  if (i >= NHEADS * 16384) return;
  const int h = i >> 14, rc = i & 16383;
  const int col = rc >> 7, row = rc & 127;
  biasT[i] = rpb[rpi[row * 128 + col] * NHEADS + h];
}

// maskT[wc][col][row] = mask[wc][row][col]  (fp32, 16.8 MB). Coalesced writes.
__global__ __launch_bounds__(256) void k_maskT(
    const float* __restrict__ mask, float* __restrict__ maskT) {
  const int i = blockIdx.x * 256 + threadIdx.x;
  const int wc = i >> 14, rc = i & 16383;
  const int col = rc >> 7, row = rc & 127;
  maskT[i] = mask[(size_t)wc * 16384 + row * 128 + col];
}

// LN1 + roll + partition -> A1 bf16 [131072][128], col 120 = 1.0 (bias col).
__global__ __launch_bounds__(256) void k_a1(
    const float* __restrict__ x, const float* __restrict__ g1,
    const float* __restrict__ b1, bf16* __restrict__ A1) {
  const int token = blockIdx.x * 256 + threadIdx.x;
  const float4* xr4 = (const float4*)(x + token_src_offset(token));
  float xv[CC];
#pragma unroll
  for (int k = 0; k < 30; k++) {
    const float4 v = xr4[k];
    xv[k * 4] = v.x; xv[k * 4 + 1] = v.y; xv[k * 4 + 2] = v.z; xv[k * 4 + 3] = v.w;
  }
  ln120(xv, g1, b1);
  bf16x8* dst8 = (bf16x8*)(A1 + (size_t)token * 128);
#pragma unroll
  for (int k = 0; k < 15; k++) {
    bf16x8 v;
#pragma unroll
    for (int j = 0; j < 8; j++) v[j] = f2bf_s(xv[k * 8 + j]);
    dst8[k] = v;
  }
  bf16x8 tail = {0, 0, 0, 0, 0, 0, 0, 0};
  tail[0] = f2bf_s(1.0f);
  dst8[15] = tail;
}

// ---------------------------------------------------------------------------
// FUSED QKV + attention (Round-3 measured-best structure).
template <bool MUT>
__device__ __forceinline__ void fattn_body(
    const int wi, const bf16* __restrict__ A1, const bf16* __restrict__ W2,
    const float* __restrict__ posqT, const float* __restrict__ biasT,
    const float* __restrict__ maskT, bf16* __restrict__ xout,
    bf16* kS, bf16* vS, bf16* qP) {
  const int w = threadIdx.x >> 6, lane = threadIdx.x & 63;
  const int ln = lane & 15, quad = lane >> 4;
  // A-fragments for this wave's 32 rows (reused across 6 heads x 3 groups)
  bf16x8 af[2][4];
#pragma unroll
  for (int mi = 0; mi < 2; mi++)
#pragma unroll
    for (int s = 0; s < 4; s++)
      af[mi][s] = *(const bf16x8*)(A1 + (size_t)(wi * NTOK + w * 32 + mi * 16 + ln) * 128 + s * 32 + quad * 8);
  const int wc = wi & 255;
  // window crosses the roll boundary iff any block index is the last one
  const bool hasmask = ((wc >> 6) == 3) || (((wc >> 3) & 7) == 7) || ((wc & 7) == 7);
  const float* maskTb = maskT + (size_t)wc * 16384;

  for (int hh = 0; hh < NHEADS; hh++) {
    // ---- QKV phase: group g = 0(q) 1(k) 2(v) ----
#pragma unroll
    for (int g = 0; g < 3; g++) {
      bf16x8 bfr[2][4];
#pragma unroll
      for (int nt = 0; nt < 2; nt++)
#pragma unroll
        for (int s = 0; s < 4; s++)
          bfr[nt][s] = *(const bf16x8*)(W2 + (size_t)(g * 192 + hh * 32 + nt * 16 + ln) * 128 + s * 32 + quad * 8);
      f32x4 acc[2][2] = {};
#pragma unroll
      for (int s = 0; s < 4; s++)
#pragma unroll
        for (int mi = 0; mi < 2; mi++)
#pragma unroll
          for (int nt = 0; nt < 2; nt++)
            acc[mi][nt] = mfma16(af[mi][s], bfr[nt][s], acc[mi][nt]);
      if (MUT) {
#pragma unroll
        for (int mi = 0; mi < 2; mi++)
#pragma unroll
          for (int nt = 0; nt < 2; nt++) {
            const f32x4 pq = *(const f32x4*)&posqT[
                (size_t)(g * 192 + hh * 32 + nt * 16 + ln) * 64 +
                ((w * 32 + mi * 16 + quad * 4) & 63)];
            acc[mi][nt] += pq;
          }
      }
#pragma unroll
      for (int mi = 0; mi < 2; mi++)
#pragma unroll
        for (int nt = 0; nt < 2; nt++)
#pragma unroll
          for (int r = 0; r < 4; r++) {
            const int lrow = w * 32 + mi * 16 + quad * 4 + r;
            const short bv = f2bf_s(acc[mi][nt][r]);
            if (g == 0)      *(short*)&qP[lrow * 40 + nt * 16 + ln] = bv;
            else if (g == 1) *(short*)&kS[lrow * 40 + nt * 16 + ln] = bv;
            else             *(short*)&vS[(nt * 16 + ln) * 136 + lrow] = bv;
          }
    }
    lds_barrier();
    // ---- attention phase ----
    bf16x8 qf[2];
#pragma unroll
    for (int i = 0; i < 2; i++)
      qf[i] = *(const bf16x8*)(&qP[(w * 32 + i * 16 + ln) * 40 + quad * 8]);
    f32x4 accO[2][2];
#pragma unroll
    for (int i = 0; i < 2; i++)
#pragma unroll
      for (int nt = 0; nt < 2; nt++) accO[i][nt] = (f32x4){0.f, 0.f, 0.f, 0.f};
    const int kb = MUT ? ((w < 2) ? 64 : 0) : 0;
    const int nchunk = MUT ? 2 : 4;
    for (int chunk = 0; chunk < nchunk; chunk++) {
      const int key0 = kb + chunk * 32;
      bf16x8 kf[2], vf[2];
      kf[0] = *(const bf16x8*)(&kS[(key0 + ln) * 40 + quad * 8]);
      kf[1] = *(const bf16x8*)(&kS[(key0 + 16 + ln) * 40 + quad * 8]);
      vf[0] = *(const bf16x8*)(&vS[ln * 136 + key0 + quad * 8]);
      vf[1] = *(const bf16x8*)(&vS[(16 + ln) * 136 + key0 + quad * 8]);
#pragma unroll
      for (int i = 0; i < 2; i++) {
        const int rb = w * 32 + i * 16 + quad * 4;
        f32x4 c0, c1;
        if (MUT) {
          if (hasmask) {
            c0 = *(const f32x4*)&maskTb[(chunk * 32 + ln) * 128 + (rb & 63)];
            c1 = *(const f32x4*)&maskTb[(chunk * 32 + 16 + ln) * 128 + (rb & 63)];
          } else {
            c0 = (f32x4){0.f, 0.f, 0.f, 0.f};
            c1 = (f32x4){0.f, 0.f, 0.f, 0.f};
          }
        } else {
          c0 = *(const f32x4*)&biasT[(size_t)hh * 16384 + (key0 + ln) * 128 + rb];
          c1 = *(const f32x4*)&biasT[(size_t)hh * 16384 + (key0 + 16 + ln) * 128 + rb];
          if (hasmask) {
            c0 += *(const f32x4*)&maskTb[(key0 + ln) * 128 + rb];
            c1 += *(const f32x4*)&maskTb[(key0 + 16 + ln) * 128 + rb];
          }
        }
        const f32x4 s0 = mfma16(qf[i], kf[0], c0);
        const f32x4 s1 = mfma16(qf[i], kf[1], c1);
#pragma unroll
        for (int r = 0; r < 4; r++) {
          const int row = rb + r;
          *(short*)&qP[row * 40 + ln] = f2bf_s(__expf(s0[r]));
          *(short*)&qP[row * 40 + 16 + ln] = f2bf_s(__expf(s1[r]));
        }
      }
#pragma unroll
      for (int i = 0; i < 2; i++) {
        bf16x8 pf = *(const bf16x8*)(&qP[(w * 32 + i * 16 + ln) * 40 + quad * 8]);
        accO[i][0] = mfma16(pf, vf[0], accO[i][0]);
        accO[i][1] = mfma16(pf, vf[1], accO[i][1]);
      }
    }
    // ---- epilogue: rowsum (V pad col 20) + normalize + write ----
#pragma unroll
    for (int i = 0; i < 2; i++) {
#pragma unroll
      for (int r = 0; r < 4; r++) {
        const float rs = __shfl(accO[i][1][r], (lane & 48) + 4, 64);
        const float inv = 1.f / rs;
        const int row = w * 32 + i * 16 + quad * 4 + r;
        const int orow_i = MUT ? ((w < 2) ? 64 + row : row - 64) : row;
        const int token = wi * NTOK + orow_i;
        bf16* orow = xout + (size_t)token * 256 + (MUT ? 0 : CC) + hh * HDIM;
        orow[ln] = __float2bfloat16(accO[i][0][r] * inv);
        if (ln < 4) orow[16 + ln] = __float2bfloat16(accO[i][1][r] * inv);
      }
    }
    lds_barrier();   // protect kS/vS/qP before next head's QKV overwrite
  }
}

// Merged self+mut launch: blocks 0..1023 self, 1024..2047 mut. (R3 measured best.)
__global__ __launch_bounds__(256, 4) void k_fattn2(
    const bf16* __restrict__ A1, const bf16* __restrict__ Wself2,
    const bf16* __restrict__ Wmut2, const float* __restrict__ posqT,
    const float* __restrict__ biasT, const float* __restrict__ maskT,
    bf16* __restrict__ xout) {
  __shared__ bf16 kS[128 * 40];
  __shared__ bf16 vS[32 * 136];
  __shared__ bf16 qP[128 * 40];   // q staging, then P
  if (blockIdx.x < 1024)
    fattn_body<false>(blockIdx.x, A1, Wself2, nullptr, biasT, maskT, xout, kS, vS, qP);
  else
    fattn_body<true>(blockIdx.x - 1024, A1, Wmut2, posqT, biasT, maskT, xout, kS, vS, qP);
}

// LN2 -> bf16 A-matrix [131072][128]. float4 loads + bf16x8 stores. (R3 verbatim.)
__global__ __launch_bounds__(256) void k_ln2(
    const float* __restrict__ out, const float* __restrict__ g2,
    const float* __restrict__ b2, bf16* __restrict__ A2) {
  const int row = blockIdx.x * 256 + threadIdx.x;
  const float4* xr4 = (const float4*)(out + (size_t)row * CC);
  float xv[CC];
#pragma unroll
  for (int k = 0; k < 30; k++) {
    const float4 v = xr4[k];
    xv[k * 4] = v.x; xv[k * 4 + 1] = v.y; xv[k * 4 + 2] = v.z; xv[k * 4 + 3] = v.w;
  }
  ln120(xv, g2, b2);
  bf16x8* dst8 = (bf16x8*)(A2 + (size_t)row * 128);
#pragma unroll
  for (int k = 0; k < 15; k++) {
    bf16x8 v;
#pragma unroll
    for (int j = 0; j < 8; j++) v[j] = f2bf_s(xv[k * 8 + j]);
    dst8[k] = v;
  }
  bf16x8 tail = {0, 0, 0, 0, 0, 0, 0, 0};
  dst8[15] = tail;
}

// Output GEMM, K=256 (padded), N=120. grid (1, 1024). PROJ path (R3 verbatim).
template <bool PROJ>
__global__ __launch_bounds__(256) void k_out_mfma(
    const bf16* __restrict__ A, const bf16* __restrict__ Bw,
    const float* __restrict__ bias, const float* __restrict__ xin,
    float* __restrict__ out) {
  const int w = threadIdx.x >> 6;
  const int lane = threadIdx.x & 63;
  const int ln = lane & 15, quad = lane >> 4;
  bf16x8 bfr[2][8];
#pragma unroll
  for (int nt = 0; nt < 2; nt++)
#pragma unroll
    for (int s = 0; s < 8; s++)
      bfr[nt][s] = *(const bf16x8*)(Bw + (size_t)((w * 2 + nt) * 16 + ln) * 256 + s * 32 + quad * 8);
  const int m_base = blockIdx.y * 128;
  for (int it = 0; it < 4; it++) {
    const int m0 = m_base + it * 32;
    f32x4 acc[2][2] = {};
    bf16x8 af[2][8];
#pragma unroll
    for (int mi = 0; mi < 2; mi++)
#pragma unroll
      for (int s = 0; s < 8; s++)
        af[mi][s] = *(const bf16x8*)(A + (size_t)(m0 + mi * 16 + ln) * 256 + s * 32 + quad * 8);
#pragma unroll
    for (int s = 0; s < 8; s++)
#pragma unroll
      for (int mi = 0; mi < 2; mi++)
#pragma unroll
        for (int nt = 0; nt < 2; nt++)
          acc[mi][nt] = mfma16(af[mi][s], bfr[nt][s], acc[mi][nt]);
#pragma unroll
    for (int mi = 0; mi < 2; mi++)
#pragma unroll
      for (int nt = 0; nt < 2; nt++) {
        const int colc = (w * 2 + nt) * 16 + ln;
        if (colc < CC) {
#pragma unroll
          for (int r = 0; r < 4; r++) {
            const int row = m0 + mi * 16 + quad * 4 + r;
            if (PROJ) {
              const size_t dst = token_src_offset(row);
              out[dst + colc] = xin[dst + colc] + bias[colc] + acc[mi][nt][r];
            } else {
              out[(size_t)row * CC + colc] += bias[colc] + acc[mi][nt][r];
            }
          }
        }
      }
  }
}

// ---------------------------------------------------------------------------
// FUSED FFN: per block, 32 token rows. Phase 1: h = gelu(A2@W11^T)*(A2@W12^T)
// into LDS (240 cols, K-pad 256 is zero-weighted). ONE barrier. Phase 2:
// out += h @ fc2^T + bias, A-fragments read from LDS (+8 pad -> 2-way banks).
// Kills the 134 MB h round-trip to HBM; Bffn/Bfc2 (187 KB) stay L2-resident.
__global__ __launch_bounds__(256) void k_ffn_fused(
    const bf16* __restrict__ A2, const bf16* __restrict__ Bffn,
    const bf16* __restrict__ Bfc2, const float* __restrict__ b11,
    const float* __restrict__ b12, const float* __restrict__ fc2b,
    float* __restrict__ out) {
  __shared__ bf16 hS[32][264];
  const int w = threadIdx.x >> 6;
  const int lane = threadIdx.x & 63;
  const int ln = lane & 15, quad = lane >> 4;
  const int m0 = blockIdx.x * 32;
  // ---- phase 1: FFN1, wave w owns cols w*64 .. w*64+63 ----
  bf16x8 af[2][4];
#pragma unroll
  for (int mi = 0; mi < 2; mi++)
#pragma unroll
    for (int s = 0; s < 4; s++)
      af[mi][s] = *(const bf16x8*)(A2 + (size_t)(m0 + mi * 16 + ln) * 128 + s * 32 + quad * 8);
#pragma unroll
  for (int nt = 0; nt < 4; nt++) {
    const int col = w * 64 + nt * 16 + ln;
    bf16x8 b1f[4], b2f[4];
#pragma unroll
    for (int s = 0; s < 4; s++) {
      b1f[s] = *(const bf16x8*)(Bffn + (size_t)col * 128 + s * 32 + quad * 8);
      b2f[s] = *(const bf16x8*)(Bffn + (size_t)(256 + col) * 128 + s * 32 + quad * 8);
    }
    f32x4 acc1[2] = {}, acc2[2] = {};
#pragma unroll
    for (int s = 0; s < 4; s++)
#pragma unroll
      for (int mi = 0; mi < 2; mi++) {
        acc1[mi] = mfma16(af[mi][s], b1f[s], acc1[mi]);
        acc2[mi] = mfma16(af[mi][s], b2f[s], acc2[mi]);
      }
    const float bias1 = (col < HID2) ? b11[col] : 0.f;
    const float bias2 = (col < HID2) ? b12[col] : 0.f;
#pragma unroll
    for (int mi = 0; mi < 2; mi++)
#pragma unroll
      for (int r = 0; r < 4; r++) {
        const int row = mi * 16 + quad * 4 + r;
        const float a = acc1[mi][r] + bias1;
        const float c = acc2[mi][r] + bias2;
        const float ge = 0.5f * a * (1.f + erff(a * 0.70710678118654752f));
        hS[row][col] = __float2bfloat16(ge * c);
      }
  }
  lds_barrier();
  // ---- phase 2: FFN2 (K = 256, cols 240..255 of hS are zero-weighted) ----
  bf16x8 bfr[2][8];
#pragma unroll
  for (int nt = 0; nt < 2; nt++)
#pragma unroll
    for (int s = 0; s < 8; s++)
      bfr[nt][s] = *(const bf16x8*)(Bfc2 + (size_t)((w * 2 + nt) * 16 + ln) * 256 + s * 32 + quad * 8);
  bf16x8 af2[2][8];
#pragma unroll
  for (int mi = 0; mi < 2; mi++)
#pragma unroll
    for (int s = 0; s < 8; s++)
      af2[mi][s] = *(const bf16x8*)(&hS[mi * 16 + ln][s * 32 + quad * 8]);
  f32x4 acc[2][2] = {};
#pragma unroll
  for (int s = 0; s < 8; s++)
#pragma unroll
    for (int mi = 0; mi < 2; mi++)
#pragma unroll
      for (int nt = 0; nt < 2; nt++)
        acc[mi][nt] = mfma16(af2[mi][s], bfr[nt][s], acc[mi][nt]);
#pragma unroll
  for (int mi = 0; mi < 2; mi++)
#pragma unroll
    for (int nt = 0; nt < 2; nt++) {
      const int colc = (w * 2 + nt) * 16 + ln;
      if (colc < CC) {
#pragma unroll
        for (int r = 0; r < 4; r++) {
          const int row = m0 + mi * 16 + quad * 4 + r;
          out[(size_t)row * CC + colc] += fc2b[colc] + acc[mi][nt][r];
        }
      }
    }
}

// ===========================================================================
// FALLBACK PATH (round-2 proven kernels; used only if ws is too small)
// ===========================================================================
__global__ __launch_bounds__(128) void k_attn_self_fb(
    const float* __restrict__ x, const float* __restrict__ g1,
    const float* __restrict__ b1, const float* __restrict__ wqkv,
    const float* __restrict__ bqkv, const float* __restrict__ mask,
    const float* __restrict__ rpb, const int* __restrict__ rpi,
    bf16* __restrict__ xout) {
  __shared__ float kl[NTOK][HDIM];
  __shared__ float vl[NTOK][HDIM];
  const int wi = blockIdx.x, hh = blockIdx.y, t = threadIdx.x;
  const int token = wi * NTOK + t;
  const float* xr = x + token_src_offset(token);
  float xv[CC];
#pragma unroll
  for (int k = 0; k < CC; k++) xv[k] = xr[k];
  ln120(xv, g1, b1);
  float q[HDIM];
  for (int j = 0; j < HDIM; j++) {
    const int c = hh * HDIM + j;
    q[j] = (dot120(xv, wqkv + (size_t)c * CC) + bqkv[c]) * SCALE_F;
    kl[t][j] = dot120(xv, wqkv + (size_t)(CC + c) * CC) + bqkv[CC + c];
    vl[t][j] = dot120(xv, wqkv + (size_t)(2 * CC + c) * CC) + bqkv[2 * CC + c];
  }
  __syncthreads();
  const float* mrow = mask + ((size_t)(wi & 255) * NTOK + t) * NTOK;
  const int* rrow = rpi + t * NTOK;
  float sum = 0.f;
  float o[HDIM];
#pragma unroll
  for (int i = 0; i < HDIM; i++) o[i] = 0.f;
  for (int m = 0; m < NTOK; m++) {
    float a0 = 0.f, a1 = 0.f, a2 = 0.f, a3 = 0.f;
#pragma unroll
    for (int i = 0; i < HDIM; i += 4) {
      a0 = fmaf(q[i], kl[m][i], a0);
      a1 = fmaf(q[i + 1], kl[m][i + 1], a1);
      a2 = fmaf(q[i + 2], kl[m][i + 2], a2);
      a3 = fmaf(q[i + 3], kl[m][i + 3], a3);
    }
    const float sc = (a0 + a1) + (a2 + a3) + rpb[rrow[m] * NHEADS + hh] + mrow[m];
    const float p = __expf(sc);
    sum += p;
#pragma unroll
    for (int i = 0; i < HDIM; i++) o[i] = fmaf(p, vl[m][i], o[i]);
  }
  const float inv = 1.f / sum;
  bf16* orow = xout + (size_t)token * HID2 + CC + hh * HDIM;
#pragma unroll
  for (int i = 0; i < HDIM; i++) orow[i] = __float2bfloat16(o[i] * inv);
}

__global__ __launch_bounds__(64) void k_attn_mut_fb(
    const float* __restrict__ x, const float* __restrict__ g1,
    const float* __restrict__ b1, const float* __restrict__ wqkv,
    const float* __restrict__ bqkv, const float* __restrict__ pos,
    const float* __restrict__ mask, bf16* __restrict__ xout) {
  __shared__ float kl[64][HDIM];
  __shared__ float vl[64][HDIM];
  const int wi = blockIdx.x, hh = blockIdx.y, which = blockIdx.z;
  const int t = threadIdx.x;
  const int qtok = which ? t : 64 + t;
  const int ktok = which ? 64 + t : t;
  const float* pr = pos + (size_t)t * CC;
  float xv[CC];
  {
    const float* xr = x + token_src_offset(wi * NTOK + ktok);
#pragma unroll
    for (int k = 0; k < CC; k++) xv[k] = xr[k];
    ln120(xv, g1, b1);
#pragma unroll
    for (int k = 0; k < CC; k++) xv[k] += pr[k];
    for (int j = 0; j < HDIM; j++) {
      const int c = hh * HDIM + j;
      kl[t][j] = dot120(xv, wqkv + (size_t)(CC + c) * CC) + bqkv[CC + c];
      vl[t][j] = dot120(xv, wqkv + (size_t)(2 * CC + c) * CC) + bqkv[2 * CC + c];
    }
  }
  float q[HDIM];
  {
    const float* xr = x + token_src_offset(wi * NTOK + qtok);
#pragma unroll
    for (int k = 0; k < CC; k++) xv[k] = xr[k];
    ln120(xv, g1, b1);
#pragma unroll
    for (int k = 0; k < CC; k++) xv[k] += pr[k];
    for (int j = 0; j < HDIM; j++) {
      const int c = hh * HDIM + j;
      q[j] = (dot120(xv, wqkv + (size_t)c * CC) + bqkv[c]) * SCALE_F;
    }
  }
  __syncthreads();
  const float* mrow = mask + ((size_t)(wi & 255) * NTOK + t) * NTOK;
  float sum = 0.f;
  float o[HDIM];
#pragma unroll
  for (int i = 0; i < HDIM; i++) o[i] = 0.f;
  for (int m = 0; m < 64; m++) {
    float a0 = 0.f, a1 = 0.f, a2 = 0.f, a3 = 0.f;
#pragma unroll
    for (int i = 0; i < HDIM; i += 4) {
      a0 = fmaf(q[i], kl[m][i], a0);
      a1 = fmaf(q[i + 1], kl[m][i + 1], a1);
      a2 = fmaf(q[i + 2], kl[m][i + 2], a2);
      a3 = fmaf(q[i + 3], kl[m][i + 3], a3);
    }
    const float p = __expf((a0 + a1) + (a2 + a3) + mrow[m]);
    sum += p;
#pragma unroll
    for (int i = 0; i < HDIM; i++) o[i] = fmaf(p, vl[m][i], o[i]);
  }
  const float inv = 1.f / sum;
  const int orow_i = which ? 64 + t : t;
  bf16* orow = xout + (size_t)(wi * NTOK + orow_i) * HID2 + hh * HDIM;
#pragma unroll
  for (int i = 0; i < HDIM; i++) orow[i] = __float2bfloat16(o[i] * inv);
}

template <int HALF>
__global__ __launch_bounds__(256) void k_proj_fb(
    const bf16* __restrict__ xout, const float* __restrict__ pw,
    const float* __restrict__ pb, const float* __restrict__ xin,
    float* __restrict__ out) {
  const int token = blockIdx.x * 256 + threadIdx.x;
  float xv[CC];
  const bf16* xr = xout + (size_t)token * HID2 + HALF * CC;
#pragma unroll
  for (int k = 0; k < CC; k++) xv[k] = __bfloat162float(xr[k]);
  const size_t dst = token_src_offset(token);
  for (int o = 0; o < CC; o++) {
    const float acc = dot120(xv, pw + (size_t)o * HID2 + HALF * CC);
    if (HALF == 0)
      out[dst + o] = xin[dst + o] + pb[o] + acc;
    else
      out[dst + o] += acc;
  }
}

__global__ __launch_bounds__(256) void k_ffn1_fb(
    const float* __restrict__ xres, const float* __restrict__ g,
    const float* __restrict__ bb, const float* __restrict__ w11,
    const float* __restrict__ b11, const float* __restrict__ w12,
    const float* __restrict__ b12, bf16* __restrict__ hbuf) {
  const int row = blockIdx.x * 256 + threadIdx.x;
  const float* xr = xres + (size_t)row * CC;
  float xv[CC];
#pragma unroll
  for (int k = 0; k < CC; k++) xv[k] = xr[k];
  ln120(xv, g, bb);
  bf16* hr = hbuf + (size_t)row * HID2;
  for (int o = 0; o < HID2; o++) {
    const float a = b11[o] + dot120(xv, w11 + (size_t)o * CC);
    const float c = b12[o] + dot120(xv, w12 + (size_t)o * CC);
    const float ge = 0.5f * a * (1.f + erff(a * 0.70710678118654752f));
    hr[o] = __float2bfloat16(ge * c);
  }
}

template <int HALF>
__global__ __launch_bounds__(256) void k_ffn2_fb(
    const bf16* __restrict__ hbuf, const float* __restrict__ w2,
    const float* __restrict__ b2f, float* __restrict__ out) {
  const int row = blockIdx.x * 256 + threadIdx.x;
  float xv[CC];
  const bf16* xr = hbuf + (size_t)row * HID2 + HALF * CC;
#pragma unroll
  for (int k = 0; k < CC; k++) xv[k] = __bfloat162float(xr[k]);
  float* orow = out + (size_t)row * CC;
  for (int o = 0; o < CC; o++) {
    float acc = dot120(xv, w2 + (size_t)o * HID2 + HALF * CC);
    if (HALF == 0) acc += b2f[o];
    orow[o] += acc;
  }
}

// ---------------------------------------------------------------------------
extern "C" void kernel_launch(void* const* d_in, const int* in_sizes, int n_in,
                              void* d_out, int out_size, void* d_ws, size_t ws_size,
                              hipStream_t stream) {
  const float* x          = (const float*)d_in[0];
  const float* attn_mask  = (const float*)d_in[1];
  const float* g1         = (const float*)d_in[2];
  const float* b1         = (const float*)d_in[3];
  const float* qkv_self_w = (const float*)d_in[4];
  const float* qkv_self_b = (const float*)d_in[5];
  const float* qkv_mut_w  = (const float*)d_in[6];
  const float* qkv_mut_b  = (const float*)d_in[7];
  const float* proj_w     = (const float*)d_in[8];
  const float* proj_b     = (const float*)d_in[9];
  const float* rpb_table  = (const float*)d_in[10];
  const float* pos_bias   = (const float*)d_in[11];
  const float* g2         = (const float*)d_in[12];
  const float* b2         = (const float*)d_in[13];
  const float* fc11_w     = (const float*)d_in[14];
  const float* fc11_b     = (const float*)d_in[15];
  const float* fc12_w     = (const float*)d_in[16];
  const float* fc12_b     = (const float*)d_in[17];
  const float* fc2_w      = (const float*)d_in[18];
  const float* fc2_b      = (const float*)d_in[19];
  const int*   rpi        = (const int*)d_in[20];
  float* out = (float*)d_out;

  // ws layout (bytes), gate unchanged:
  //   xout  @ 0           : 131072*256*2 = 67,108,864
  //   A1/A2 @ 67,108,864  : 131072*128*2 = 33,554,432
  //   Bffn  @ 100,663,296 : 131,072 ; Bfc2 +65,536 ; Bproj +65,536
  // d_out doubles as scratch until proj overwrites every element:
  //   Wself2 @ 40,000,000 ; Wmut2 @ 40,200,000 ; posqT @ 40,400,000
  //   biasT @ 41,000,000 (393,216) ; maskT @ 41,500,000 (16,777,216)
  //   -> ends 58,277,216 < 62,914,560 (out bytes)
  const bool fast = ws_size >= (size_t)100925440;

  if (fast) {
    bf16* xout  = (bf16*)d_ws;
    bf16* A1    = (bf16*)((char*)d_ws + 67108864);
    bf16* A2    = A1;
    bf16* Bffn  = (bf16*)((char*)d_ws + 100663296);
    bf16* Bfc2  = Bffn + 65536;
    bf16* Bproj = Bfc2 + 32768;

    bf16*  Wself2 = (bf16*)((char*)d_out + 40000000);
    bf16*  Wmut2  = (bf16*)((char*)d_out + 40200000);
    float* posqT  = (float*)((char*)d_out + 40400000);
    float* biasT  = (float*)((char*)d_out + 41000000);
    float* maskT  = (float*)((char*)d_out + 41500000);

    k_prep<<<1088, 256, 0, stream>>>(fc11_w, fc12_w, fc2_w, proj_w,
                                     qkv_self_w, qkv_self_b, qkv_mut_w, qkv_mut_b,
                                     Bffn, Bfc2, Bproj, Wself2, Wmut2);
    k_posqT<<<144, 256, 0, stream>>>(pos_bias, qkv_mut_w, posqT);
    k_biasT<<<384, 256, 0, stream>>>(rpi, rpb_table, biasT);
    k_maskT<<<16384, 256, 0, stream>>>(attn_mask, maskT);
    k_a1<<<512, 256, 0, stream>>>(x, g1, b1, A1);
    k_fattn2<<<2048, 256, 0, stream>>>(A1, Wself2, Wmut2, posqT, biasT, maskT, xout);
    k_out_mfma<true><<<dim3(1, 1024), 256, 0, stream>>>(xout, Bproj, proj_b, x, out);
    k_ln2<<<512, 256, 0, stream>>>(out, g2, b2, A2);
    k_ffn_fused<<<4096, 256, 0, stream>>>(A2, Bffn, Bfc2, fc11_b, fc12_b, fc2_b, out);
  } else {
    bf16* xout = (bf16*)d_ws;
    bf16* hbuf = (bf16*)d_ws;
    k_attn_self_fb<<<dim3(1024, NHEADS), 128, 0, stream>>>(
        x, g1, b1, qkv_self_w, qkv_self_b, attn_mask, rpb_table, rpi, xout);
    k_attn_mut_fb<<<dim3(1024, NHEADS, 2), 64, 0, stream>>>(
        x, g1, b1, qkv_mut_w, qkv_mut_b, pos_bias, attn_mask, xout);
    k_proj_fb<0><<<512, 256, 0, stream>>>(xout, proj_w, proj_b, x, out);
    k_proj_fb<1><<<512, 256, 0, stream>>>(xout, proj_w, proj_b, x, out);
    k_ffn1_fb<<<512, 256, 0, stream>>>(out, g2, b2, fc11_w, fc11_b, fc12_w, fc12_b, hbuf);
    k_ffn2_fb<0><<<512, 256, 0, stream>>>(hbuf, fc2_w, fc2_b, out);
    k_ffn2_fb<1><<<512, 256, 0, stream>>>(hbuf, fc2_w, fc2_b, out);
  }
}

// Round 15
// 589.926 us; speedup vs baseline: 1.2737x; 1.1893x over previous
//
#include <hip/hip_runtime.h>
#include <hip/hip_bf16.h>
#include <math.h>

#define CC 120       // channels
#define NHEADS 6
#define HDIM 20      // head dim
#define NTOK 128     // tokens per window
#define HID2 240
#define SCALE_F 0.2236067977499790f  // 20^-0.5

typedef __hip_bfloat16 bf16;
typedef __attribute__((ext_vector_type(8))) short bf16x8;   // 8 bf16 (4 VGPRs)
typedef __attribute__((ext_vector_type(4))) float f32x4;    // MFMA accumulator

__device__ inline f32x4 mfma16(bf16x8 a, bf16x8 b, f32x4 c) {
  return __builtin_amdgcn_mfma_f32_16x16x32_bf16(a, b, c, 0, 0, 0);
}

__device__ inline short f2bf_s(float f) {
  bf16 h = __float2bfloat16(f);
  return *reinterpret_cast<short*>(&h);
}

// LDS-only barrier: order LDS ops across waves WITHOUT draining vmcnt
// (global stores keep flying across phases).
__device__ __forceinline__ void lds_barrier() {
  asm volatile("s_waitcnt lgkmcnt(0)" ::: "memory");
  __builtin_amdgcn_s_barrier();
  asm volatile("" ::: "memory");
}

// ---------------------------------------------------------------------------
// token -> rolled spatial source position (also the scatter destination for
// window-reverse + un-roll, which is the same map).
__device__ inline size_t token_src_offset(int token) {
  const int wi = token >> 7, n = token & 127;
  const int b_ = wi >> 8, rem = wi & 255;
  const int dB = rem >> 6, hB = (rem >> 3) & 7, wB = rem & 7;
  const int dI = n >> 6, hI = (n >> 3) & 7, wI = n & 7;
  const int d = dB * 2 + dI, h = hB * 8 + hI, w = wB * 8 + wI;
  const int ds = (d + 1) & 7, hs = (h + 4) & 63, ws2 = (w + 4) & 63;
  return (((size_t)(b_ * 8 + ds) * 64 + hs) * 64 + ws2) * CC;
}

__device__ inline void ln120(float* xv, const float* __restrict__ g,
                             const float* __restrict__ bb) {
  float s0 = 0.f, s1 = 0.f, s2 = 0.f, s3 = 0.f;
#pragma unroll
  for (int k = 0; k < CC; k += 4) {
    s0 += xv[k]; s1 += xv[k + 1]; s2 += xv[k + 2]; s3 += xv[k + 3];
  }
  const float mean = ((s0 + s1) + (s2 + s3)) * (1.f / 120.f);
  float v0 = 0.f, v1 = 0.f, v2 = 0.f, v3 = 0.f;
#pragma unroll
  for (int k = 0; k < CC; k += 4) {
    float d0 = xv[k] - mean, d1 = xv[k + 1] - mean;
    float d2 = xv[k + 2] - mean, d3 = xv[k + 3] - mean;
    v0 += d0 * d0; v1 += d1 * d1; v2 += d2 * d2; v3 += d3 * d3;
  }
  const float rstd = rsqrtf(((v0 + v1) + (v2 + v3)) * (1.f / 120.f) + 1e-5f);
#pragma unroll
  for (int k = 0; k < CC; k++) xv[k] = (xv[k] - mean) * rstd * g[k] + bb[k];
}

__device__ inline float dot120(const float* xv, const float* __restrict__ wr) {
  float a0 = 0.f, a1 = 0.f, a2 = 0.f, a3 = 0.f;
#pragma unroll
  for (int k = 0; k < CC; k += 4) {
    a0 = fmaf(xv[k], wr[k], a0);
    a1 = fmaf(xv[k + 1], wr[k + 1], a1);
    a2 = fmaf(xv[k + 2], wr[k + 2], a2);
    a3 = fmaf(xv[k + 3], wr[k + 3], a3);
  }
  return (a0 + a1) + (a2 + a3);
}

// ===========================================================================
// FAST PATH
// ===========================================================================
// Weight prep.
//  Bffn [512][128]: rows 0..239 = W11, 256..495 = W12 (K pad, bias separate)
//  Bfc2 [128][256], Bproj [128][256]
//  Wself2/Wmut2 [576][128]: rows 0..191 q (heads padded to 32, SCALE folded),
//    192..383 k, 384..575 v. col 120 = bias (A1 col120 == 1), pads 0.
//    v-row pad chan 20 = e120 (=> V col 20 == 1.0: PV computes softmax rowsum).
__global__ __launch_bounds__(256) void k_prep(
    const float* __restrict__ w11, const float* __restrict__ w12,
    const float* __restrict__ fc2w, const float* __restrict__ projw,
    const float* __restrict__ wself, const float* __restrict__ bself,
    const float* __restrict__ wmut, const float* __restrict__ bmut,
    bf16* __restrict__ Bffn, bf16* __restrict__ Bfc2, bf16* __restrict__ Bproj,
    bf16* __restrict__ Wself2, bf16* __restrict__ Wmut2) {
  const int i = blockIdx.x * 256 + threadIdx.x;
  if (i < 65536) {
    const int r = i >> 7, k = i & 127;
    float v = 0.f;
    if (k < 120) {
      if (r < 240) v = w11[r * 120 + k];
      else if (r >= 256 && r < 496) v = w12[(r - 256) * 120 + k];
    }
    Bffn[i] = __float2bfloat16(v);
  } else if (i < 98304) {
    const int j = i - 65536, r = j >> 8, k = j & 255;
    Bfc2[j] = __float2bfloat16((r < 120 && k < 240) ? fc2w[r * 240 + k] : 0.f);
  } else if (i < 131072) {
    const int j = i - 98304, r = j >> 8, k = j & 255;
    Bproj[j] = __float2bfloat16((r < 120 && k < 240) ? projw[r * 240 + k] : 0.f);
  } else if (i < 278528) {
    const int j = (i - 131072) % 73728;
    const bool is_self = (i - 131072) < 73728;
    const float* w = is_self ? wself : wmut;
    const float* b = is_self ? bself : bmut;
    const int r = j >> 7, k = j & 127;
    const int grp = r / 192;              // 0=q 1=k 2=v
    const int rr = r % 192;
    const int hh = rr >> 5, jj = rr & 31;
    float v = 0.f;
    if (jj < 20) {
      const int orow = grp * 120 + hh * 20 + jj;
      if (k < 120) v = w[orow * 120 + k];
      else if (k == 120) v = b[orow];
      if (grp == 0) v *= SCALE_F;
    } else if (grp == 2 && jj == 20 && k == 120) {
      v = 1.0f;                           // rowsum column
    }
    (is_self ? Wself2 : Wmut2)[j] = __float2bfloat16(v);
  }
}

// posqT[c][t63] = dot(pos[t63], W'_c over real channels); SCALE on q cols.
// TRANSPOSED so the QKV phase can f32x4-load 4 consecutive token rows
// (matching the MFMA C/D row layout quad*4+r).
__global__ __launch_bounds__(256) void k_posqT(
    const float* __restrict__ pos, const float* __restrict__ wmut,
    float* __restrict__ posqT) {
  const int i = blockIdx.x * 256 + threadIdx.x;
  if (i >= 576 * 64) return;
  const int c = i >> 6, t63 = i & 63;
  const int grp = c / 192, rr = c % 192;
  const int hh = rr >> 5, jj = rr & 31;
  float v = 0.f;
  if (jj < 20) {
    v = dot120(pos + (size_t)t63 * CC, wmut + (size_t)(grp * 120 + hh * 20 + jj) * CC);
    if (grp == 0) v *= SCALE_F;
  }
  posqT[i] = v;   // i == c*64 + t63
}

// biasT[h][col][row] = rpb[rpi[row,col]*6+h]  (TRANSPOSED rel-pos bias, fp32)
__global__ __launch_bounds__(256) void k_biasT(
    const int* __restrict__ rpi, const float* __restrict__ rpb,
    float* __restrict__ biasT) {
  const int i = blockIdx.x * 256 + threadIdx.x;
  if (i >= NHEADS * 16384) return;
  const int h = i >> 14, rc = i & 16383;
  const int col = rc >> 7, row = rc & 127;
  biasT[i] = rpb[rpi[row * 128 + col] * NHEADS + h];
}

// LN1 + roll + partition -> A1 bf16 [131072][128], col 120 = 1.0 (bias col).
__global__ __launch_bounds__(256) void k_a1(
    const float* __restrict__ x, const float* __restrict__ g1,
    const float* __restrict__ b1, bf16* __restrict__ A1) {
  const int token = blockIdx.x * 256 + threadIdx.x;
  const float4* xr4 = (const float4*)(x + token_src_offset(token));
  float xv[CC];
#pragma unroll
  for (int k = 0; k < 30; k++) {
    const float4 v = xr4[k];
    xv[k * 4] = v.x; xv[k * 4 + 1] = v.y; xv[k * 4 + 2] = v.z; xv[k * 4 + 3] = v.w;
  }
  ln120(xv, g1, b1);
  bf16x8* dst8 = (bf16x8*)(A1 + (size_t)token * 128);
#pragma unroll
  for (int k = 0; k < 15; k++) {
    bf16x8 v;
#pragma unroll
    for (int j = 0; j < 8; j++) v[j] = f2bf_s(xv[k * 8 + j]);
    dst8[k] = v;
  }
  bf16x8 tail = {0, 0, 0, 0, 0, 0, 0, 0};
  tail[0] = f2bf_s(1.0f);
  dst8[15] = tail;
}

// ---------------------------------------------------------------------------
// FUSED QKV + attention (R3 structure). Mask is computed ON THE FLY from a
// 128-entry per-window region table in LDS (rgn[t] = Swin region id of token
// t in ROLLED coords) -- replaces the 16.8 MB maskT table + its transpose
// kernel. mask[r][c] = -100 iff rgn[r] != rgn[c], used only when hasmask.
template <bool MUT>
__device__ __forceinline__ void fattn_body(
    const int wi, const bf16* __restrict__ A1, const bf16* __restrict__ W2,
    const float* __restrict__ posqT, const float* __restrict__ biasT,
    bf16* __restrict__ xout, bf16* kS, bf16* vS, bf16* qP, int* rgn) {
  const int w = threadIdx.x >> 6, lane = threadIdx.x & 63;
  const int ln = lane & 15, quad = lane >> 4;
  const int wc = wi & 255;
  // window crosses the roll boundary iff any block index is the last one
  const bool hasmask = ((wc >> 6) == 3) || (((wc >> 3) & 7) == 7) || ((wc & 7) == 7);
  // region table (rolled coords): rd=(d>=6)+(d>=7), rh=(h>=56)+(h>=60),
  // rw=(w>=56)+(w>=60); cnt = rd*9+rh*3+rw (matches reference slice order).
  if (threadIdx.x < 128) {
    const int t = threadIdx.x;
    const int d = (wc >> 6) * 2 + (t >> 6);
    const int h = (((wc >> 3) & 7) << 3) + ((t >> 3) & 7);
    const int w2 = ((wc & 7) << 3) + (t & 7);
    const int rd = (d >= 6) + (d >= 7);
    const int rh = (h >= 56) + (h >= 60);
    const int rw = (w2 >= 56) + (w2 >= 60);
    rgn[t] = rd * 9 + rh * 3 + rw;
  }
  // A-fragments for this wave's 32 rows (reused across 6 heads x 3 groups)
  bf16x8 af[2][4];
#pragma unroll
  for (int mi = 0; mi < 2; mi++)
#pragma unroll
    for (int s = 0; s < 4; s++)
      af[mi][s] = *(const bf16x8*)(A1 + (size_t)(wi * NTOK + w * 32 + mi * 16 + ln) * 128 + s * 32 + quad * 8);

  for (int hh = 0; hh < NHEADS; hh++) {
    // ---- QKV phase: group g = 0(q) 1(k) 2(v) ----
#pragma unroll
    for (int g = 0; g < 3; g++) {
      bf16x8 bfr[2][4];
#pragma unroll
      for (int nt = 0; nt < 2; nt++)
#pragma unroll
        for (int s = 0; s < 4; s++)
          bfr[nt][s] = *(const bf16x8*)(W2 + (size_t)(g * 192 + hh * 32 + nt * 16 + ln) * 128 + s * 32 + quad * 8);
      f32x4 acc[2][2] = {};
#pragma unroll
      for (int s = 0; s < 4; s++)
#pragma unroll
        for (int mi = 0; mi < 2; mi++)
#pragma unroll
          for (int nt = 0; nt < 2; nt++)
            acc[mi][nt] = mfma16(af[mi][s], bfr[nt][s], acc[mi][nt]);
      if (MUT) {
#pragma unroll
        for (int mi = 0; mi < 2; mi++)
#pragma unroll
          for (int nt = 0; nt < 2; nt++) {
            const f32x4 pq = *(const f32x4*)&posqT[
                (size_t)(g * 192 + hh * 32 + nt * 16 + ln) * 64 +
                ((w * 32 + mi * 16 + quad * 4) & 63)];
            acc[mi][nt] += pq;
          }
      }
#pragma unroll
      for (int mi = 0; mi < 2; mi++)
#pragma unroll
        for (int nt = 0; nt < 2; nt++)
#pragma unroll
          for (int r = 0; r < 4; r++) {
            const int lrow = w * 32 + mi * 16 + quad * 4 + r;
            const short bv = f2bf_s(acc[mi][nt][r]);
            if (g == 0)      *(short*)&qP[lrow * 40 + nt * 16 + ln] = bv;
            else if (g == 1) *(short*)&kS[lrow * 40 + nt * 16 + ln] = bv;
            else             *(short*)&vS[(nt * 16 + ln) * 136 + lrow] = bv;
          }
    }
    lds_barrier();
    // ---- attention phase ----
    bf16x8 qf[2];
#pragma unroll
    for (int i = 0; i < 2; i++)
      qf[i] = *(const bf16x8*)(&qP[(w * 32 + i * 16 + ln) * 40 + quad * 8]);
    f32x4 accO[2][2];
#pragma unroll
    for (int i = 0; i < 2; i++)
#pragma unroll
      for (int nt = 0; nt < 2; nt++) accO[i][nt] = (f32x4){0.f, 0.f, 0.f, 0.f};
    const int kb = MUT ? ((w < 2) ? 64 : 0) : 0;
    const int nchunk = MUT ? 2 : 4;
    for (int chunk = 0; chunk < nchunk; chunk++) {
      const int key0 = kb + chunk * 32;
      bf16x8 kf[2], vf[2];
      kf[0] = *(const bf16x8*)(&kS[(key0 + ln) * 40 + quad * 8]);
      kf[1] = *(const bf16x8*)(&kS[(key0 + 16 + ln) * 40 + quad * 8]);
      vf[0] = *(const bf16x8*)(&vS[ln * 136 + key0 + quad * 8]);
      vf[1] = *(const bf16x8*)(&vS[(16 + ln) * 136 + key0 + quad * 8]);
#pragma unroll
      for (int i = 0; i < 2; i++) {
        const int rb = w * 32 + i * 16 + quad * 4;
        f32x4 c0, c1;
        if (MUT) {
          c0 = (f32x4){0.f, 0.f, 0.f, 0.f};
          c1 = (f32x4){0.f, 0.f, 0.f, 0.f};
          if (hasmask) {
            const int rc0 = rgn[chunk * 32 + ln];
            const int rc1 = rgn[chunk * 32 + 16 + ln];
#pragma unroll
            for (int r = 0; r < 4; r++) {
              const int rr = rgn[(rb & 63) + r];
              if (rr != rc0) c0[r] = -100.f;
              if (rr != rc1) c1[r] = -100.f;
            }
          }
        } else {
          c0 = *(const f32x4*)&biasT[(size_t)hh * 16384 + (key0 + ln) * 128 + rb];
          c1 = *(const f32x4*)&biasT[(size_t)hh * 16384 + (key0 + 16 + ln) * 128 + rb];
          if (hasmask) {
            const int rc0 = rgn[key0 + ln];
            const int rc1 = rgn[key0 + 16 + ln];
#pragma unroll
            for (int r = 0; r < 4; r++) {
              const int rr = rgn[rb + r];
              if (rr != rc0) c0[r] -= 100.f;
              if (rr != rc1) c1[r] -= 100.f;
            }
          }
        }
        const f32x4 s0 = mfma16(qf[i], kf[0], c0);
        const f32x4 s1 = mfma16(qf[i], kf[1], c1);
#pragma unroll
        for (int r = 0; r < 4; r++) {
          const int row = rb + r;
          *(short*)&qP[row * 40 + ln] = f2bf_s(__expf(s0[r]));
          *(short*)&qP[row * 40 + 16 + ln] = f2bf_s(__expf(s1[r]));
        }
      }
#pragma unroll
      for (int i = 0; i < 2; i++) {
        bf16x8 pf = *(const bf16x8*)(&qP[(w * 32 + i * 16 + ln) * 40 + quad * 8]);
        accO[i][0] = mfma16(pf, vf[0], accO[i][0]);
        accO[i][1] = mfma16(pf, vf[1], accO[i][1]);
      }
    }
    // ---- epilogue: rowsum (V pad col 20) + normalize + write ----
#pragma unroll
    for (int i = 0; i < 2; i++) {
#pragma unroll
      for (int r = 0; r < 4; r++) {
        const float rs = __shfl(accO[i][1][r], (lane & 48) + 4, 64);
        const float inv = 1.f / rs;
        const int row = w * 32 + i * 16 + quad * 4 + r;
        const int orow_i = MUT ? ((w < 2) ? 64 + row : row - 64) : row;
        const int token = wi * NTOK + orow_i;
        bf16* orow = xout + (size_t)token * 256 + (MUT ? 0 : CC) + hh * HDIM;
        orow[ln] = __float2bfloat16(accO[i][0][r] * inv);
        if (ln < 4) orow[16 + ln] = __float2bfloat16(accO[i][1][r] * inv);
      }
    }
    lds_barrier();   // protect kS/vS/qP before next head's QKV overwrite
  }
}

// Merged self+mut launch: blocks 0..1023 self, 1024..2047 mut.
__global__ __launch_bounds__(256, 4) void k_fattn2(
    const bf16* __restrict__ A1, const bf16* __restrict__ Wself2,
    const bf16* __restrict__ Wmut2, const float* __restrict__ posqT,
    const float* __restrict__ biasT, bf16* __restrict__ xout) {
  __shared__ bf16 kS[128 * 40];
  __shared__ bf16 vS[32 * 136];
  __shared__ bf16 qP[128 * 40];   // q staging, then P
  __shared__ int rgnS[128];       // per-window Swin region ids
  if (blockIdx.x < 1024)
    fattn_body<false>(blockIdx.x, A1, Wself2, nullptr, biasT, xout, kS, vS, qP, rgnS);
  else
    fattn_body<true>(blockIdx.x - 1024, A1, Wmut2, posqT, biasT, xout, kS, vS, qP, rgnS);
}

// LN2 -> bf16 A-matrix [131072][128]. float4 loads + bf16x8 stores. (R3 verbatim.)
__global__ __launch_bounds__(256) void k_ln2(
    const float* __restrict__ out, const float* __restrict__ g2,
    const float* __restrict__ b2, bf16* __restrict__ A2) {
  const int row = blockIdx.x * 256 + threadIdx.x;
  const float4* xr4 = (const float4*)(out + (size_t)row * CC);
  float xv[CC];
#pragma unroll
  for (int k = 0; k < 30; k++) {
    const float4 v = xr4[k];
    xv[k * 4] = v.x; xv[k * 4 + 1] = v.y; xv[k * 4 + 2] = v.z; xv[k * 4 + 3] = v.w;
  }
  ln120(xv, g2, b2);
  bf16x8* dst8 = (bf16x8*)(A2 + (size_t)row * 128);
#pragma unroll
  for (int k = 0; k < 15; k++) {
    bf16x8 v;
#pragma unroll
    for (int j = 0; j < 8; j++) v[j] = f2bf_s(xv[k * 8 + j]);
    dst8[k] = v;
  }
  bf16x8 tail = {0, 0, 0, 0, 0, 0, 0, 0};
  dst8[15] = tail;
}

// Output GEMM, K=256 (padded), N=120. grid (1, 1024). PROJ path (R3 verbatim).
template <bool PROJ>
__global__ __launch_bounds__(256) void k_out_mfma(
    const bf16* __restrict__ A, const bf16* __restrict__ Bw,
    const float* __restrict__ bias, const float* __restrict__ xin,
    float* __restrict__ out) {
  const int w = threadIdx.x >> 6;
  const int lane = threadIdx.x & 63;
  const int ln = lane & 15, quad = lane >> 4;
  bf16x8 bfr[2][8];
#pragma unroll
  for (int nt = 0; nt < 2; nt++)
#pragma unroll
    for (int s = 0; s < 8; s++)
      bfr[nt][s] = *(const bf16x8*)(Bw + (size_t)((w * 2 + nt) * 16 + ln) * 256 + s * 32 + quad * 8);
  const int m_base = blockIdx.y * 128;
  for (int it = 0; it < 4; it++) {
    const int m0 = m_base + it * 32;
    f32x4 acc[2][2] = {};
    bf16x8 af[2][8];
#pragma unroll
    for (int mi = 0; mi < 2; mi++)
#pragma unroll
      for (int s = 0; s < 8; s++)
        af[mi][s] = *(const bf16x8*)(A + (size_t)(m0 + mi * 16 + ln) * 256 + s * 32 + quad * 8);
#pragma unroll
    for (int s = 0; s < 8; s++)
#pragma unroll
      for (int mi = 0; mi < 2; mi++)
#pragma unroll
        for (int nt = 0; nt < 2; nt++)
          acc[mi][nt] = mfma16(af[mi][s], bfr[nt][s], acc[mi][nt]);
#pragma unroll
    for (int mi = 0; mi < 2; mi++)
#pragma unroll
      for (int nt = 0; nt < 2; nt++) {
        const int colc = (w * 2 + nt) * 16 + ln;
        if (colc < CC) {
#pragma unroll
          for (int r = 0; r < 4; r++) {
            const int row = m0 + mi * 16 + quad * 4 + r;
            if (PROJ) {
              const size_t dst = token_src_offset(row);
              out[dst + colc] = xin[dst + colc] + bias[colc] + acc[mi][nt][r];
            } else {
              out[(size_t)row * CC + colc] += bias[colc] + acc[mi][nt][r];
            }
          }
        }
      }
  }
}

// ---------------------------------------------------------------------------
// FUSED FFN: per block, 32 token rows. Phase 1: h = gelu(A2@W11^T)*(A2@W12^T)
// into LDS (240 cols, K-pad 256 is zero-weighted). ONE barrier. Phase 2:
// out += h @ fc2^T + bias, A-fragments read from LDS (+8 pad -> 2-way banks).
__global__ __launch_bounds__(256) void k_ffn_fused(
    const bf16* __restrict__ A2, const bf16* __restrict__ Bffn,
    const bf16* __restrict__ Bfc2, const float* __restrict__ b11,
    const float* __restrict__ b12, const float* __restrict__ fc2b,
    float* __restrict__ out) {
  __shared__ bf16 hS[32][264];
  const int w = threadIdx.x >> 6;
  const int lane = threadIdx.x & 63;
  const int ln = lane & 15, quad = lane >> 4;
  const int m0 = blockIdx.x * 32;
  // ---- phase 1: FFN1, wave w owns cols w*64 .. w*64+63 ----
  bf16x8 af[2][4];
#pragma unroll
  for (int mi = 0; mi < 2; mi++)
#pragma unroll
    for (int s = 0; s < 4; s++)
      af[mi][s] = *(const bf16x8*)(A2 + (size_t)(m0 + mi * 16 + ln) * 128 + s * 32 + quad * 8);
#pragma unroll
  for (int nt = 0; nt < 4; nt++) {
    const int col = w * 64 + nt * 16 + ln;
    bf16x8 b1f[4], b2f[4];
#pragma unroll
    for (int s = 0; s < 4; s++) {
      b1f[s] = *(const bf16x8*)(Bffn + (size_t)col * 128 + s * 32 + quad * 8);
      b2f[s] = *(const bf16x8*)(Bffn + (size_t)(256 + col) * 128 + s * 32 + quad * 8);
    }
    f32x4 acc1[2] = {}, acc2[2] = {};
#pragma unroll
    for (int s = 0; s < 4; s++)
#pragma unroll
      for (int mi = 0; mi < 2; mi++) {
        acc1[mi] = mfma16(af[mi][s], b1f[s], acc1[mi]);
        acc2[mi] = mfma16(af[mi][s], b2f[s], acc2[mi]);
      }
    const float bias1 = (col < HID2) ? b11[col] : 0.f;
    const float bias2 = (col < HID2) ? b12[col] : 0.f;
#pragma unroll
    for (int mi = 0; mi < 2; mi++)
#pragma unroll
      for (int r = 0; r < 4; r++) {
        const int row = mi * 16 + quad * 4 + r;
        const float a = acc1[mi][r] + bias1;
        const float c = acc2[mi][r] + bias2;
        const float ge = 0.5f * a * (1.f + erff(a * 0.70710678118654752f));
        hS[row][col] = __float2bfloat16(ge * c);
      }
  }
  lds_barrier();
  // ---- phase 2: FFN2 (K = 256, cols 240..255 of hS are zero-weighted) ----
  bf16x8 bfr[2][8];
#pragma unroll
  for (int nt = 0; nt < 2; nt++)
#pragma unroll
    for (int s = 0; s < 8; s++)
      bfr[nt][s] = *(const bf16x8*)(Bfc2 + (size_t)((w * 2 + nt) * 16 + ln) * 256 + s * 32 + quad * 8);
  bf16x8 af2[2][8];
#pragma unroll
  for (int mi = 0; mi < 2; mi++)
#pragma unroll
    for (int s = 0; s < 8; s++)
      af2[mi][s] = *(const bf16x8*)(&hS[mi * 16 + ln][s * 32 + quad * 8]);
  f32x4 acc[2][2] = {};
#pragma unroll
  for (int s = 0; s < 8; s++)
#pragma unroll
    for (int mi = 0; mi < 2; mi++)
#pragma unroll
      for (int nt = 0; nt < 2; nt++)
        acc[mi][nt] = mfma16(af2[mi][s], bfr[nt][s], acc[mi][nt]);
#pragma unroll
  for (int mi = 0; mi < 2; mi++)
#pragma unroll
    for (int nt = 0; nt < 2; nt++) {
      const int colc = (w * 2 + nt) * 16 + ln;
      if (colc < CC) {
#pragma unroll
        for (int r = 0; r < 4; r++) {
          const int row = m0 + mi * 16 + quad * 4 + r;
          out[(size_t)row * CC + colc] += fc2b[colc] + acc[mi][nt][r];
        }
      }
    }
}

// ===========================================================================
// FALLBACK PATH (round-2 proven kernels; used only if ws is too small)
// ===========================================================================
__global__ __launch_bounds__(128) void k_attn_self_fb(
    const float* __restrict__ x, const float* __restrict__ g1,
    const float* __restrict__ b1, const float* __restrict__ wqkv,
    const float* __restrict__ bqkv, const float* __restrict__ mask,
    const float* __restrict__ rpb, const int* __restrict__ rpi,
    bf16* __restrict__ xout) {
  __shared__ float kl[NTOK][HDIM];
  __shared__ float vl[NTOK][HDIM];
  const int wi = blockIdx.x, hh = blockIdx.y, t = threadIdx.x;
  const int token = wi * NTOK + t;
  const float* xr = x + token_src_offset(token);
  float xv[CC];
#pragma unroll
  for (int k = 0; k < CC; k++) xv[k] = xr[k];
  ln120(xv, g1, b1);
  float q[HDIM];
  for (int j = 0; j < HDIM; j++) {
    const int c = hh * HDIM + j;
    q[j] = (dot120(xv, wqkv + (size_t)c * CC) + bqkv[c]) * SCALE_F;
    kl[t][j] = dot120(xv, wqkv + (size_t)(CC + c) * CC) + bqkv[CC + c];
    vl[t][j] = dot120(xv, wqkv + (size_t)(2 * CC + c) * CC) + bqkv[2 * CC + c];
  }
  __syncthreads();
  const float* mrow = mask + ((size_t)(wi & 255) * NTOK + t) * NTOK;
  const int* rrow = rpi + t * NTOK;
  float sum = 0.f;
  float o[HDIM];
#pragma unroll
  for (int i = 0; i < HDIM; i++) o[i] = 0.f;
  for (int m = 0; m < NTOK; m++) {
    float a0 = 0.f, a1 = 0.f, a2 = 0.f, a3 = 0.f;
#pragma unroll
    for (int i = 0; i < HDIM; i += 4) {
      a0 = fmaf(q[i], kl[m][i], a0);
      a1 = fmaf(q[i + 1], kl[m][i + 1], a1);
      a2 = fmaf(q[i + 2], kl[m][i + 2], a2);
      a3 = fmaf(q[i + 3], kl[m][i + 3], a3);
    }
    const float sc = (a0 + a1) + (a2 + a3) + rpb[rrow[m] * NHEADS + hh] + mrow[m];
    const float p = __expf(sc);
    sum += p;
#pragma unroll
    for (int i = 0; i < HDIM; i++) o[i] = fmaf(p, vl[m][i], o[i]);
  }
  const float inv = 1.f / sum;
  bf16* orow = xout + (size_t)token * HID2 + CC + hh * HDIM;
#pragma unroll
  for (int i = 0; i < HDIM; i++) orow[i] = __float2bfloat16(o[i] * inv);
}

__global__ __launch_bounds__(64) void k_attn_mut_fb(
    const float* __restrict__ x, const float* __restrict__ g1,
    const float* __restrict__ b1, const float* __restrict__ wqkv,
    const float* __restrict__ bqkv, const float* __restrict__ pos,
    const float* __restrict__ mask, bf16* __restrict__ xout) {
  __shared__ float kl[64][HDIM];
  __shared__ float vl[64][HDIM];
  const int wi = blockIdx.x, hh = blockIdx.y, which = blockIdx.z;
  const int t = threadIdx.x;
  const int qtok = which ? t : 64 + t;
  const int ktok = which ? 64 + t : t;
  const float* pr = pos + (size_t)t * CC;
  float xv[CC];
  {
    const float* xr = x + token_src_offset(wi * NTOK + ktok);
#pragma unroll
    for (int k = 0; k < CC; k++) xv[k] = xr[k];
    ln120(xv, g1, b1);
#pragma unroll
    for (int k = 0; k < CC; k++) xv[k] += pr[k];
    for (int j = 0; j < HDIM; j++) {
      const int c = hh * HDIM + j;
      kl[t][j] = dot120(xv, wqkv + (size_t)(CC + c) * CC) + bqkv[CC + c];
      vl[t][j] = dot120(xv, wqkv + (size_t)(2 * CC + c) * CC) + bqkv[2 * CC + c];
    }
  }
  float q[HDIM];
  {
    const float* xr = x + token_src_offset(wi * NTOK + qtok);
#pragma unroll
    for (int k = 0; k < CC; k++) xv[k] = xr[k];
    ln120(xv, g1, b1);
#pragma unroll
    for (int k = 0; k < CC; k++) xv[k] += pr[k];
    for (int j = 0; j < HDIM; j++) {
      const int c = hh * HDIM + j;
      q[j] = (dot120(xv, wqkv + (size_t)c * CC) + bqkv[c]) * SCALE_F;
    }
  }
  __syncthreads();
  const float* mrow = mask + ((size_t)(wi & 255) * NTOK + t) * NTOK;
  float sum = 0.f;
  float o[HDIM];
#pragma unroll
  for (int i = 0; i < HDIM; i++) o[i] = 0.f;
  for (int m = 0; m < 64; m++) {
    float a0 = 0.f, a1 = 0.f, a2 = 0.f, a3 = 0.f;
#pragma unroll
    for (int i = 0; i < HDIM; i += 4) {
      a0 = fmaf(q[i], kl[m][i], a0);
      a1 = fmaf(q[i + 1], kl[m][i + 1], a1);
      a2 = fmaf(q[i + 2], kl[m][i + 2], a2);
      a3 = fmaf(q[i + 3], kl[m][i + 3], a3);
    }
    const float p = __expf((a0 + a1) + (a2 + a3) + mrow[m]);
    sum += p;
#pragma unroll
    for (int i = 0; i < HDIM; i++) o[i] = fmaf(p, vl[m][i], o[i]);
  }
  const float inv = 1.f / sum;
  const int orow_i = which ? 64 + t : t;
  bf16* orow = xout + (size_t)(wi * NTOK + orow_i) * HID2 + hh * HDIM;
#pragma unroll
  for (int i = 0; i < HDIM; i++) orow[i] = __float2bfloat16(o[i] * inv);
}

template <int HALF>
__global__ __launch_bounds__(256) void k_proj_fb(
    const bf16* __restrict__ xout, const float* __restrict__ pw,
    const float* __restrict__ pb, const float* __restrict__ xin,
    float* __restrict__ out) {
  const int token = blockIdx.x * 256 + threadIdx.x;
  float xv[CC];
  const bf16* xr = xout + (size_t)token * HID2 + HALF * CC;
#pragma unroll
  for (int k = 0; k < CC; k++) xv[k] = __bfloat162float(xr[k]);
  const size_t dst = token_src_offset(token);
  for (int o = 0; o < CC; o++) {
    const float acc = dot120(xv, pw + (size_t)o * HID2 + HALF * CC);
    if (HALF == 0)
      out[dst + o] = xin[dst + o] + pb[o] + acc;
    else
      out[dst + o] += acc;
  }
}

__global__ __launch_bounds__(256) void k_ffn1_fb(
    const float* __restrict__ xres, const float* __restrict__ g,
    const float* __restrict__ bb, const float* __restrict__ w11,
    const float* __restrict__ b11, const float* __restrict__ w12,
    const float* __restrict__ b12, bf16* __restrict__ hbuf) {
  const int row = blockIdx.x * 256 + threadIdx.x;
  const float* xr = xres + (size_t)row * CC;
  float xv[CC];
#pragma unroll
  for (int k = 0; k < CC; k++) xv[k] = xr[k];
  ln120(xv, g, bb);
  bf16* hr = hbuf + (size_t)row * HID2;
  for (int o = 0; o < HID2; o++) {
    const float a = b11[o] + dot120(xv, w11 + (size_t)o * CC);
    const float c = b12[o] + dot120(xv, w12 + (size_t)o * CC);
    const float ge = 0.5f * a * (1.f + erff(a * 0.70710678118654752f));
    hr[o] = __float2bfloat16(ge * c);
  }
}

template <int HALF>
__global__ __launch_bounds__(256) void k_ffn2_fb(
    const bf16* __restrict__ hbuf, const float* __restrict__ w2,
    const float* __restrict__ b2f, float* __restrict__ out) {
  const int row = blockIdx.x * 256 + threadIdx.x;
  float xv[CC];
  const bf16* xr = hbuf + (size_t)row * HID2 + HALF * CC;
#pragma unroll
  for (int k = 0; k < CC; k++) xv[k] = __bfloat162float(xr[k]);
  float* orow = out + (size_t)row * CC;
  for (int o = 0; o < CC; o++) {
    float acc = dot120(xv, w2 + (size_t)o * HID2 + HALF * CC);
    if (HALF == 0) acc += b2f[o];
    orow[o] += acc;
  }
}

// ---------------------------------------------------------------------------
extern "C" void kernel_launch(void* const* d_in, const int* in_sizes, int n_in,
                              void* d_out, int out_size, void* d_ws, size_t ws_size,
                              hipStream_t stream) {
  const float* x          = (const float*)d_in[0];
  const float* attn_mask  = (const float*)d_in[1];
  const float* g1         = (const float*)d_in[2];
  const float* b1         = (const float*)d_in[3];
  const float* qkv_self_w = (const float*)d_in[4];
  const float* qkv_self_b = (const float*)d_in[5];
  const float* qkv_mut_w  = (const float*)d_in[6];
  const float* qkv_mut_b  = (const float*)d_in[7];
  const float* proj_w     = (const float*)d_in[8];
  const float* proj_b     = (const float*)d_in[9];
  const float* rpb_table  = (const float*)d_in[10];
  const float* pos_bias   = (const float*)d_in[11];
  const float* g2         = (const float*)d_in[12];
  const float* b2         = (const float*)d_in[13];
  const float* fc11_w     = (const float*)d_in[14];
  const float* fc11_b     = (const float*)d_in[15];
  const float* fc12_w     = (const float*)d_in[16];
  const float* fc12_b     = (const float*)d_in[17];
  const float* fc2_w      = (const float*)d_in[18];
  const float* fc2_b      = (const float*)d_in[19];
  const int*   rpi        = (const int*)d_in[20];
  float* out = (float*)d_out;

  // ws layout (bytes), gate unchanged:
  //   xout  @ 0           : 131072*256*2 = 67,108,864
  //   A1/A2 @ 67,108,864  : 131072*128*2 = 33,554,432
  //   Bffn  @ 100,663,296 : 131,072 ; Bfc2 +65,536 ; Bproj +65,536
  // d_out doubles as scratch until proj overwrites every element:
  //   Wself2 @ 40,000,000 ; Wmut2 @ 40,200,000 ; posqT @ 40,400,000
  //   biasT @ 41,000,000 (393,216) -> ends 41.4 MB < 62.9 MB
  const bool fast = ws_size >= (size_t)100925440;

  if (fast) {
    bf16* xout  = (bf16*)d_ws;
    bf16* A1    = (bf16*)((char*)d_ws + 67108864);
    bf16* A2    = A1;
    bf16* Bffn  = (bf16*)((char*)d_ws + 100663296);
    bf16* Bfc2  = Bffn + 65536;
    bf16* Bproj = Bfc2 + 32768;

    bf16*  Wself2 = (bf16*)((char*)d_out + 40000000);
    bf16*  Wmut2  = (bf16*)((char*)d_out + 40200000);
    float* posqT  = (float*)((char*)d_out + 40400000);
    float* biasT  = (float*)((char*)d_out + 41000000);

    k_prep<<<1088, 256, 0, stream>>>(fc11_w, fc12_w, fc2_w, proj_w,
                                     qkv_self_w, qkv_self_b, qkv_mut_w, qkv_mut_b,
                                     Bffn, Bfc2, Bproj, Wself2, Wmut2);
    k_posqT<<<144, 256, 0, stream>>>(pos_bias, qkv_mut_w, posqT);
    k_biasT<<<384, 256, 0, stream>>>(rpi, rpb_table, biasT);
    k_a1<<<512, 256, 0, stream>>>(x, g1, b1, A1);
    k_fattn2<<<2048, 256, 0, stream>>>(A1, Wself2, Wmut2, posqT, biasT, xout);
    k_out_mfma<true><<<dim3(1, 1024), 256, 0, stream>>>(xout, Bproj, proj_b, x, out);
    k_ln2<<<512, 256, 0, stream>>>(out, g2, b2, A2);
    k_ffn_fused<<<4096, 256, 0, stream>>>(A2, Bffn, Bfc2, fc11_b, fc12_b, fc2_b, out);
  } else {
    bf16* xout = (bf16*)d_ws;
    bf16* hbuf = (bf16*)d_ws;
    k_attn_self_fb<<<dim3(1024, NHEADS), 128, 0, stream>>>(
        x, g1, b1, qkv_self_w, qkv_self_b, attn_mask, rpb_table, rpi, xout);
    k_attn_mut_fb<<<dim3(1024, NHEADS, 2), 64, 0, stream>>>(
        x, g1, b1, qkv_mut_w, qkv_mut_b, pos_bias, attn_mask, xout);
    k_proj_fb<0><<<512, 256, 0, stream>>>(xout, proj_w, proj_b, x, out);
    k_proj_fb<1><<<512, 256, 0, stream>>>(xout, proj_w, proj_b, x, out);
    k_ffn1_fb<<<512, 256, 0, stream>>>(out, g2, b2, fc11_w, fc11_b, fc12_w, fc12_b, hbuf);
    k_ffn2_fb<0><<<512, 256, 0, stream>>>(hbuf, fc2_w, fc2_b, out);
    k_ffn2_fb<1><<<512, 256, 0, stream>>>(hbuf, fc2_w, fc2_b, out);
  }
}

// Round 17
// 562.100 us; speedup vs baseline: 1.3368x; 1.0495x over previous
//
#include <hip/hip_runtime.h>
#include <hip/hip_bf16.h>
#include <math.h>

#define CC 120       // channels
#define NHEADS 6
#define HDIM 20      // head dim
#define NTOK 128     // tokens per window
#define HID2 240
#define SCALE_F 0.2236067977499790f  // 20^-0.5

typedef __hip_bfloat16 bf16;
typedef __attribute__((ext_vector_type(8))) short bf16x8;   // 8 bf16 (4 VGPRs)
typedef __attribute__((ext_vector_type(4))) float f32x4;    // MFMA accumulator

__device__ inline f32x4 mfma16(bf16x8 a, bf16x8 b, f32x4 c) {
  return __builtin_amdgcn_mfma_f32_16x16x32_bf16(a, b, c, 0, 0, 0);
}

__device__ inline short f2bf_s(float f) {
  bf16 h = __float2bfloat16(f);
  return *reinterpret_cast<short*>(&h);
}

// LDS-only barrier: order LDS ops across waves WITHOUT draining vmcnt
// (global stores keep flying across phases).
__device__ __forceinline__ void lds_barrier() {
  asm volatile("s_waitcnt lgkmcnt(0)" ::: "memory");
  __builtin_amdgcn_s_barrier();
  asm volatile("" ::: "memory");
}

// ---------------------------------------------------------------------------
// token -> rolled spatial source position (also the scatter destination for
// window-reverse + un-roll, which is the same map).
__device__ inline size_t token_src_offset(int token) {
  const int wi = token >> 7, n = token & 127;
  const int b_ = wi >> 8, rem = wi & 255;
  const int dB = rem >> 6, hB = (rem >> 3) & 7, wB = rem & 7;
  const int dI = n >> 6, hI = (n >> 3) & 7, wI = n & 7;
  const int d = dB * 2 + dI, h = hB * 8 + hI, w = wB * 8 + wI;
  const int ds = (d + 1) & 7, hs = (h + 4) & 63, ws2 = (w + 4) & 63;
  return (((size_t)(b_ * 8 + ds) * 64 + hs) * 64 + ws2) * CC;
}

__device__ inline void ln120(float* xv, const float* __restrict__ g,
                             const float* __restrict__ bb) {
  float s0 = 0.f, s1 = 0.f, s2 = 0.f, s3 = 0.f;
#pragma unroll
  for (int k = 0; k < CC; k += 4) {
    s0 += xv[k]; s1 += xv[k + 1]; s2 += xv[k + 2]; s3 += xv[k + 3];
  }
  const float mean = ((s0 + s1) + (s2 + s3)) * (1.f / 120.f);
  float v0 = 0.f, v1 = 0.f, v2 = 0.f, v3 = 0.f;
#pragma unroll
  for (int k = 0; k < CC; k += 4) {
    float d0 = xv[k] - mean, d1 = xv[k + 1] - mean;
    float d2 = xv[k + 2] - mean, d3 = xv[k + 3] - mean;
    v0 += d0 * d0; v1 += d1 * d1; v2 += d2 * d2; v3 += d3 * d3;
  }
  const float rstd = rsqrtf(((v0 + v1) + (v2 + v3)) * (1.f / 120.f) + 1e-5f);
#pragma unroll
  for (int k = 0; k < CC; k++) xv[k] = (xv[k] - mean) * rstd * g[k] + bb[k];
}

__device__ inline float dot120(const float* xv, const float* __restrict__ wr) {
  float a0 = 0.f, a1 = 0.f, a2 = 0.f, a3 = 0.f;
#pragma unroll
  for (int k = 0; k < CC; k += 4) {
    a0 = fmaf(xv[k], wr[k], a0);
    a1 = fmaf(xv[k + 1], wr[k + 1], a1);
    a2 = fmaf(xv[k + 2], wr[k + 2], a2);
    a3 = fmaf(xv[k + 3], wr[k + 3], a3);
  }
  return (a0 + a1) + (a2 + a3);
}

// ===========================================================================
// FAST PATH
// ===========================================================================
// Weight prep.
//  Bffn [512][128]: rows 0..239 = W11, 256..495 = W12 (K pad, bias separate)
//  Bfc2 [128][256], Bproj [128][256]
//  Wself2/Wmut2 [576][128]: rows 0..191 q (heads padded to 32, SCALE folded),
//    192..383 k, 384..575 v. col 120 = bias (A1 col120 == 1), pads 0.
//    v-row pad chan 20 = e120 (=> V col 20 == 1.0: PV computes softmax rowsum).
__global__ __launch_bounds__(256) void k_prep(
    const float* __restrict__ w11, const float* __restrict__ w12,
    const float* __restrict__ fc2w, const float* __restrict__ projw,
    const float* __restrict__ wself, const float* __restrict__ bself,
    const float* __restrict__ wmut, const float* __restrict__ bmut,
    bf16* __restrict__ Bffn, bf16* __restrict__ Bfc2, bf16* __restrict__ Bproj,
    bf16* __restrict__ Wself2, bf16* __restrict__ Wmut2) {
  const int i = blockIdx.x * 256 + threadIdx.x;
  if (i < 65536) {
    const int r = i >> 7, k = i & 127;
    float v = 0.f;
    if (k < 120) {
      if (r < 240) v = w11[r * 120 + k];
      else if (r >= 256 && r < 496) v = w12[(r - 256) * 120 + k];
    }
    Bffn[i] = __float2bfloat16(v);
  } else if (i < 98304) {
    const int j = i - 65536, r = j >> 8, k = j & 255;
    Bfc2[j] = __float2bfloat16((r < 120 && k < 240) ? fc2w[r * 240 + k] : 0.f);
  } else if (i < 131072) {
    const int j = i - 98304, r = j >> 8, k = j & 255;
    Bproj[j] = __float2bfloat16((r < 120 && k < 240) ? projw[r * 240 + k] : 0.f);
  } else if (i < 278528) {
    const int j = (i - 131072) % 73728;
    const bool is_self = (i - 131072) < 73728;
    const float* w = is_self ? wself : wmut;
    const float* b = is_self ? bself : bmut;
    const int r = j >> 7, k = j & 127;
    const int grp = r / 192;              // 0=q 1=k 2=v
    const int rr = r % 192;
    const int hh = rr >> 5, jj = rr & 31;
    float v = 0.f;
    if (jj < 20) {
      const int orow = grp * 120 + hh * 20 + jj;
      if (k < 120) v = w[orow * 120 + k];
      else if (k == 120) v = b[orow];
      if (grp == 0) v *= SCALE_F;
    } else if (grp == 2 && jj == 20 && k == 120) {
      v = 1.0f;                           // rowsum column
    }
    (is_self ? Wself2 : Wmut2)[j] = __float2bfloat16(v);
  }
}

// posqT[c][t63] = dot(pos[t63], W'_c over real channels); SCALE on q cols.
// TRANSPOSED so the QKV phase can f32x4-load 4 consecutive token rows
// (matching the MFMA C/D row layout quad*4+r).
__global__ __launch_bounds__(256) void k_posqT(
    const float* __restrict__ pos, const float* __restrict__ wmut,
    float* __restrict__ posqT) {
  const int i = blockIdx.x * 256 + threadIdx.x;
  if (i >= 576 * 64) return;
  const int c = i >> 6, t63 = i & 63;
  const int grp = c / 192, rr = c % 192;
  const int hh = rr >> 5, jj = rr & 31;
  float v = 0.f;
  if (jj < 20) {
    v = dot120(pos + (size_t)t63 * CC, wmut + (size_t)(grp * 120 + hh * 20 + jj) * CC);
    if (grp == 0) v *= SCALE_F;
  }
  posqT[i] = v;   // i == c*64 + t63
}

// biasT[h][col][row] = rpb[rpi[row,col]*6+h]  (TRANSPOSED rel-pos bias, fp32)
__global__ __launch_bounds__(256) void k_biasT(
    const int* __restrict__ rpi, const float* __restrict__ rpb,
    float* __restrict__ biasT) {
  const int i = blockIdx.x * 256 + threadIdx.x;
  if (i >= NHEADS * 16384) return;
  const int h = i >> 14, rc = i & 16383;
  const int col = rc >> 7, row = rc & 127;
  biasT[i] = rpb[rpi[row * 128 + col] * NHEADS + h];
}

// LN1 + roll + partition -> A1 bf16 [131072][128], col 120 = 1.0 (bias col).
__global__ __launch_bounds__(256) void k_a1(
    const float* __restrict__ x, const float* __restrict__ g1,
    const float* __restrict__ b1, bf16* __restrict__ A1) {
  const int token = blockIdx.x * 256 + threadIdx.x;
  const float4* xr4 = (const float4*)(x + token_src_offset(token));
  float xv[CC];
#pragma unroll
  for (int k = 0; k < 30; k++) {
    const float4 v = xr4[k];
    xv[k * 4] = v.x; xv[k * 4 + 1] = v.y; xv[k * 4 + 2] = v.z; xv[k * 4 + 3] = v.w;
  }
  ln120(xv, g1, b1);
  bf16x8* dst8 = (bf16x8*)(A1 + (size_t)token * 128);
#pragma unroll
  for (int k = 0; k < 15; k++) {
    bf16x8 v;
#pragma unroll
    for (int j = 0; j < 8; j++) v[j] = f2bf_s(xv[k * 8 + j]);
    dst8[k] = v;
  }
  bf16x8 tail = {0, 0, 0, 0, 0, 0, 0, 0};
  tail[0] = f2bf_s(1.0f);
  dst8[15] = tail;
}

// ---------------------------------------------------------------------------
// FUSED QKV + attention (R15 measured-best: on-the-fly mask from LDS region
// table; no maskT traffic).
template <bool MUT>
__device__ __forceinline__ void fattn_body(
    const int wi, const bf16* __restrict__ A1, const bf16* __restrict__ W2,
    const float* __restrict__ posqT, const float* __restrict__ biasT,
    bf16* __restrict__ xout, bf16* kS, bf16* vS, bf16* qP, int* rgn) {
  const int w = threadIdx.x >> 6, lane = threadIdx.x & 63;
  const int ln = lane & 15, quad = lane >> 4;
  const int wc = wi & 255;
  // window crosses the roll boundary iff any block index is the last one
  const bool hasmask = ((wc >> 6) == 3) || (((wc >> 3) & 7) == 7) || ((wc & 7) == 7);
  // region table (rolled coords): rd=(d>=6)+(d>=7), rh=(h>=56)+(h>=60),
  // rw=(w>=56)+(w>=60); cnt = rd*9+rh*3+rw (matches reference slice order).
  if (threadIdx.x < 128) {
    const int t = threadIdx.x;
    const int d = (wc >> 6) * 2 + (t >> 6);
    const int h = (((wc >> 3) & 7) << 3) + ((t >> 3) & 7);
    const int w2 = ((wc & 7) << 3) + (t & 7);
    const int rd = (d >= 6) + (d >= 7);
    const int rh = (h >= 56) + (h >= 60);
    const int rw = (w2 >= 56) + (w2 >= 60);
    rgn[t] = rd * 9 + rh * 3 + rw;
  }
  // A-fragments for this wave's 32 rows (reused across 6 heads x 3 groups)
  bf16x8 af[2][4];
#pragma unroll
  for (int mi = 0; mi < 2; mi++)
#pragma unroll
    for (int s = 0; s < 4; s++)
      af[mi][s] = *(const bf16x8*)(A1 + (size_t)(wi * NTOK + w * 32 + mi * 16 + ln) * 128 + s * 32 + quad * 8);

  for (int hh = 0; hh < NHEADS; hh++) {
    // ---- QKV phase: group g = 0(q) 1(k) 2(v) ----
#pragma unroll
    for (int g = 0; g < 3; g++) {
      bf16x8 bfr[2][4];
#pragma unroll
      for (int nt = 0; nt < 2; nt++)
#pragma unroll
        for (int s = 0; s < 4; s++)
          bfr[nt][s] = *(const bf16x8*)(W2 + (size_t)(g * 192 + hh * 32 + nt * 16 + ln) * 128 + s * 32 + quad * 8);
      f32x4 acc[2][2] = {};
#pragma unroll
      for (int s = 0; s < 4; s++)
#pragma unroll
        for (int mi = 0; mi < 2; mi++)
#pragma unroll
          for (int nt = 0; nt < 2; nt++)
            acc[mi][nt] = mfma16(af[mi][s], bfr[nt][s], acc[mi][nt]);
      if (MUT) {
#pragma unroll
        for (int mi = 0; mi < 2; mi++)
#pragma unroll
          for (int nt = 0; nt < 2; nt++) {
            const f32x4 pq = *(const f32x4*)&posqT[
                (size_t)(g * 192 + hh * 32 + nt * 16 + ln) * 64 +
                ((w * 32 + mi * 16 + quad * 4) & 63)];
            acc[mi][nt] += pq;
          }
      }
#pragma unroll
      for (int mi = 0; mi < 2; mi++)
#pragma unroll
        for (int nt = 0; nt < 2; nt++)
#pragma unroll
          for (int r = 0; r < 4; r++) {
            const int lrow = w * 32 + mi * 16 + quad * 4 + r;
            const short bv = f2bf_s(acc[mi][nt][r]);
            if (g == 0)      *(short*)&qP[lrow * 40 + nt * 16 + ln] = bv;
            else if (g == 1) *(short*)&kS[lrow * 40 + nt * 16 + ln] = bv;
            else             *(short*)&vS[(nt * 16 + ln) * 136 + lrow] = bv;
          }
    }
    lds_barrier();
    // ---- attention phase ----
    bf16x8 qf[2];
#pragma unroll
    for (int i = 0; i < 2; i++)
      qf[i] = *(const bf16x8*)(&qP[(w * 32 + i * 16 + ln) * 40 + quad * 8]);
    f32x4 accO[2][2];
#pragma unroll
    for (int i = 0; i < 2; i++)
#pragma unroll
      for (int nt = 0; nt < 2; nt++) accO[i][nt] = (f32x4){0.f, 0.f, 0.f, 0.f};
    const int kb = MUT ? ((w < 2) ? 64 : 0) : 0;
    const int nchunk = MUT ? 2 : 4;
    for (int chunk = 0; chunk < nchunk; chunk++) {
      const int key0 = kb + chunk * 32;
      bf16x8 kf[2], vf[2];
      kf[0] = *(const bf16x8*)(&kS[(key0 + ln) * 40 + quad * 8]);
      kf[1] = *(const bf16x8*)(&kS[(key0 + 16 + ln) * 40 + quad * 8]);
      vf[0] = *(const bf16x8*)(&vS[ln * 136 + key0 + quad * 8]);
      vf[1] = *(const bf16x8*)(&vS[(16 + ln) * 136 + key0 + quad * 8]);
#pragma unroll
      for (int i = 0; i < 2; i++) {
        const int rb = w * 32 + i * 16 + quad * 4;
        f32x4 c0, c1;
        if (MUT) {
          c0 = (f32x4){0.f, 0.f, 0.f, 0.f};
          c1 = (f32x4){0.f, 0.f, 0.f, 0.f};
          if (hasmask) {
            const int rc0 = rgn[chunk * 32 + ln];
            const int rc1 = rgn[chunk * 32 + 16 + ln];
#pragma unroll
            for (int r = 0; r < 4; r++) {
              const int rr = rgn[(rb & 63) + r];
              if (rr != rc0) c0[r] = -100.f;
              if (rr != rc1) c1[r] = -100.f;
            }
          }
        } else {
          c0 = *(const f32x4*)&biasT[(size_t)hh * 16384 + (key0 + ln) * 128 + rb];
          c1 = *(const f32x4*)&biasT[(size_t)hh * 16384 + (key0 + 16 + ln) * 128 + rb];
          if (hasmask) {
            const int rc0 = rgn[key0 + ln];
            const int rc1 = rgn[key0 + 16 + ln];
#pragma unroll
            for (int r = 0; r < 4; r++) {
              const int rr = rgn[rb + r];
              if (rr != rc0) c0[r] -= 100.f;
              if (rr != rc1) c1[r] -= 100.f;
            }
          }
        }
        const f32x4 s0 = mfma16(qf[i], kf[0], c0);
        const f32x4 s1 = mfma16(qf[i], kf[1], c1);
#pragma unroll
        for (int r = 0; r < 4; r++) {
          const int row = rb + r;
          *(short*)&qP[row * 40 + ln] = f2bf_s(__expf(s0[r]));
          *(short*)&qP[row * 40 + 16 + ln] = f2bf_s(__expf(s1[r]));
        }
      }
#pragma unroll
      for (int i = 0; i < 2; i++) {
        bf16x8 pf = *(const bf16x8*)(&qP[(w * 32 + i * 16 + ln) * 40 + quad * 8]);
        accO[i][0] = mfma16(pf, vf[0], accO[i][0]);
        accO[i][1] = mfma16(pf, vf[1], accO[i][1]);
      }
    }
    // ---- epilogue: rowsum (V pad col 20) + normalize + write ----
#pragma unroll
    for (int i = 0; i < 2; i++) {
#pragma unroll
      for (int r = 0; r < 4; r++) {
        const float rs = __shfl(accO[i][1][r], (lane & 48) + 4, 64);
        const float inv = 1.f / rs;
        const int row = w * 32 + i * 16 + quad * 4 + r;
        const int orow_i = MUT ? ((w < 2) ? 64 + row : row - 64) : row;
        const int token = wi * NTOK + orow_i;
        bf16* orow = xout + (size_t)token * 256 + (MUT ? 0 : CC) + hh * HDIM;
        orow[ln] = __float2bfloat16(accO[i][0][r] * inv);
        if (ln < 4) orow[16 + ln] = __float2bfloat16(accO[i][1][r] * inv);
      }
    }
    lds_barrier();   // protect kS/vS/qP before next head's QKV overwrite
  }
}

// Merged self+mut launch: blocks 0..1023 self, 1024..2047 mut.
__global__ __launch_bounds__(256, 4) void k_fattn2(
    const bf16* __restrict__ A1, const bf16* __restrict__ Wself2,
    const bf16* __restrict__ Wmut2, const float* __restrict__ posqT,
    const float* __restrict__ biasT, bf16* __restrict__ xout) {
  __shared__ bf16 kS[128 * 40];
  __shared__ bf16 vS[32 * 136];
  __shared__ bf16 qP[128 * 40];   // q staging, then P
  __shared__ int rgnS[128];       // per-window Swin region ids
  if (blockIdx.x < 1024)
    fattn_body<false>(blockIdx.x, A1, Wself2, nullptr, biasT, xout, kS, vS, qP, rgnS);
  else
    fattn_body<true>(blockIdx.x - 1024, A1, Wmut2, posqT, biasT, xout, kS, vS, qP, rgnS);
}

// Output GEMM, K=256 (padded), N=120. grid (1, 1024). PROJ path (R3 verbatim).
template <bool PROJ>
__global__ __launch_bounds__(256) void k_out_mfma(
    const bf16* __restrict__ A, const bf16* __restrict__ Bw,
    const float* __restrict__ bias, const float* __restrict__ xin,
    float* __restrict__ out) {
  const int w = threadIdx.x >> 6;
  const int lane = threadIdx.x & 63;
  const int ln = lane & 15, quad = lane >> 4;
  bf16x8 bfr[2][8];
#pragma unroll
  for (int nt = 0; nt < 2; nt++)
#pragma unroll
    for (int s = 0; s < 8; s++)
      bfr[nt][s] = *(const bf16x8*)(Bw + (size_t)((w * 2 + nt) * 16 + ln) * 256 + s * 32 + quad * 8);
  const int m_base = blockIdx.y * 128;
  for (int it = 0; it < 4; it++) {
    const int m0 = m_base + it * 32;
    f32x4 acc[2][2] = {};
    bf16x8 af[2][8];
#pragma unroll
    for (int mi = 0; mi < 2; mi++)
#pragma unroll
      for (int s = 0; s < 8; s++)
        af[mi][s] = *(const bf16x8*)(A + (size_t)(m0 + mi * 16 + ln) * 256 + s * 32 + quad * 8);
#pragma unroll
    for (int s = 0; s < 8; s++)
#pragma unroll
      for (int mi = 0; mi < 2; mi++)
#pragma unroll
        for (int nt = 0; nt < 2; nt++)
          acc[mi][nt] = mfma16(af[mi][s], bfr[nt][s], acc[mi][nt]);
#pragma unroll
    for (int mi = 0; mi < 2; mi++)
#pragma unroll
      for (int nt = 0; nt < 2; nt++) {
        const int colc = (w * 2 + nt) * 16 + ln;
        if (colc < CC) {
#pragma unroll
          for (int r = 0; r < 4; r++) {
            const int row = m0 + mi * 16 + quad * 4 + r;
            if (PROJ) {
              const size_t dst = token_src_offset(row);
              out[dst + colc] = xin[dst + colc] + bias[colc] + acc[mi][nt][r];
            } else {
              out[(size_t)row * CC + colc] += bias[colc] + acc[mi][nt][r];
            }
          }
        }
      }
  }
}

// ---------------------------------------------------------------------------
// FUSED LN2 + FFN: per block, 32 token rows.
// Phase 0: LN2 on `out` rows (8 thr/row, shuffle-tree) -> aS bf16 [32][136].
// Phase 1: h = gelu(aS@W11^T)*(aS@W12^T) -> hS [32][264]. Phase 2:
// out += h @ fc2^T + bias. Replaces k_ln2 + A2 buffer entirely.
__global__ __launch_bounds__(256) void k_ffn_fused2(
    const bf16* __restrict__ Bffn, const bf16* __restrict__ Bfc2,
    const float* __restrict__ b11, const float* __restrict__ b12,
    const float* __restrict__ fc2b, const float* __restrict__ g2,
    const float* __restrict__ b2, float* out) {
  __shared__ bf16 aS[32][136];
  __shared__ bf16 hS[32][264];
  const int w = threadIdx.x >> 6;
  const int lane = threadIdx.x & 63;
  const int ln = lane & 15, quad = lane >> 4;
  const int m0 = blockIdx.x * 32;
  // ---- phase 0: LN2 -> aS ----
  {
    const int rloc = threadIdx.x >> 3, sub = threadIdx.x & 7;
    const float* orow = out + (size_t)(m0 + rloc) * CC;
    float v[15];
#pragma unroll
    for (int k = 0; k < 15; k++) v[k] = orow[sub * 15 + k];
    float s = 0.f;
#pragma unroll
    for (int k = 0; k < 15; k++) s += v[k];
    s += __shfl_xor(s, 1); s += __shfl_xor(s, 2); s += __shfl_xor(s, 4);
    const float mean = s * (1.f / 120.f);
    float vv = 0.f;
#pragma unroll
    for (int k = 0; k < 15; k++) { const float d = v[k] - mean; vv += d * d; }
    vv += __shfl_xor(vv, 1); vv += __shfl_xor(vv, 2); vv += __shfl_xor(vv, 4);
    const float rstd = rsqrtf(vv * (1.f / 120.f) + 1e-5f);
#pragma unroll
    for (int k = 0; k < 15; k++) {
      const int c = sub * 15 + k;
      aS[rloc][c] = __float2bfloat16((v[k] - mean) * rstd * g2[c] + b2[c]);
    }
    if (sub == 0) {   // zero K-pad cols 120..127 (read by fragments, 0-weighted)
      bf16x8 z = {0, 0, 0, 0, 0, 0, 0, 0};
      *(bf16x8*)&aS[rloc][120] = z;
    }
  }
  lds_barrier();
  // ---- phase 1: FFN1, wave w owns cols w*64 .. w*64+63 ----
  bf16x8 af[2][4];
#pragma unroll
  for (int mi = 0; mi < 2; mi++)
#pragma unroll
    for (int s = 0; s < 4; s++)
      af[mi][s] = *(const bf16x8*)(&aS[mi * 16 + ln][s * 32 + quad * 8]);
#pragma unroll
  for (int nt = 0; nt < 4; nt++) {
    const int col = w * 64 + nt * 16 + ln;
    bf16x8 b1f[4], b2f[4];
#pragma unroll
    for (int s = 0; s < 4; s++) {
      b1f[s] = *(const bf16x8*)(Bffn + (size_t)col * 128 + s * 32 + quad * 8);
      b2f[s] = *(const bf16x8*)(Bffn + (size_t)(256 + col) * 128 + s * 32 + quad * 8);
    }
    f32x4 acc1[2] = {}, acc2[2] = {};
#pragma unroll
    for (int s = 0; s < 4; s++)
#pragma unroll
      for (int mi = 0; mi < 2; mi++) {
        acc1[mi] = mfma16(af[mi][s], b1f[s], acc1[mi]);
        acc2[mi] = mfma16(af[mi][s], b2f[s], acc2[mi]);
      }
    const float bias1 = (col < HID2) ? b11[col] : 0.f;
    const float bias2 = (col < HID2) ? b12[col] : 0.f;
#pragma unroll
    for (int mi = 0; mi < 2; mi++)
#pragma unroll
      for (int r = 0; r < 4; r++) {
        const int row = mi * 16 + quad * 4 + r;
        const float a = acc1[mi][r] + bias1;
        const float c = acc2[mi][r] + bias2;
        const float ge = 0.5f * a * (1.f + erff(a * 0.70710678118654752f));
        hS[row][col] = __float2bfloat16(ge * c);
      }
  }
  lds_barrier();
  // ---- phase 2: FFN2 (K = 256, cols 240..255 of hS are zero-weighted) ----
  bf16x8 bfr[2][8];
#pragma unroll
  for (int nt = 0; nt < 2; nt++)
#pragma unroll
    for (int s = 0; s < 8; s++)
      bfr[nt][s] = *(const bf16x8*)(Bfc2 + (size_t)((w * 2 + nt) * 16 + ln) * 256 + s * 32 + quad * 8);
  bf16x8 af2[2][8];
#pragma unroll
  for (int mi = 0; mi < 2; mi++)
#pragma unroll
    for (int s = 0; s < 8; s++)
      af2[mi][s] = *(const bf16x8*)(&hS[mi * 16 + ln][s * 32 + quad * 8]);
  f32x4 acc[2][2] = {};
#pragma unroll
  for (int s = 0; s < 8; s++)
#pragma unroll
    for (int mi = 0; mi < 2; mi++)
#pragma unroll
      for (int nt = 0; nt < 2; nt++)
        acc[mi][nt] = mfma16(af2[mi][s], bfr[nt][s], acc[mi][nt]);
#pragma unroll
  for (int mi = 0; mi < 2; mi++)
#pragma unroll
    for (int nt = 0; nt < 2; nt++) {
      const int colc = (w * 2 + nt) * 16 + ln;
      if (colc < CC) {
#pragma unroll
        for (int r = 0; r < 4; r++) {
          const int row = m0 + mi * 16 + quad * 4 + r;
          out[(size_t)row * CC + colc] += fc2b[colc] + acc[mi][nt][r];
        }
      }
    }
}

// ===========================================================================
// FALLBACK PATH (round-2 proven kernels; used only if ws is too small)
// ===========================================================================
__global__ __launch_bounds__(128) void k_attn_self_fb(
    const float* __restrict__ x, const float* __restrict__ g1,
    const float* __restrict__ b1, const float* __restrict__ wqkv,
    const float* __restrict__ bqkv, const float* __restrict__ mask,
    const float* __restrict__ rpb, const int* __restrict__ rpi,
    bf16* __restrict__ xout) {
  __shared__ float kl[NTOK][HDIM];
  __shared__ float vl[NTOK][HDIM];
  const int wi = blockIdx.x, hh = blockIdx.y, t = threadIdx.x;
  const int token = wi * NTOK + t;
  const float* xr = x + token_src_offset(token);
  float xv[CC];
#pragma unroll
  for (int k = 0; k < CC; k++) xv[k] = xr[k];
  ln120(xv, g1, b1);
  float q[HDIM];
  for (int j = 0; j < HDIM; j++) {
    const int c = hh * HDIM + j;
    q[j] = (dot120(xv, wqkv + (size_t)c * CC) + bqkv[c]) * SCALE_F;
    kl[t][j] = dot120(xv, wqkv + (size_t)(CC + c) * CC) + bqkv[CC + c];
    vl[t][j] = dot120(xv, wqkv + (size_t)(2 * CC + c) * CC) + bqkv[2 * CC + c];
  }
  __syncthreads();
  const float* mrow = mask + ((size_t)(wi & 255) * NTOK + t) * NTOK;
  const int* rrow = rpi + t * NTOK;
  float sum = 0.f;
  float o[HDIM];
#pragma unroll
  for (int i = 0; i < HDIM; i++) o[i] = 0.f;
  for (int m = 0; m < NTOK; m++) {
    float a0 = 0.f, a1 = 0.f, a2 = 0.f, a3 = 0.f;
#pragma unroll
    for (int i = 0; i < HDIM; i += 4) {
      a0 = fmaf(q[i], kl[m][i], a0);
      a1 = fmaf(q[i + 1], kl[m][i + 1], a1);
      a2 = fmaf(q[i + 2], kl[m][i + 2], a2);
      a3 = fmaf(q[i + 3], kl[m][i + 3], a3);
    }
    const float sc = (a0 + a1) + (a2 + a3) + rpb[rrow[m] * NHEADS + hh] + mrow[m];
    const float p = __expf(sc);
    sum += p;
#pragma unroll
    for (int i = 0; i < HDIM; i++) o[i] = fmaf(p, vl[m][i], o[i]);
  }
  const float inv = 1.f / sum;
  bf16* orow = xout + (size_t)token * HID2 + CC + hh * HDIM;
#pragma unroll
  for (int i = 0; i < HDIM; i++) orow[i] = __float2bfloat16(o[i] * inv);
}

__global__ __launch_bounds__(64) void k_attn_mut_fb(
    const float* __restrict__ x, const float* __restrict__ g1,
    const float* __restrict__ b1, const float* __restrict__ wqkv,
    const float* __restrict__ bqkv, const float* __restrict__ pos,
    const float* __restrict__ mask, bf16* __restrict__ xout) {
  __shared__ float kl[64][HDIM];
  __shared__ float vl[64][HDIM];
  const int wi = blockIdx.x, hh = blockIdx.y, which = blockIdx.z;
  const int t = threadIdx.x;
  const int qtok = which ? t : 64 + t;
  const int ktok = which ? 64 + t : t;
  const float* pr = pos + (size_t)t * CC;
  float xv[CC];
  {
    const float* xr = x + token_src_offset(wi * NTOK + ktok);
#pragma unroll
    for (int k = 0; k < CC; k++) xv[k] = xr[k];
    ln120(xv, g1, b1);
#pragma unroll
    for (int k = 0; k < CC; k++) xv[k] += pr[k];
    for (int j = 0; j < HDIM; j++) {
      const int c = hh * HDIM + j;
      kl[t][j] = dot120(xv, wqkv + (size_t)(CC + c) * CC) + bqkv[CC + c];
      vl[t][j] = dot120(xv, wqkv + (size_t)(2 * CC + c) * CC) + bqkv[2 * CC + c];
    }
  }
  float q[HDIM];
  {
    const float* xr = x + token_src_offset(wi * NTOK + qtok);
#pragma unroll
    for (int k = 0; k < CC; k++) xv[k] = xr[k];
    ln120(xv, g1, b1);
#pragma unroll
    for (int k = 0; k < CC; k++) xv[k] += pr[k];
    for (int j = 0; j < HDIM; j++) {
      const int c = hh * HDIM + j;
      q[j] = (dot120(xv, wqkv + (size_t)c * CC) + bqkv[c]) * SCALE_F;
    }
  }
  __syncthreads();
  const float* mrow = mask + ((size_t)(wi & 255) * NTOK + t) * NTOK;
  float sum = 0.f;
  float o[HDIM];
#pragma unroll
  for (int i = 0; i < HDIM; i++) o[i] = 0.f;
  for (int m = 0; m < 64; m++) {
    float a0 = 0.f, a1 = 0.f, a2 = 0.f, a3 = 0.f;
#pragma unroll
    for (int i = 0; i < HDIM; i += 4) {
      a0 = fmaf(q[i], kl[m][i], a0);
      a1 = fmaf(q[i + 1], kl[m][i + 1], a1);
      a2 = fmaf(q[i + 2], kl[m][i + 2], a2);
      a3 = fmaf(q[i + 3], kl[m][i + 3], a3);
    }
    const float p = __expf((a0 + a1) + (a2 + a3) + mrow[m]);
    sum += p;
#pragma unroll
    for (int i = 0; i < HDIM; i++) o[i] = fmaf(p, vl[m][i], o[i]);
  }
  const float inv = 1.f / sum;
  const int orow_i = which ? 64 + t : t;
  bf16* orow = xout + (size_t)(wi * NTOK + orow_i) * HID2 + hh * HDIM;
#pragma unroll
  for (int i = 0; i < HDIM; i++) orow[i] = __float2bfloat16(o[i] * inv);
}

template <int HALF>
__global__ __launch_bounds__(256) void k_proj_fb(
    const bf16* __restrict__ xout, const float* __restrict__ pw,
    const float* __restrict__ pb, const float* __restrict__ xin,
    float* __restrict__ out) {
  const int token = blockIdx.x * 256 + threadIdx.x;
  float xv[CC];
  const bf16* xr = xout + (size_t)token * HID2 + HALF * CC;
#pragma unroll
  for (int k = 0; k < CC; k++) xv[k] = __bfloat162float(xr[k]);
  const size_t dst = token_src_offset(token);
  for (int o = 0; o < CC; o++) {
    const float acc = dot120(xv, pw + (size_t)o * HID2 + HALF * CC);
    if (HALF == 0)
      out[dst + o] = xin[dst + o] + pb[o] + acc;
    else
      out[dst + o] += acc;
  }
}

__global__ __launch_bounds__(256) void k_ffn1_fb(
    const float* __restrict__ xres, const float* __restrict__ g,
    const float* __restrict__ bb, const float* __restrict__ w11,
    const float* __restrict__ b11, const float* __restrict__ w12,
    const float* __restrict__ b12, bf16* __restrict__ hbuf) {
  const int row = blockIdx.x * 256 + threadIdx.x;
  const float* xr = xres + (size_t)row * CC;
  float xv[CC];
#pragma unroll
  for (int k = 0; k < CC; k++) xv[k] = xr[k];
  ln120(xv, g, bb);
  bf16* hr = hbuf + (size_t)row * HID2;
  for (int o = 0; o < HID2; o++) {
    const float a = b11[o] + dot120(xv, w11 + (size_t)o * CC);
    const float c = b12[o] + dot120(xv, w12 + (size_t)o * CC);
    const float ge = 0.5f * a * (1.f + erff(a * 0.70710678118654752f));
    hr[o] = __float2bfloat16(ge * c);
  }
}

template <int HALF>
__global__ __launch_bounds__(256) void k_ffn2_fb(
    const bf16* __restrict__ hbuf, const float* __restrict__ w2,
    const float* __restrict__ b2f, float* __restrict__ out) {
  const int row = blockIdx.x * 256 + threadIdx.x;
  float xv[CC];
  const bf16* xr = hbuf + (size_t)row * HID2 + HALF * CC;
#pragma unroll
  for (int k = 0; k < CC; k++) xv[k] = __bfloat162float(xr[k]);
  float* orow = out + (size_t)row * CC;
  for (int o = 0; o < CC; o++) {
    float acc = dot120(xv, w2 + (size_t)o * HID2 + HALF * CC);
    if (HALF == 0) acc += b2f[o];
    orow[o] += acc;
  }
}

// ---------------------------------------------------------------------------
extern "C" void kernel_launch(void* const* d_in, const int* in_sizes, int n_in,
                              void* d_out, int out_size, void* d_ws, size_t ws_size,
                              hipStream_t stream) {
  const float* x          = (const float*)d_in[0];
  const float* attn_mask  = (const float*)d_in[1];
  const float* g1         = (const float*)d_in[2];
  const float* b1         = (const float*)d_in[3];
  const float* qkv_self_w = (const float*)d_in[4];
  const float* qkv_self_b = (const float*)d_in[5];
  const float* qkv_mut_w  = (const float*)d_in[6];
  const float* qkv_mut_b  = (const float*)d_in[7];
  const float* proj_w     = (const float*)d_in[8];
  const float* proj_b     = (const float*)d_in[9];
  const float* rpb_table  = (const float*)d_in[10];
  const float* pos_bias   = (const float*)d_in[11];
  const float* g2         = (const float*)d_in[12];
  const float* b2         = (const float*)d_in[13];
  const float* fc11_w     = (const float*)d_in[14];
  const float* fc11_b     = (const float*)d_in[15];
  const float* fc12_w     = (const float*)d_in[16];
  const float* fc12_b     = (const float*)d_in[17];
  const float* fc2_w      = (const float*)d_in[18];
  const float* fc2_b      = (const float*)d_in[19];
  const int*   rpi        = (const int*)d_in[20];
  float* out = (float*)d_out;

  // ws layout (bytes), gate unchanged:
  //   xout  @ 0           : 131072*256*2 = 67,108,864
  //   A1    @ 67,108,864  : 131072*128*2 = 33,554,432
  //   Bffn  @ 100,663,296 : 131,072 ; Bfc2 +65,536 ; Bproj +65,536
  // d_out doubles as scratch until proj overwrites every element:
  //   Wself2 @ 40,000,000 ; Wmut2 @ 40,200,000 ; posqT @ 40,400,000
  //   biasT @ 41,000,000 (393,216) -> ends 41.4 MB < 62.9 MB
  const bool fast = ws_size >= (size_t)100925440;

  if (fast) {
    bf16* xout  = (bf16*)d_ws;
    bf16* A1    = (bf16*)((char*)d_ws + 67108864);
    bf16* Bffn  = (bf16*)((char*)d_ws + 100663296);
    bf16* Bfc2  = Bffn + 65536;
    bf16* Bproj = Bfc2 + 32768;

    bf16*  Wself2 = (bf16*)((char*)d_out + 40000000);
    bf16*  Wmut2  = (bf16*)((char*)d_out + 40200000);
    float* posqT  = (float*)((char*)d_out + 40400000);
    float* biasT  = (float*)((char*)d_out + 41000000);

    k_prep<<<1088, 256, 0, stream>>>(fc11_w, fc12_w, fc2_w, proj_w,
                                     qkv_self_w, qkv_self_b, qkv_mut_w, qkv_mut_b,
                                     Bffn, Bfc2, Bproj, Wself2, Wmut2);
    k_posqT<<<144, 256, 0, stream>>>(pos_bias, qkv_mut_w, posqT);
    k_biasT<<<384, 256, 0, stream>>>(rpi, rpb_table, biasT);
    k_a1<<<512, 256, 0, stream>>>(x, g1, b1, A1);
    k_fattn2<<<2048, 256, 0, stream>>>(A1, Wself2, Wmut2, posqT, biasT, xout);
    k_out_mfma<true><<<dim3(1, 1024), 256, 0, stream>>>(xout, Bproj, proj_b, x, out);
    k_ffn_fused2<<<4096, 256, 0, stream>>>(Bffn, Bfc2, fc11_b, fc12_b, fc2_b, g2, b2, out);
  } else {
    bf16* xout = (bf16*)d_ws;
    bf16* hbuf = (bf16*)d_ws;
    k_attn_self_fb<<<dim3(1024, NHEADS), 128, 0, stream>>>(
        x, g1, b1, qkv_self_w, qkv_self_b, attn_mask, rpb_table, rpi, xout);
    k_attn_mut_fb<<<dim3(1024, NHEADS, 2), 64, 0, stream>>>(
        x, g1, b1, qkv_mut_w, qkv_mut_b, pos_bias, attn_mask, xout);
    k_proj_fb<0><<<512, 256, 0, stream>>>(xout, proj_w, proj_b, x, out);
    k_proj_fb<1><<<512, 256, 0, stream>>>(xout, proj_w, proj_b, x, out);
    k_ffn1_fb<<<512, 256, 0, stream>>>(out, g2, b2, fc11_w, fc11_b, fc12_w, fc12_b, hbuf);
    k_ffn2_fb<0><<<512, 256, 0, stream>>>(hbuf, fc2_w, fc2_b, out);
    k_ffn2_fb<1><<<512, 256, 0, stream>>>(hbuf, fc2_w, fc2_b, out);
  }
}

// Round 18
// 548.139 us; speedup vs baseline: 1.3708x; 1.0255x over previous
//
#include <hip/hip_runtime.h>
#include <hip/hip_bf16.h>
#include <math.h>

#define CC 120       // channels
#define NHEADS 6
#define HDIM 20      // head dim
#define NTOK 128     // tokens per window
#define HID2 240
#define SCALE_F 0.2236067977499790f  // 20^-0.5

typedef __hip_bfloat16 bf16;
typedef __attribute__((ext_vector_type(8))) short bf16x8;   // 8 bf16 (4 VGPRs)
typedef __attribute__((ext_vector_type(4))) float f32x4;    // MFMA accumulator

__device__ inline f32x4 mfma16(bf16x8 a, bf16x8 b, f32x4 c) {
  return __builtin_amdgcn_mfma_f32_16x16x32_bf16(a, b, c, 0, 0, 0);
}

__device__ inline short f2bf_s(float f) {
  bf16 h = __float2bfloat16(f);
  return *reinterpret_cast<short*>(&h);
}

// LDS-only barrier: order LDS ops across waves WITHOUT draining vmcnt
// (global stores keep flying across phases).
__device__ __forceinline__ void lds_barrier() {
  asm volatile("s_waitcnt lgkmcnt(0)" ::: "memory");
  __builtin_amdgcn_s_barrier();
  asm volatile("" ::: "memory");
}

// ---------------------------------------------------------------------------
// token -> rolled spatial source position (also the scatter destination for
// window-reverse + un-roll, which is the same map).
__device__ inline size_t token_src_offset(int token) {
  const int wi = token >> 7, n = token & 127;
  const int b_ = wi >> 8, rem = wi & 255;
  const int dB = rem >> 6, hB = (rem >> 3) & 7, wB = rem & 7;
  const int dI = n >> 6, hI = (n >> 3) & 7, wI = n & 7;
  const int d = dB * 2 + dI, h = hB * 8 + hI, w = wB * 8 + wI;
  const int ds = (d + 1) & 7, hs = (h + 4) & 63, ws2 = (w + 4) & 63;
  return (((size_t)(b_ * 8 + ds) * 64 + hs) * 64 + ws2) * CC;
}

__device__ inline void ln120(float* xv, const float* __restrict__ g,
                             const float* __restrict__ bb) {
  float s0 = 0.f, s1 = 0.f, s2 = 0.f, s3 = 0.f;
#pragma unroll
  for (int k = 0; k < CC; k += 4) {
    s0 += xv[k]; s1 += xv[k + 1]; s2 += xv[k + 2]; s3 += xv[k + 3];
  }
  const float mean = ((s0 + s1) + (s2 + s3)) * (1.f / 120.f);
  float v0 = 0.f, v1 = 0.f, v2 = 0.f, v3 = 0.f;
#pragma unroll
  for (int k = 0; k < CC; k += 4) {
    float d0 = xv[k] - mean, d1 = xv[k + 1] - mean;
    float d2 = xv[k + 2] - mean, d3 = xv[k + 3] - mean;
    v0 += d0 * d0; v1 += d1 * d1; v2 += d2 * d2; v3 += d3 * d3;
  }
  const float rstd = rsqrtf(((v0 + v1) + (v2 + v3)) * (1.f / 120.f) + 1e-5f);
#pragma unroll
  for (int k = 0; k < CC; k++) xv[k] = (xv[k] - mean) * rstd * g[k] + bb[k];
}

__device__ inline float dot120(const float* xv, const float* __restrict__ wr) {
  float a0 = 0.f, a1 = 0.f, a2 = 0.f, a3 = 0.f;
#pragma unroll
  for (int k = 0; k < CC; k += 4) {
    a0 = fmaf(xv[k], wr[k], a0);
    a1 = fmaf(xv[k + 1], wr[k + 1], a1);
    a2 = fmaf(xv[k + 2], wr[k + 2], a2);
    a3 = fmaf(xv[k + 3], wr[k + 3], a3);
  }
  return (a0 + a1) + (a2 + a3);
}

// ===========================================================================
// FAST PATH
// ===========================================================================
// Weight prep.
//  Bffn [512][128]: rows 0..239 = W11, 256..495 = W12 (K pad, bias separate)
//  Bfc2 [128][256], Bproj [128][256]
//  Wself2/Wmut2 [576][128]: rows 0..191 q (heads padded to 32, SCALE folded),
//    192..383 k, 384..575 v. col 120 = bias (A col120 == 1), pads 0.
//    v-row pad chan 20 = e120 (=> V col 20 == 1.0: PV computes softmax rowsum).
__global__ __launch_bounds__(256) void k_prep(
    const float* __restrict__ w11, const float* __restrict__ w12,
    const float* __restrict__ fc2w, const float* __restrict__ projw,
    const float* __restrict__ wself, const float* __restrict__ bself,
    const float* __restrict__ wmut, const float* __restrict__ bmut,
    bf16* __restrict__ Bffn, bf16* __restrict__ Bfc2, bf16* __restrict__ Bproj,
    bf16* __restrict__ Wself2, bf16* __restrict__ Wmut2) {
  const int i = blockIdx.x * 256 + threadIdx.x;
  if (i < 65536) {
    const int r = i >> 7, k = i & 127;
    float v = 0.f;
    if (k < 120) {
      if (r < 240) v = w11[r * 120 + k];
      else if (r >= 256 && r < 496) v = w12[(r - 256) * 120 + k];
    }
    Bffn[i] = __float2bfloat16(v);
  } else if (i < 98304) {
    const int j = i - 65536, r = j >> 8, k = j & 255;
    Bfc2[j] = __float2bfloat16((r < 120 && k < 240) ? fc2w[r * 240 + k] : 0.f);
  } else if (i < 131072) {
    const int j = i - 98304, r = j >> 8, k = j & 255;
    Bproj[j] = __float2bfloat16((r < 120 && k < 240) ? projw[r * 240 + k] : 0.f);
  } else if (i < 278528) {
    const int j = (i - 131072) % 73728;
    const bool is_self = (i - 131072) < 73728;
    const float* w = is_self ? wself : wmut;
    const float* b = is_self ? bself : bmut;
    const int r = j >> 7, k = j & 127;
    const int grp = r / 192;              // 0=q 1=k 2=v
    const int rr = r % 192;
    const int hh = rr >> 5, jj = rr & 31;
    float v = 0.f;
    if (jj < 20) {
      const int orow = grp * 120 + hh * 20 + jj;
      if (k < 120) v = w[orow * 120 + k];
      else if (k == 120) v = b[orow];
      if (grp == 0) v *= SCALE_F;
    } else if (grp == 2 && jj == 20 && k == 120) {
      v = 1.0f;                           // rowsum column
    }
    (is_self ? Wself2 : Wmut2)[j] = __float2bfloat16(v);
  }
}

// posqT[c][t63] = dot(pos[t63], W'_c over real channels); SCALE on q cols.
// TRANSPOSED so the QKV phase can f32x4-load 4 consecutive token rows
// (matching the MFMA C/D row layout quad*4+r).
__global__ __launch_bounds__(256) void k_posqT(
    const float* __restrict__ pos, const float* __restrict__ wmut,
    float* __restrict__ posqT) {
  const int i = blockIdx.x * 256 + threadIdx.x;
  if (i >= 576 * 64) return;
  const int c = i >> 6, t63 = i & 63;
  const int grp = c / 192, rr = c % 192;
  const int hh = rr >> 5, jj = rr & 31;
  float v = 0.f;
  if (jj < 20) {
    v = dot120(pos + (size_t)t63 * CC, wmut + (size_t)(grp * 120 + hh * 20 + jj) * CC);
    if (grp == 0) v *= SCALE_F;
  }
  posqT[i] = v;   // i == c*64 + t63
}

// biasT[h][col][row] = rpb[rpi[row,col]*6+h]  (TRANSPOSED rel-pos bias, fp32)
__global__ __launch_bounds__(256) void k_biasT(
    const int* __restrict__ rpi, const float* __restrict__ rpb,
    float* __restrict__ biasT) {
  const int i = blockIdx.x * 256 + threadIdx.x;
  if (i >= NHEADS * 16384) return;
  const int h = i >> 14, rc = i & 16383;
  const int col = rc >> 7, row = rc & 127;
  biasT[i] = rpb[rpi[row * 128 + col] * NHEADS + h];
}

// ---------------------------------------------------------------------------
// FUSED LN1 + QKV + attention (R17 structure + inline LN1: k_a1 and the A1
// round-trip are eliminated). Each row's LN is computed by its 4 quads via
// shfl_xor(16/32) butterflies; col 120 = 1.0 bias col, 121..127 = 0.
template <bool MUT>
__device__ __forceinline__ void fattn_body(
    const int wi, const float* __restrict__ x, const float* __restrict__ g1,
    const float* __restrict__ b1, const bf16* __restrict__ W2,
    const float* __restrict__ posqT, const float* __restrict__ biasT,
    bf16* __restrict__ xout, bf16* kS, bf16* vS, bf16* qP, int* rgn) {
  const int w = threadIdx.x >> 6, lane = threadIdx.x & 63;
  const int ln = lane & 15, quad = lane >> 4;
  const int wc = wi & 255;
  // window crosses the roll boundary iff any block index is the last one
  const bool hasmask = ((wc >> 6) == 3) || (((wc >> 3) & 7) == 7) || ((wc & 7) == 7);
  // region table (rolled coords): rd=(d>=6)+(d>=7), rh=(h>=56)+(h>=60),
  // rw=(w>=56)+(w>=60); cnt = rd*9+rh*3+rw (matches reference slice order).
  if (threadIdx.x < 128) {
    const int t = threadIdx.x;
    const int d = (wc >> 6) * 2 + (t >> 6);
    const int h = (((wc >> 3) & 7) << 3) + ((t >> 3) & 7);
    const int w2 = ((wc & 7) << 3) + (t & 7);
    const int rd = (d >= 6) + (d >= 7);
    const int rh = (h >= 56) + (h >= 60);
    const int rw = (w2 >= 56) + (w2 >= 60);
    rgn[t] = rd * 9 + rh * 3 + rw;
  }
  // A-fragments via inline LN1. Row w*32+mi*16+ln is split across 4 quads
  // (32 cols each); full-row mean/var via quad-butterfly shuffles.
  bf16x8 af[2][4];
#pragma unroll
  for (int mi = 0; mi < 2; mi++) {
    const int row = w * 32 + mi * 16 + ln;
    const float* xr = x + token_src_offset(wi * NTOK + row);
    float vals[4][8];
    float ps = 0.f;
#pragma unroll
    for (int s = 0; s < 4; s++) {
      if (!(quad == 3 && s == 3)) {     // quad3,s3 = cols 120..127 (pad)
        const int c0 = s * 32 + quad * 8;
        const float4 v0 = *(const float4*)(xr + c0);
        const float4 v1 = *(const float4*)(xr + c0 + 4);
        vals[s][0] = v0.x; vals[s][1] = v0.y; vals[s][2] = v0.z; vals[s][3] = v0.w;
        vals[s][4] = v1.x; vals[s][5] = v1.y; vals[s][6] = v1.z; vals[s][7] = v1.w;
        ps += ((v0.x + v0.y) + (v0.z + v0.w)) + ((v1.x + v1.y) + (v1.z + v1.w));
      }
    }
    ps += __shfl_xor(ps, 16);
    ps += __shfl_xor(ps, 32);
    const float mean = ps * (1.f / 120.f);
    float pv = 0.f;
#pragma unroll
    for (int s = 0; s < 4; s++) {
      if (!(quad == 3 && s == 3)) {
#pragma unroll
        for (int j = 0; j < 8; j++) { const float d = vals[s][j] - mean; pv += d * d; }
      }
    }
    pv += __shfl_xor(pv, 16);
    pv += __shfl_xor(pv, 32);
    const float rstd = rsqrtf(pv * (1.f / 120.f) + 1e-5f);
#pragma unroll
    for (int s = 0; s < 4; s++) {
      bf16x8 v;
      if (quad == 3 && s == 3) {
#pragma unroll
        for (int j = 0; j < 8; j++) v[j] = 0;
        v[0] = f2bf_s(1.0f);            // bias column 120
      } else {
        const int c0 = s * 32 + quad * 8;
#pragma unroll
        for (int j = 0; j < 8; j++)
          v[j] = f2bf_s((vals[s][j] - mean) * rstd * g1[c0 + j] + b1[c0 + j]);
      }
      af[mi][s] = v;
    }
  }

  for (int hh = 0; hh < NHEADS; hh++) {
    // ---- QKV phase: group g = 0(q) 1(k) 2(v) ----
#pragma unroll
    for (int g = 0; g < 3; g++) {
      bf16x8 bfr[2][4];
#pragma unroll
      for (int nt = 0; nt < 2; nt++)
#pragma unroll
        for (int s = 0; s < 4; s++)
          bfr[nt][s] = *(const bf16x8*)(W2 + (size_t)(g * 192 + hh * 32 + nt * 16 + ln) * 128 + s * 32 + quad * 8);
      f32x4 acc[2][2] = {};
#pragma unroll
      for (int s = 0; s < 4; s++)
#pragma unroll
        for (int mi = 0; mi < 2; mi++)
#pragma unroll
          for (int nt = 0; nt < 2; nt++)
            acc[mi][nt] = mfma16(af[mi][s], bfr[nt][s], acc[mi][nt]);
      if (MUT) {
#pragma unroll
        for (int mi = 0; mi < 2; mi++)
#pragma unroll
          for (int nt = 0; nt < 2; nt++) {
            const f32x4 pq = *(const f32x4*)&posqT[
                (size_t)(g * 192 + hh * 32 + nt * 16 + ln) * 64 +
                ((w * 32 + mi * 16 + quad * 4) & 63)];
            acc[mi][nt] += pq;
          }
      }
#pragma unroll
      for (int mi = 0; mi < 2; mi++)
#pragma unroll
        for (int nt = 0; nt < 2; nt++)
#pragma unroll
          for (int r = 0; r < 4; r++) {
            const int lrow = w * 32 + mi * 16 + quad * 4 + r;
            const short bv = f2bf_s(acc[mi][nt][r]);
            if (g == 0)      *(short*)&qP[lrow * 40 + nt * 16 + ln] = bv;
            else if (g == 1) *(short*)&kS[lrow * 40 + nt * 16 + ln] = bv;
            else             *(short*)&vS[(nt * 16 + ln) * 136 + lrow] = bv;
          }
    }
    lds_barrier();
    // ---- attention phase ----
    bf16x8 qf[2];
#pragma unroll
    for (int i = 0; i < 2; i++)
      qf[i] = *(const bf16x8*)(&qP[(w * 32 + i * 16 + ln) * 40 + quad * 8]);
    f32x4 accO[2][2];
#pragma unroll
    for (int i = 0; i < 2; i++)
#pragma unroll
      for (int nt = 0; nt < 2; nt++) accO[i][nt] = (f32x4){0.f, 0.f, 0.f, 0.f};
    const int kb = MUT ? ((w < 2) ? 64 : 0) : 0;
    const int nchunk = MUT ? 2 : 4;
    for (int chunk = 0; chunk < nchunk; chunk++) {
      const int key0 = kb + chunk * 32;
      bf16x8 kf[2], vf[2];
      kf[0] = *(const bf16x8*)(&kS[(key0 + ln) * 40 + quad * 8]);
      kf[1] = *(const bf16x8*)(&kS[(key0 + 16 + ln) * 40 + quad * 8]);
      vf[0] = *(const bf16x8*)(&vS[ln * 136 + key0 + quad * 8]);
      vf[1] = *(const bf16x8*)(&vS[(16 + ln) * 136 + key0 + quad * 8]);
#pragma unroll
      for (int i = 0; i < 2; i++) {
        const int rb = w * 32 + i * 16 + quad * 4;
        f32x4 c0, c1;
        if (MUT) {
          c0 = (f32x4){0.f, 0.f, 0.f, 0.f};
          c1 = (f32x4){0.f, 0.f, 0.f, 0.f};
          if (hasmask) {
            const int rc0 = rgn[chunk * 32 + ln];
            const int rc1 = rgn[chunk * 32 + 16 + ln];
#pragma unroll
            for (int r = 0; r < 4; r++) {
              const int rr = rgn[(rb & 63) + r];
              if (rr != rc0) c0[r] = -100.f;
              if (rr != rc1) c1[r] = -100.f;
            }
          }
        } else {
          c0 = *(const f32x4*)&biasT[(size_t)hh * 16384 + (key0 + ln) * 128 + rb];
          c1 = *(const f32x4*)&biasT[(size_t)hh * 16384 + (key0 + 16 + ln) * 128 + rb];
          if (hasmask) {
            const int rc0 = rgn[key0 + ln];
            const int rc1 = rgn[key0 + 16 + ln];
#pragma unroll
            for (int r = 0; r < 4; r++) {
              const int rr = rgn[rb + r];
              if (rr != rc0) c0[r] -= 100.f;
              if (rr != rc1) c1[r] -= 100.f;
            }
          }
        }
        const f32x4 s0 = mfma16(qf[i], kf[0], c0);
        const f32x4 s1 = mfma16(qf[i], kf[1], c1);
#pragma unroll
        for (int r = 0; r < 4; r++) {
          const int row = rb + r;
          *(short*)&qP[row * 40 + ln] = f2bf_s(__expf(s0[r]));
          *(short*)&qP[row * 40 + 16 + ln] = f2bf_s(__expf(s1[r]));
        }
      }
#pragma unroll
      for (int i = 0; i < 2; i++) {
        bf16x8 pf = *(const bf16x8*)(&qP[(w * 32 + i * 16 + ln) * 40 + quad * 8]);
        accO[i][0] = mfma16(pf, vf[0], accO[i][0]);
        accO[i][1] = mfma16(pf, vf[1], accO[i][1]);
      }
    }
    // ---- epilogue: rowsum (V pad col 20) + normalize + write ----
#pragma unroll
    for (int i = 0; i < 2; i++) {
#pragma unroll
      for (int r = 0; r < 4; r++) {
        const float rs = __shfl(accO[i][1][r], (lane & 48) + 4, 64);
        const float inv = 1.f / rs;
        const int row = w * 32 + i * 16 + quad * 4 + r;
        const int orow_i = MUT ? ((w < 2) ? 64 + row : row - 64) : row;
        const int token = wi * NTOK + orow_i;
        bf16* orow = xout + (size_t)token * 256 + (MUT ? 0 : CC) + hh * HDIM;
        orow[ln] = __float2bfloat16(accO[i][0][r] * inv);
        if (ln < 4) orow[16 + ln] = __float2bfloat16(accO[i][1][r] * inv);
      }
    }
    lds_barrier();   // protect kS/vS/qP before next head's QKV overwrite
  }
}

// Merged self+mut launch: blocks 0..1023 self, 1024..2047 mut.
__global__ __launch_bounds__(256, 4) void k_fattn2(
    const float* __restrict__ x, const float* __restrict__ g1,
    const float* __restrict__ b1, const bf16* __restrict__ Wself2,
    const bf16* __restrict__ Wmut2, const float* __restrict__ posqT,
    const float* __restrict__ biasT, bf16* __restrict__ xout) {
  __shared__ bf16 kS[128 * 40];
  __shared__ bf16 vS[32 * 136];
  __shared__ bf16 qP[128 * 40];   // q staging, then P
  __shared__ int rgnS[128];       // per-window Swin region ids
  if (blockIdx.x < 1024)
    fattn_body<false>(blockIdx.x, x, g1, b1, Wself2, nullptr, biasT, xout, kS, vS, qP, rgnS);
  else
    fattn_body<true>(blockIdx.x - 1024, x, g1, b1, Wmut2, posqT, biasT, xout, kS, vS, qP, rgnS);
}

// Output GEMM, K=256 (padded), N=120. grid (1, 1024). PROJ path (R3 verbatim).
template <bool PROJ>
__global__ __launch_bounds__(256) void k_out_mfma(
    const bf16* __restrict__ A, const bf16* __restrict__ Bw,
    const float* __restrict__ bias, const float* __restrict__ xin,
    float* __restrict__ out) {
  const int w = threadIdx.x >> 6;
  const int lane = threadIdx.x & 63;
  const int ln = lane & 15, quad = lane >> 4;
  bf16x8 bfr[2][8];
#pragma unroll
  for (int nt = 0; nt < 2; nt++)
#pragma unroll
    for (int s = 0; s < 8; s++)
      bfr[nt][s] = *(const bf16x8*)(Bw + (size_t)((w * 2 + nt) * 16 + ln) * 256 + s * 32 + quad * 8);
  const int m_base = blockIdx.y * 128;
  for (int it = 0; it < 4; it++) {
    const int m0 = m_base + it * 32;
    f32x4 acc[2][2] = {};
    bf16x8 af[2][8];
#pragma unroll
    for (int mi = 0; mi < 2; mi++)
#pragma unroll
      for (int s = 0; s < 8; s++)
        af[mi][s] = *(const bf16x8*)(A + (size_t)(m0 + mi * 16 + ln) * 256 + s * 32 + quad * 8);
#pragma unroll
    for (int s = 0; s < 8; s++)
#pragma unroll
      for (int mi = 0; mi < 2; mi++)
#pragma unroll
        for (int nt = 0; nt < 2; nt++)
          acc[mi][nt] = mfma16(af[mi][s], bfr[nt][s], acc[mi][nt]);
#pragma unroll
    for (int mi = 0; mi < 2; mi++)
#pragma unroll
      for (int nt = 0; nt < 2; nt++) {
        const int colc = (w * 2 + nt) * 16 + ln;
        if (colc < CC) {
#pragma unroll
          for (int r = 0; r < 4; r++) {
            const int row = m0 + mi * 16 + quad * 4 + r;
            if (PROJ) {
              const size_t dst = token_src_offset(row);
              out[dst + colc] = xin[dst + colc] + bias[colc] + acc[mi][nt][r];
            } else {
              out[(size_t)row * CC + colc] += bias[colc] + acc[mi][nt][r];
            }
          }
        }
      }
  }
}

// ---------------------------------------------------------------------------
// FUSED LN2 + FFN: per block, 32 token rows.
// Phase 0: LN2 on `out` rows (8 thr/row, shuffle-tree) -> aS bf16 [32][136].
// Phase 1: h = gelu(aS@W11^T)*(aS@W12^T) -> hS [32][264]. Phase 2:
// out += h @ fc2^T + bias. Replaces k_ln2 + A2 buffer entirely.
__global__ __launch_bounds__(256) void k_ffn_fused2(
    const bf16* __restrict__ Bffn, const bf16* __restrict__ Bfc2,
    const float* __restrict__ b11, const float* __restrict__ b12,
    const float* __restrict__ fc2b, const float* __restrict__ g2,
    const float* __restrict__ b2, float* out) {
  __shared__ bf16 aS[32][136];
  __shared__ bf16 hS[32][264];
  const int w = threadIdx.x >> 6;
  const int lane = threadIdx.x & 63;
  const int ln = lane & 15, quad = lane >> 4;
  const int m0 = blockIdx.x * 32;
  // ---- phase 0: LN2 -> aS ----
  {
    const int rloc = threadIdx.x >> 3, sub = threadIdx.x & 7;
    const float* orow = out + (size_t)(m0 + rloc) * CC;
    float v[15];
#pragma unroll
    for (int k = 0; k < 15; k++) v[k] = orow[sub * 15 + k];
    float s = 0.f;
#pragma unroll
    for (int k = 0; k < 15; k++) s += v[k];
    s += __shfl_xor(s, 1); s += __shfl_xor(s, 2); s += __shfl_xor(s, 4);
    const float mean = s * (1.f / 120.f);
    float vv = 0.f;
#pragma unroll
    for (int k = 0; k < 15; k++) { const float d = v[k] - mean; vv += d * d; }
    vv += __shfl_xor(vv, 1); vv += __shfl_xor(vv, 2); vv += __shfl_xor(vv, 4);
    const float rstd = rsqrtf(vv * (1.f / 120.f) + 1e-5f);
#pragma unroll
    for (int k = 0; k < 15; k++) {
      const int c = sub * 15 + k;
      aS[rloc][c] = __float2bfloat16((v[k] - mean) * rstd * g2[c] + b2[c]);
    }
    if (sub == 0) {   // zero K-pad cols 120..127 (read by fragments, 0-weighted)
      bf16x8 z = {0, 0, 0, 0, 0, 0, 0, 0};
      *(bf16x8*)&aS[rloc][120] = z;
    }
  }
  lds_barrier();
  // ---- phase 1: FFN1, wave w owns cols w*64 .. w*64+63 ----
  bf16x8 af[2][4];
#pragma unroll
  for (int mi = 0; mi < 2; mi++)
#pragma unroll
    for (int s = 0; s < 4; s++)
      af[mi][s] = *(const bf16x8*)(&aS[mi * 16 + ln][s * 32 + quad * 8]);
#pragma unroll
  for (int nt = 0; nt < 4; nt++) {
    const int col = w * 64 + nt * 16 + ln;
    bf16x8 b1f[4], b2f[4];
#pragma unroll
    for (int s = 0; s < 4; s++) {
      b1f[s] = *(const bf16x8*)(Bffn + (size_t)col * 128 + s * 32 + quad * 8);
      b2f[s] = *(const bf16x8*)(Bffn + (size_t)(256 + col) * 128 + s * 32 + quad * 8);
    }
    f32x4 acc1[2] = {}, acc2[2] = {};
#pragma unroll
    for (int s = 0; s < 4; s++)
#pragma unroll
      for (int mi = 0; mi < 2; mi++) {
        acc1[mi] = mfma16(af[mi][s], b1f[s], acc1[mi]);
        acc2[mi] = mfma16(af[mi][s], b2f[s], acc2[mi]);
      }
    const float bias1 = (col < HID2) ? b11[col] : 0.f;
    const float bias2 = (col < HID2) ? b12[col] : 0.f;
#pragma unroll
    for (int mi = 0; mi < 2; mi++)
#pragma unroll
      for (int r = 0; r < 4; r++) {
        const int row = mi * 16 + quad * 4 + r;
        const float a = acc1[mi][r] + bias1;
        const float c = acc2[mi][r] + bias2;
        const float ge = 0.5f * a * (1.f + erff(a * 0.70710678118654752f));
        hS[row][col] = __float2bfloat16(ge * c);
      }
  }
  lds_barrier();
  // ---- phase 2: FFN2 (K = 256, cols 240..255 of hS are zero-weighted) ----
  bf16x8 bfr[2][8];
#pragma unroll
  for (int nt = 0; nt < 2; nt++)
#pragma unroll
    for (int s = 0; s < 8; s++)
      bfr[nt][s] = *(const bf16x8*)(Bfc2 + (size_t)((w * 2 + nt) * 16 + ln) * 256 + s * 32 + quad * 8);
  bf16x8 af2[2][8];
#pragma unroll
  for (int mi = 0; mi < 2; mi++)
#pragma unroll
    for (int s = 0; s < 8; s++)
      af2[mi][s] = *(const bf16x8*)(&hS[mi * 16 + ln][s * 32 + quad * 8]);
  f32x4 acc[2][2] = {};
#pragma unroll
  for (int s = 0; s < 8; s++)
#pragma unroll
    for (int mi = 0; mi < 2; mi++)
#pragma unroll
      for (int nt = 0; nt < 2; nt++)
        acc[mi][nt] = mfma16(af2[mi][s], bfr[nt][s], acc[mi][nt]);
#pragma unroll
  for (int mi = 0; mi < 2; mi++)
#pragma unroll
    for (int nt = 0; nt < 2; nt++) {
      const int colc = (w * 2 + nt) * 16 + ln;
      if (colc < CC) {
#pragma unroll
        for (int r = 0; r < 4; r++) {
          const int row = m0 + mi * 16 + quad * 4 + r;
          out[(size_t)row * CC + colc] += fc2b[colc] + acc[mi][nt][r];
        }
      }
    }
}

// ===========================================================================
// FALLBACK PATH (round-2 proven kernels; used only if ws is too small)
// ===========================================================================
__global__ __launch_bounds__(128) void k_attn_self_fb(
    const float* __restrict__ x, const float* __restrict__ g1,
    const float* __restrict__ b1, const float* __restrict__ wqkv,
    const float* __restrict__ bqkv, const float* __restrict__ mask,
    const float* __restrict__ rpb, const int* __restrict__ rpi,
    bf16* __restrict__ xout) {
  __shared__ float kl[NTOK][HDIM];
  __shared__ float vl[NTOK][HDIM];
  const int wi = blockIdx.x, hh = blockIdx.y, t = threadIdx.x;
  const int token = wi * NTOK + t;
  const float* xr = x + token_src_offset(token);
  float xv[CC];
#pragma unroll
  for (int k = 0; k < CC; k++) xv[k] = xr[k];
  ln120(xv, g1, b1);
  float q[HDIM];
  for (int j = 0; j < HDIM; j++) {
    const int c = hh * HDIM + j;
    q[j] = (dot120(xv, wqkv + (size_t)c * CC) + bqkv[c]) * SCALE_F;
    kl[t][j] = dot120(xv, wqkv + (size_t)(CC + c) * CC) + bqkv[CC + c];
    vl[t][j] = dot120(xv, wqkv + (size_t)(2 * CC + c) * CC) + bqkv[2 * CC + c];
  }
  __syncthreads();
  const float* mrow = mask + ((size_t)(wi & 255) * NTOK + t) * NTOK;
  const int* rrow = rpi + t * NTOK;
  float sum = 0.f;
  float o[HDIM];
#pragma unroll
  for (int i = 0; i < HDIM; i++) o[i] = 0.f;
  for (int m = 0; m < NTOK; m++) {
    float a0 = 0.f, a1 = 0.f, a2 = 0.f, a3 = 0.f;
#pragma unroll
    for (int i = 0; i < HDIM; i += 4) {
      a0 = fmaf(q[i], kl[m][i], a0);
      a1 = fmaf(q[i + 1], kl[m][i + 1], a1);
      a2 = fmaf(q[i + 2], kl[m][i + 2], a2);
      a3 = fmaf(q[i + 3], kl[m][i + 3], a3);
    }
    const float sc = (a0 + a1) + (a2 + a3) + rpb[rrow[m] * NHEADS + hh] + mrow[m];
    const float p = __expf(sc);
    sum += p;
#pragma unroll
    for (int i = 0; i < HDIM; i++) o[i] = fmaf(p, vl[m][i], o[i]);
  }
  const float inv = 1.f / sum;
  bf16* orow = xout + (size_t)token * HID2 + CC + hh * HDIM;
#pragma unroll
  for (int i = 0; i < HDIM; i++) orow[i] = __float2bfloat16(o[i] * inv);
}

__global__ __launch_bounds__(64) void k_attn_mut_fb(
    const float* __restrict__ x, const float* __restrict__ g1,
    const float* __restrict__ b1, const float* __restrict__ wqkv,
    const float* __restrict__ bqkv, const float* __restrict__ pos,
    const float* __restrict__ mask, bf16* __restrict__ xout) {
  __shared__ float kl[64][HDIM];
  __shared__ float vl[64][HDIM];
  const int wi = blockIdx.x, hh = blockIdx.y, which = blockIdx.z;
  const int t = threadIdx.x;
  const int qtok = which ? t : 64 + t;
  const int ktok = which ? 64 + t : t;
  const float* pr = pos + (size_t)t * CC;
  float xv[CC];
  {
    const float* xr = x + token_src_offset(wi * NTOK + ktok);
#pragma unroll
    for (int k = 0; k < CC; k++) xv[k] = xr[k];
    ln120(xv, g1, b1);
#pragma unroll
    for (int k = 0; k < CC; k++) xv[k] += pr[k];
    for (int j = 0; j < HDIM; j++) {
      const int c = hh * HDIM + j;
      kl[t][j] = dot120(xv, wqkv + (size_t)(CC + c) * CC) + bqkv[CC + c];
      vl[t][j] = dot120(xv, wqkv + (size_t)(2 * CC + c) * CC) + bqkv[2 * CC + c];
    }
  }
  float q[HDIM];
  {
    const float* xr = x + token_src_offset(wi * NTOK + qtok);
#pragma unroll
    for (int k = 0; k < CC; k++) xv[k] = xr[k];
    ln120(xv, g1, b1);
#pragma unroll
    for (int k = 0; k < CC; k++) xv[k] += pr[k];
    for (int j = 0; j < HDIM; j++) {
      const int c = hh * HDIM + j;
      q[j] = (dot120(xv, wqkv + (size_t)c * CC) + bqkv[c]) * SCALE_F;
    }
  }
  __syncthreads();
  const float* mrow = mask + ((size_t)(wi & 255) * NTOK + t) * NTOK;
  float sum = 0.f;
  float o[HDIM];
#pragma unroll
  for (int i = 0; i < HDIM; i++) o[i] = 0.f;
  for (int m = 0; m < 64; m++) {
    float a0 = 0.f, a1 = 0.f, a2 = 0.f, a3 = 0.f;
#pragma unroll
    for (int i = 0; i < HDIM; i += 4) {
      a0 = fmaf(q[i], kl[m][i], a0);
      a1 = fmaf(q[i + 1], kl[m][i + 1], a1);
      a2 = fmaf(q[i + 2], kl[m][i + 2], a2);
      a3 = fmaf(q[i + 3], kl[m][i + 3], a3);
    }
    const float p = __expf((a0 + a1) + (a2 + a3) + mrow[m]);
    sum += p;
#pragma unroll
    for (int i = 0; i < HDIM; i++) o[i] = fmaf(p, vl[m][i], o[i]);
  }
  const float inv = 1.f / sum;
  const int orow_i = which ? 64 + t : t;
  bf16* orow = xout + (size_t)(wi * NTOK + orow_i) * HID2 + hh * HDIM;
#pragma unroll
  for (int i = 0; i < HDIM; i++) orow[i] = __float2bfloat16(o[i] * inv);
}

template <int HALF>
__global__ __launch_bounds__(256) void k_proj_fb(
    const bf16* __restrict__ xout, const float* __restrict__ pw,
    const float* __restrict__ pb, const float* __restrict__ xin,
    float* __restrict__ out) {
  const int token = blockIdx.x * 256 + threadIdx.x;
  float xv[CC];
  const bf16* xr = xout + (size_t)token * HID2 + HALF * CC;
#pragma unroll
  for (int k = 0; k < CC; k++) xv[k] = __bfloat162float(xr[k]);
  const size_t dst = token_src_offset(token);
  for (int o = 0; o < CC; o++) {
    const float acc = dot120(xv, pw + (size_t)o * HID2 + HALF * CC);
    if (HALF == 0)
      out[dst + o] = xin[dst + o] + pb[o] + acc;
    else
      out[dst + o] += acc;
  }
}

__global__ __launch_bounds__(256) void k_ffn1_fb(
    const float* __restrict__ xres, const float* __restrict__ g,
    const float* __restrict__ bb, const float* __restrict__ w11,
    const float* __restrict__ b11, const float* __restrict__ w12,
    const float* __restrict__ b12, bf16* __restrict__ hbuf) {
  const int row = blockIdx.x * 256 + threadIdx.x;
  const float* xr = xres + (size_t)row * CC;
  float xv[CC];
#pragma unroll
  for (int k = 0; k < CC; k++) xv[k] = xr[k];
  ln120(xv, g, bb);
  bf16* hr = hbuf + (size_t)row * HID2;
  for (int o = 0; o < HID2; o++) {
    const float a = b11[o] + dot120(xv, w11 + (size_t)o * CC);
    const float c = b12[o] + dot120(xv, w12 + (size_t)o * CC);
    const float ge = 0.5f * a * (1.f + erff(a * 0.70710678118654752f));
    hr[o] = __float2bfloat16(ge * c);
  }
}

template <int HALF>
__global__ __launch_bounds__(256) void k_ffn2_fb(
    const bf16* __restrict__ hbuf, const float* __restrict__ w2,
    const float* __restrict__ b2f, float* __restrict__ out) {
  const int row = blockIdx.x * 256 + threadIdx.x;
  float xv[CC];
  const bf16* xr = hbuf + (size_t)row * HID2 + HALF * CC;
#pragma unroll
  for (int k = 0; k < CC; k++) xv[k] = __bfloat162float(xr[k]);
  float* orow = out + (size_t)row * CC;
  for (int o = 0; o < CC; o++) {
    float acc = dot120(xv, w2 + (size_t)o * HID2 + HALF * CC);
    if (HALF == 0) acc += b2f[o];
    orow[o] += acc;
  }
}

// ---------------------------------------------------------------------------
extern "C" void kernel_launch(void* const* d_in, const int* in_sizes, int n_in,
                              void* d_out, int out_size, void* d_ws, size_t ws_size,
                              hipStream_t stream) {
  const float* x          = (const float*)d_in[0];
  const float* attn_mask  = (const float*)d_in[1];
  const float* g1         = (const float*)d_in[2];
  const float* b1         = (const float*)d_in[3];
  const float* qkv_self_w = (const float*)d_in[4];
  const float* qkv_self_b = (const float*)d_in[5];
  const float* qkv_mut_w  = (const float*)d_in[6];
  const float* qkv_mut_b  = (const float*)d_in[7];
  const float* proj_w     = (const float*)d_in[8];
  const float* proj_b     = (const float*)d_in[9];
  const float* rpb_table  = (const float*)d_in[10];
  const float* pos_bias   = (const float*)d_in[11];
  const float* g2         = (const float*)d_in[12];
  const float* b2         = (const float*)d_in[13];
  const float* fc11_w     = (const float*)d_in[14];
  const float* fc11_b     = (const float*)d_in[15];
  const float* fc12_w     = (const float*)d_in[16];
  const float* fc12_b     = (const float*)d_in[17];
  const float* fc2_w      = (const float*)d_in[18];
  const float* fc2_b      = (const float*)d_in[19];
  const int*   rpi        = (const int*)d_in[20];
  float* out = (float*)d_out;

  // ws layout (bytes), gate unchanged:
  //   xout  @ 0           : 131072*256*2 = 67,108,864
  //   (A1 slot free)      @ 67,108,864
  //   Bffn  @ 100,663,296 : 131,072 ; Bfc2 +65,536 ; Bproj +65,536
  // d_out doubles as scratch until proj overwrites every element:
  //   Wself2 @ 40,000,000 ; Wmut2 @ 40,200,000 ; posqT @ 40,400,000
  //   biasT @ 41,000,000 (393,216) -> ends 41.4 MB < 62.9 MB
  const bool fast = ws_size >= (size_t)100925440;

  if (fast) {
    bf16* xout  = (bf16*)d_ws;
    bf16* Bffn  = (bf16*)((char*)d_ws + 100663296);
    bf16* Bfc2  = Bffn + 65536;
    bf16* Bproj = Bfc2 + 32768;

    bf16*  Wself2 = (bf16*)((char*)d_out + 40000000);
    bf16*  Wmut2  = (bf16*)((char*)d_out + 40200000);
    float* posqT  = (float*)((char*)d_out + 40400000);
    float* biasT  = (float*)((char*)d_out + 41000000);

    k_prep<<<1088, 256, 0, stream>>>(fc11_w, fc12_w, fc2_w, proj_w,
                                     qkv_self_w, qkv_self_b, qkv_mut_w, qkv_mut_b,
                                     Bffn, Bfc2, Bproj, Wself2, Wmut2);
    k_posqT<<<144, 256, 0, stream>>>(pos_bias, qkv_mut_w, posqT);
    k_biasT<<<384, 256, 0, stream>>>(rpi, rpb_table, biasT);
    k_fattn2<<<2048, 256, 0, stream>>>(x, g1, b1, Wself2, Wmut2, posqT, biasT, xout);
    k_out_mfma<true><<<dim3(1, 1024), 256, 0, stream>>>(xout, Bproj, proj_b, x, out);
    k_ffn_fused2<<<4096, 256, 0, stream>>>(Bffn, Bfc2, fc11_b, fc12_b, fc2_b, g2, b2, out);
  } else {
    bf16* xout = (bf16*)d_ws;
    bf16* hbuf = (bf16*)d_ws;
    k_attn_self_fb<<<dim3(1024, NHEADS), 128, 0, stream>>>(
        x, g1, b1, qkv_self_w, qkv_self_b, attn_mask, rpb_table, rpi, xout);
    k_attn_mut_fb<<<dim3(1024, NHEADS, 2), 64, 0, stream>>>(
        x, g1, b1, qkv_mut_w, qkv_mut_b, pos_bias, attn_mask, xout);
    k_proj_fb<0><<<512, 256, 0, stream>>>(xout, proj_w, proj_b, x, out);
    k_proj_fb<1><<<512, 256, 0, stream>>>(xout, proj_w, proj_b, x, out);
    k_ffn1_fb<<<512, 256, 0, stream>>>(out, g2, b2, fc11_w, fc11_b, fc12_w, fc12_b, hbuf);
    k_ffn2_fb<0><<<512, 256, 0, stream>>>(hbuf, fc2_w, fc2_b, out);
    k_ffn2_fb<1><<<512, 256, 0, stream>>>(hbuf, fc2_w, fc2_b, out);
  }
}